// Round 1
// baseline (970.637 us; speedup 1.0000x reference)
//
#include <hip/hip_runtime.h>

#define N_PREV 250000
#define N_FULL 500000
#define NVOX   65536
#define NWORDS (1u<<20)          // bitmap words; keyspace < 2^25 bits
#define EPSF   1e-5f

__device__ __forceinline__ float lrelu(float x){ return x > 0.0f ? x : 0.1f*x; }

// ---------------- ws layout (bytes) ----------------
// zeroed region first (one memsetAsync):
#define OFF_BITMAP   0ul            // u32[NWORDS]        4,194,304
#define OFF_STATS    4194304ul      // f32[256]           1,024  (s1,q1,mu1,sc1,s2,q2,mu2,sc2)
#define OFF_CNT      4195328ul      // f32[N_PREV]        1,000,000
#define OFF_VCNT     5195328ul      // f32[NVOX]          262,144
#define OFF_POOLED   5457472ul      // f32[N_PREV*64]     64,000,000  (later aliased as P2)
#define ZERO_BYTES   69457472ul
// not zeroed:
#define OFF_PREF     69457472ul     // u32[NWORDS]
#define OFF_BSUM     73651776ul     // u32[1024]
#define OFF_BOFF     73655872ul     // u32[1024]
#define OFF_UCNT     73659968ul     // u32[1]
#define OFF_INV      73660224ul     // i32[N_PREV]
#define OFF_X1       74660224ul     // f32[N_PREV*32]   (x1; later P1 spans x1+x2 = 64MB)
#define OFF_X2       106660224ul    // f32[N_PREV*32]
#define WS_NEEDED    138660224ul

__device__ __forceinline__ int voxel_key(int4 c){
    return ((c.x*501 + (c.y>>1))*501 + (c.z>>1))*31 + (c.w>>1);
}

// ---- mark present keys ----
__global__ void k_mark(const int* __restrict__ coors, unsigned* __restrict__ bitmap){
    int i = blockIdx.x*256 + threadIdx.x;
    if(i >= N_PREV) return;
    int4 c = ((const int4*)coors)[i];
    int key = voxel_key(c);
    atomicOr(&bitmap[key>>5], 1u<<(key&31));
}

// ---- block-local exclusive scan of word popcounts ----
__global__ void __launch_bounds__(1024) k_scanA(const unsigned* __restrict__ bitmap,
                                                unsigned* __restrict__ pref,
                                                unsigned* __restrict__ bsum){
    __shared__ unsigned sh[1024];
    int tid = threadIdx.x;
    int w = blockIdx.x*1024 + tid;
    unsigned p = __popc(bitmap[w]);
    sh[tid] = p; __syncthreads();
    for(int off=1; off<1024; off<<=1){
        unsigned v = (tid>=off) ? sh[tid-off] : 0u;
        __syncthreads();
        sh[tid] += v;
        __syncthreads();
    }
    pref[w] = sh[tid] - p;                 // exclusive, block-local
    if(tid==1023) bsum[blockIdx.x] = sh[tid];
}

__global__ void __launch_bounds__(1024) k_scanB(const unsigned* __restrict__ bsum,
                                                unsigned* __restrict__ boff,
                                                unsigned* __restrict__ Ucnt){
    __shared__ unsigned sh[1024];
    int tid = threadIdx.x;
    unsigned p = bsum[tid];
    sh[tid] = p; __syncthreads();
    for(int off=1; off<1024; off<<=1){
        unsigned v = (tid>=off) ? sh[tid-off] : 0u;
        __syncthreads();
        sh[tid] += v;
        __syncthreads();
    }
    boff[tid] = sh[tid] - p;               // exclusive block offsets
    if(tid==1023) Ucnt[0] = sh[tid];       // total unique count U
}

// ---- rank per row + scatter counts + scatter pooled sums (1 wave per row) ----
__global__ void k_rank(const int* __restrict__ coors, const float* __restrict__ feat,
                       const unsigned* __restrict__ bitmap, const unsigned* __restrict__ pref,
                       const unsigned* __restrict__ boff, int* __restrict__ inv,
                       float* __restrict__ cnt, float* __restrict__ pooled){
    int wave = (blockIdx.x*256 + threadIdx.x) >> 6;
    int lane = threadIdx.x & 63;
    if(wave >= N_PREV) return;
    int4 c = ((const int4*)coors)[wave];
    int key = voxel_key(c);
    int w = key>>5, b = key&31;
    int rank = (int)(boff[w>>10] + pref[w]) + __popc(bitmap[w] & ((1u<<b)-1u));
    if(lane==0){
        inv[wave] = rank;
        atomicAdd(&cnt[rank], 1.0f);
    }
    atomicAdd(&pooled[rank*64 + lane], feat[wave*64 + lane]);
}

// ---- P1 = lrelu(features @ W_in + b_in) @ Wo1a   [N_PREV,64] ----
__global__ void k_p1(const float* __restrict__ feat, const float* __restrict__ Win,
                     const float* __restrict__ bin, const float* __restrict__ Wo1,
                     float* __restrict__ P1){
    __shared__ float wsh[64*64];
    __shared__ float wash[64*64];
    __shared__ float bsh[64];
    __shared__ float fsh[4][65];
    __shared__ float ish[4][65];
    int tid = threadIdx.x;
    for(int q=tid; q<4096; q+=256){ wsh[q]=Win[q]; wash[q]=Wo1[q]; }
    if(tid<64) bsh[tid]=bin[tid];
    __syncthreads();
    int r = tid>>6, cc = tid&63;
    int base = blockIdx.x*128;
    for(int it=0; it<32; ++it){
        int row = base + it*4 + r;
        __syncthreads();
        if(row < N_PREV) fsh[r][cc] = feat[row*64+cc];
        __syncthreads();
        if(row < N_PREV){
            float acc = 0.f;
            #pragma unroll
            for(int k=0;k<64;++k) acc += fsh[r][k]*wsh[k*64+cc];
            acc += bsh[cc];
            ish[r][cc] = lrelu(acc);
        }
        __syncthreads();
        if(row < N_PREV){
            float acc = 0.f;
            #pragma unroll
            for(int k=0;k<64;++k) acc += ish[r][k]*wash[k*64+cc];
            P1[row*64+cc] = acc;
        }
    }
}

// ---- x1 = lrelu((pooled/cnt) @ W1 + b1), accumulate BN1 stats ----
__global__ void k_ppm1(const float* __restrict__ pooled, const float* __restrict__ cnt,
                       const unsigned* __restrict__ Ucnt, const float* __restrict__ W1,
                       const float* __restrict__ b1, float* __restrict__ x1,
                       float* __restrict__ stats){
    __shared__ float wsh[64*32];
    __shared__ float bsh[32];
    __shared__ float fsh[8][65];
    int tid = threadIdx.x;
    for(int q=tid; q<2048; q+=256) wsh[q]=W1[q];
    if(tid<32) bsh[tid]=b1[tid];
    __syncthreads();
    int U = (int)Ucnt[0];
    int r = tid>>5, cc = tid&31;
    float s_acc=0.f, q_acc=0.f;
    int base = blockIdx.x*256;
    for(int it=0; it<32; ++it){
        int rowL = base + it*8;
        __syncthreads();
        for(int q2=tid; q2<512; q2+=256){
            int rr=q2>>6, kk=q2&63; int rw=rowL+rr;
            if(rw<U) fsh[rr][kk] = pooled[rw*64+kk];
        }
        __syncthreads();
        int row = rowL + r;
        if(row<U){
            float rinv = 1.0f/cnt[row];
            float acc = 0.f;
            #pragma unroll
            for(int k=0;k<64;++k) acc += fsh[r][k]*wsh[k*32+cc];
            acc = acc*rinv + bsh[cc];
            float v = lrelu(acc);
            x1[row*32+cc] = v;
            s_acc += v; q_acc += v*v;
        }
    }
    __syncthreads();
    fsh[r][cc] = s_acc; fsh[r][cc+32] = q_acc;
    __syncthreads();
    if(r==0){
        float ts=0.f, tq=0.f;
        for(int rr=0; rr<8; ++rr){ ts+=fsh[rr][cc]; tq+=fsh[rr][cc+32]; }
        atomicAdd(&stats[cc], ts);
        atomicAdd(&stats[32+cc], tq);
    }
}

// ---- finalize BN params: mu = s/n, sc = g*rsqrt(var+eps) ----
__global__ void k_bnfin(const unsigned* __restrict__ Ucnt, const float* __restrict__ g,
                        float* __restrict__ stats, int off){
    int c = threadIdx.x;
    if(c>=32) return;
    float n = (float)max(Ucnt[0], 1u);
    float mu = stats[off+c]/n;
    float var = stats[off+32+c]/n - mu*mu;
    stats[off+64+c] = mu;
    stats[off+96+c] = g[c]*rsqrtf(var + EPSF);
}

// ---- x2 = lrelu(BN1(x1) @ W2 + b2), accumulate BN2 stats ----
__global__ void k_ppm2(const float* __restrict__ x1, const unsigned* __restrict__ Ucnt,
                       const float* __restrict__ W2, const float* __restrict__ b2,
                       const float* __restrict__ be1, float* __restrict__ x2,
                       float* __restrict__ stats){
    __shared__ float wsh[32*32];
    __shared__ float bsh[32], besh[32], mush[32], scsh[32];
    __shared__ float fsh[8][33];
    int tid = threadIdx.x;
    for(int q=tid; q<1024; q+=256) wsh[q]=W2[q];
    if(tid<32){ bsh[tid]=b2[tid]; besh[tid]=be1[tid]; mush[tid]=stats[64+tid]; scsh[tid]=stats[96+tid]; }
    __syncthreads();
    int U = (int)Ucnt[0];
    int r = tid>>5, cc = tid&31;
    float s_acc=0.f, q_acc=0.f;
    int base = blockIdx.x*256;
    for(int it=0; it<32; ++it){
        int rowL = base + it*8;
        __syncthreads();
        { int rr=tid>>5, kk=tid&31; int rw=rowL+rr;
          if(rw<U) fsh[rr][kk] = (x1[rw*32+kk]-mush[kk])*scsh[kk] + besh[kk]; }
        __syncthreads();
        int row = rowL + r;
        if(row<U){
            float acc=0.f;
            #pragma unroll
            for(int k=0;k<32;++k) acc += fsh[r][k]*wsh[k*32+cc];
            acc += bsh[cc];
            float v = lrelu(acc);
            x2[row*32+cc] = v;
            s_acc += v; q_acc += v*v;
        }
    }
    __syncthreads();
    fsh[r][cc] = s_acc;
    __syncthreads();
    if(r==0){ float ts=0.f; for(int rr=0;rr<8;++rr) ts+=fsh[rr][cc]; atomicAdd(&stats[128+cc], ts); }
    __syncthreads();
    fsh[r][cc] = q_acc;
    __syncthreads();
    if(r==0){ float tq=0.f; for(int rr=0;rr<8;++rr) tq+=fsh[rr][cc]; atomicAdd(&stats[160+cc], tq); }
}

// ---- P2 = ( lrelu(BN2(x2) @ W3 + b3) ) @ Wo1b   [U,64] ----
__global__ void k_ppm3(const float* __restrict__ x2, const unsigned* __restrict__ Ucnt,
                       const float* __restrict__ W3, const float* __restrict__ b3,
                       const float* __restrict__ be2, const float* __restrict__ Wo1,
                       float* __restrict__ P2, const float* __restrict__ stats){
    __shared__ float w3sh[32*64];
    __shared__ float wbsh[64*64];
    __shared__ float b3sh[64];
    __shared__ float besh[32], mush[32], scsh[32];
    __shared__ float fsh[4][33];
    __shared__ float hsh[4][65];
    int tid = threadIdx.x;
    for(int q=tid; q<2048; q+=256) w3sh[q]=W3[q];
    for(int q=tid; q<4096; q+=256) wbsh[q]=Wo1[4096+q];  // rows 64..127 of Wo1
    if(tid<64) b3sh[tid]=b3[tid];
    if(tid<32){ besh[tid]=be2[tid]; mush[tid]=stats[192+tid]; scsh[tid]=stats[224+tid]; }
    __syncthreads();
    int U = (int)Ucnt[0];
    int r = tid>>6, cc = tid&63;
    int base = blockIdx.x*128;
    for(int it=0; it<32; ++it){
        int rowL = base + it*4;
        __syncthreads();
        if(tid<128){ int rr=tid>>5, kk=tid&31; int rw=rowL+rr;
            if(rw<U) fsh[rr][kk] = (x2[rw*32+kk]-mush[kk])*scsh[kk] + besh[kk]; }
        __syncthreads();
        int row = rowL + r;
        if(row<U){
            float acc=0.f;
            #pragma unroll
            for(int k=0;k<32;++k) acc += fsh[r][k]*w3sh[k*64+cc];
            acc += b3sh[cc];
            hsh[r][cc] = lrelu(acc);
        }
        __syncthreads();
        if(row<U){
            float acc=0.f;
            #pragma unroll
            for(int k=0;k<64;++k) acc += hsh[r][k]*wbsh[k*64+cc];
            P2[row*64+cc] = acc;
        }
    }
}

// ---- per full point: t = lrelu(P1[jp]+P2[inv[jp]]+bo1); po = t@Wo2+bo2; scatter ----
__global__ void k_out(const int* __restrict__ cif, const int* __restrict__ scv,
                      const int* __restrict__ inv, const float* __restrict__ P1,
                      const float* __restrict__ P2, const float* __restrict__ bo1,
                      const float* __restrict__ Wo2, const float* __restrict__ bo2,
                      float* __restrict__ vsum, float* __restrict__ vcnt){
    __shared__ float w2sh[64*64];
    __shared__ float bo1sh[64], bo2sh[64];
    __shared__ float tsh[8][65];
    __shared__ int jsh[8], hidx[8], ssh[8];
    int tid = threadIdx.x;
    for(int q=tid; q<4096; q+=256) w2sh[q]=Wo2[q];
    if(tid<64){ bo1sh[tid]=bo1[tid]; bo2sh[tid]=bo2[tid]; }
    __syncthreads();
    int r = tid>>6, cc = tid&63;
    int base = blockIdx.x*256;
    for(int it=0; it<32; ++it){
        int p0 = base + it*8;
        __syncthreads();
        if(tid<8){
            int p = p0 + tid;
            int jp = (p<N_FULL) ? cif[p] : 0;
            jsh[tid] = jp;
            hidx[tid] = (p<N_FULL) ? inv[jp] : 0;
            ssh[tid] = (p<N_FULL) ? scv[p] : 0;
        }
        __syncthreads();
        if(tid<8 && (p0+tid)<N_FULL) atomicAdd(&vcnt[ssh[tid]], 1.0f);
        for(int rr=r; rr<8; rr+=4){
            int p = p0 + rr;
            if(p<N_FULL){
                float g = P1[jsh[rr]*64+cc] + P2[hidx[rr]*64+cc] + bo1sh[cc];
                tsh[rr][cc] = lrelu(g);
            }
        }
        __syncthreads();
        for(int rr=r; rr<8; rr+=4){
            int p = p0 + rr;
            if(p<N_FULL){
                float acc=0.f;
                #pragma unroll
                for(int k=0;k<64;++k) acc += tsh[rr][k]*w2sh[k*64+cc];
                acc += bo2sh[cc];
                atomicAdd(&vsum[ssh[rr]*64+cc], acc);
            }
        }
    }
}

// ---- divide by counts ----
__global__ void k_div(float* __restrict__ out, const float* __restrict__ vcnt){
    int i = blockIdx.x*256 + threadIdx.x;   // over NVOX*64
    int v = i>>6;
    float c = fmaxf(vcnt[v], 1.0f);
    out[i] = out[i] / c;
}

extern "C" void kernel_launch(void* const* d_in, const int* in_sizes, int n_in,
                              void* d_out, int out_size, void* d_ws, size_t ws_size,
                              hipStream_t stream) {
    if(ws_size < WS_NEEDED) return;  // need ~133 MiB scratch

    const float* features = (const float*)d_in[0];
    const int*   coors    = (const int*)d_in[1];
    const int*   cif      = (const int*)d_in[2];
    const int*   scv      = (const int*)d_in[3];
    const float* W_in     = (const float*)d_in[4];
    const float* b_in     = (const float*)d_in[5];
    const float* W1       = (const float*)d_in[6];
    const float* b1       = (const float*)d_in[7];
    const float* g1       = (const float*)d_in[8];
    const float* be1      = (const float*)d_in[9];
    const float* W2       = (const float*)d_in[10];
    const float* b2       = (const float*)d_in[11];
    const float* g2       = (const float*)d_in[12];
    const float* be2      = (const float*)d_in[13];
    const float* W3       = (const float*)d_in[14];
    const float* b3       = (const float*)d_in[15];
    const float* Wo1      = (const float*)d_in[16];
    const float* bo1      = (const float*)d_in[17];
    const float* Wo2      = (const float*)d_in[18];
    const float* bo2      = (const float*)d_in[19];

    char* ws = (char*)d_ws;
    unsigned* bitmap = (unsigned*)(ws + OFF_BITMAP);
    float*    stats  = (float*)(ws + OFF_STATS);
    float*    cnt    = (float*)(ws + OFF_CNT);
    float*    vcnt   = (float*)(ws + OFF_VCNT);
    float*    pooled = (float*)(ws + OFF_POOLED);   // aliased as P2 after k_ppm1
    unsigned* pref   = (unsigned*)(ws + OFF_PREF);
    unsigned* bsum   = (unsigned*)(ws + OFF_BSUM);
    unsigned* boff   = (unsigned*)(ws + OFF_BOFF);
    unsigned* Ucnt   = (unsigned*)(ws + OFF_UCNT);
    int*      inv    = (int*)(ws + OFF_INV);
    float*    x1     = (float*)(ws + OFF_X1);       // P1 aliases x1..x2 span after k_ppm3
    float*    x2     = (float*)(ws + OFF_X2);
    float*    P1     = (float*)(ws + OFF_X1);
    float*    P2     = pooled;
    float*    vsum   = (float*)d_out;

    hipMemsetAsync(d_ws, 0, ZERO_BYTES, stream);
    hipMemsetAsync(d_out, 0, (size_t)out_size*sizeof(float), stream);

    k_mark <<<(N_PREV+255)/256, 256, 0, stream>>>(coors, bitmap);
    k_scanA<<<1024, 1024, 0, stream>>>(bitmap, pref, bsum);
    k_scanB<<<1, 1024, 0, stream>>>(bsum, boff, Ucnt);
    k_rank <<<N_PREV/4, 256, 0, stream>>>(coors, features, bitmap, pref, boff, inv, cnt, pooled);
    k_ppm1 <<<(N_PREV+255)/256, 256, 0, stream>>>(pooled, cnt, Ucnt, W1, b1, x1, stats);
    k_bnfin<<<1, 32, 0, stream>>>(Ucnt, g1, stats, 0);
    k_ppm2 <<<(N_PREV+255)/256, 256, 0, stream>>>(x1, Ucnt, W2, b2, be1, x2, stats);
    k_bnfin<<<1, 32, 0, stream>>>(Ucnt, g2, stats, 128);
    k_ppm3 <<<(N_PREV+127)/128, 256, 0, stream>>>(x2, Ucnt, W3, b3, be2, Wo1, P2, stats);
    k_p1   <<<(N_PREV+127)/128, 256, 0, stream>>>(features, W_in, b_in, Wo1, P1);
    k_out  <<<(N_FULL+255)/256, 256, 0, stream>>>(cif, scv, inv, P1, P2, bo1, Wo2, bo2, vsum, vcnt);
    k_div  <<<(NVOX*64)/256, 256, 0, stream>>>(vsum, vcnt);
}

// Round 2
// 834.043 us; speedup vs baseline: 1.1638x; 1.1638x over previous
//
#include <hip/hip_runtime.h>

#define N_PREV 250000
#define N_FULL 500000
#define NVOX   65536
#define NWORDS (1u<<20)          // bitmap words; keyspace < 2^25 bits
#define EPSF   1e-5f

__device__ __forceinline__ float lrelu(float x){ return x > 0.0f ? x : 0.1f*x; }

// ---------------- ws layout (bytes) ----------------
// zeroed region first (one memsetAsync):
#define OFF_BITMAP   0ul            // u32[NWORDS]        4,194,304 (aliased as csr_j/csr_h after k_rank)
#define OFF_STATS    4194304ul      // f32[256]           1,024
#define OFF_CNT      4195328ul      // f32[N_PREV]        1,000,000
#define OFF_VH       5195328ul      // u32[NVOX]          262,144  (voxel histogram, zeroed)
#define OFF_POOLED   5457472ul      // f32[N_PREV*64]     64,000,000  (later aliased as P2)
#define ZERO_BYTES   69457472ul
// not zeroed:
#define OFF_PREF     69457472ul     // u32[NWORDS]  (aliased as vstart/vnext/vpart/vbsum after k_rank)
#define OFF_BSUM     73651776ul     // u32[1024]
#define OFF_BOFF     73655872ul     // u32[1024]
#define OFF_UCNT     73659968ul     // u32[1]
#define OFF_INV      73660224ul     // i32[N_PREV]
#define OFF_X1       74660224ul     // f32[N_PREV*32]   (x1; later P1 spans x1+x2 = 64MB)
#define OFF_X2       106660224ul    // f32[N_PREV*32]
#define WS_NEEDED    138660224ul
// aliases:
#define OFF_CSRJ     0ul                       // i32[N_FULL]  (2,000,000 B) in bitmap region
#define OFF_CSRH     2000000ul                 // i32[N_FULL]
#define OFF_VSTART   69457472ul                // u32[NVOX+1] in pref region
#define OFF_VNEXT    (OFF_VSTART+262400ul)     // u32[NVOX]
#define OFF_VPART    (OFF_VNEXT+262144ul)      // u32[NVOX]
#define OFF_VBSUM    (OFF_VPART+262144ul)      // u32[64]

__device__ __forceinline__ int voxel_key(int4 c){
    return ((c.x*501 + (c.y>>1))*501 + (c.z>>1))*31 + (c.w>>1);
}

// ---- mark present keys ----
__global__ void k_mark(const int* __restrict__ coors, unsigned* __restrict__ bitmap){
    int i = blockIdx.x*256 + threadIdx.x;
    if(i >= N_PREV) return;
    int4 c = ((const int4*)coors)[i];
    int key = voxel_key(c);
    atomicOr(&bitmap[key>>5], 1u<<(key&31));
}

// ---- block-local exclusive scan of word popcounts ----
__global__ void __launch_bounds__(1024) k_scanA(const unsigned* __restrict__ bitmap,
                                                unsigned* __restrict__ pref,
                                                unsigned* __restrict__ bsum){
    __shared__ unsigned sh[1024];
    int tid = threadIdx.x;
    int w = blockIdx.x*1024 + tid;
    unsigned p = __popc(bitmap[w]);
    sh[tid] = p; __syncthreads();
    for(int off=1; off<1024; off<<=1){
        unsigned v = (tid>=off) ? sh[tid-off] : 0u;
        __syncthreads();
        sh[tid] += v;
        __syncthreads();
    }
    pref[w] = sh[tid] - p;                 // exclusive, block-local
    if(tid==1023) bsum[blockIdx.x] = sh[tid];
}

__global__ void __launch_bounds__(1024) k_scanB(const unsigned* __restrict__ bsum,
                                                unsigned* __restrict__ boff,
                                                unsigned* __restrict__ Ucnt){
    __shared__ unsigned sh[1024];
    int tid = threadIdx.x;
    unsigned p = bsum[tid];
    sh[tid] = p; __syncthreads();
    for(int off=1; off<1024; off<<=1){
        unsigned v = (tid>=off) ? sh[tid-off] : 0u;
        __syncthreads();
        sh[tid] += v;
        __syncthreads();
    }
    boff[tid] = sh[tid] - p;               // exclusive block offsets
    if(tid==1023) Ucnt[0] = sh[tid];       // total unique count U
}

// ---- rank per row + scatter counts + scatter pooled sums (1 wave per row) ----
__global__ void k_rank(const int* __restrict__ coors, const float* __restrict__ feat,
                       const unsigned* __restrict__ bitmap, const unsigned* __restrict__ pref,
                       const unsigned* __restrict__ boff, int* __restrict__ inv,
                       float* __restrict__ cnt, float* __restrict__ pooled){
    int wave = (blockIdx.x*256 + threadIdx.x) >> 6;
    int lane = threadIdx.x & 63;
    if(wave >= N_PREV) return;
    int4 c = ((const int4*)coors)[wave];
    int key = voxel_key(c);
    int w = key>>5, b = key&31;
    int rank = (int)(boff[w>>10] + pref[w]) + __popc(bitmap[w] & ((1u<<b)-1u));
    if(lane==0){
        inv[wave] = rank;
        atomicAdd(&cnt[rank], 1.0f);
    }
    atomicAdd(&pooled[rank*64 + lane], feat[wave*64 + lane]);
}

// ---- CSR build over scale voxels ----
__global__ void k_vhist(const int* __restrict__ scv, unsigned* __restrict__ vh){
    int p = blockIdx.x*256 + threadIdx.x;
    if(p < N_FULL) atomicAdd(&vh[scv[p]], 1u);
}

__global__ void __launch_bounds__(1024) k_vscanA(const unsigned* __restrict__ vh,
                                                 unsigned* __restrict__ vpart,
                                                 unsigned* __restrict__ vbsum){
    __shared__ unsigned sh[1024];
    int tid = threadIdx.x;
    int w = blockIdx.x*1024 + tid;   // 64 blocks
    unsigned p = vh[w];
    sh[tid] = p; __syncthreads();
    for(int off=1; off<1024; off<<=1){
        unsigned v = (tid>=off) ? sh[tid-off] : 0u;
        __syncthreads();
        sh[tid] += v;
        __syncthreads();
    }
    vpart[w] = sh[tid] - p;
    if(tid==1023) vbsum[blockIdx.x] = sh[tid];
}

__global__ void k_vscanB(unsigned* __restrict__ vbsum){
    int l = threadIdx.x;  // 64 threads
    unsigned v = vbsum[l], orig = v;
    for(int off=1; off<64; off<<=1){
        unsigned o = __shfl_up(v, off);
        if(l>=off) v += o;
    }
    vbsum[l] = v - orig;   // exclusive
}

__global__ void __launch_bounds__(1024) k_vfix(const unsigned* __restrict__ vpart,
                                               const unsigned* __restrict__ vbsum,
                                               unsigned* __restrict__ vstart,
                                               unsigned* __restrict__ vnext){
    int w = blockIdx.x*1024 + threadIdx.x;  // 64 blocks
    unsigned s = vpart[w] + vbsum[w>>10];
    vstart[w] = s; vnext[w] = s;
    if(w == NVOX-1) vstart[NVOX] = N_FULL;
}

__global__ void k_fill(const int* __restrict__ cif, const int* __restrict__ scv,
                       const int* __restrict__ inv, unsigned* __restrict__ vnext,
                       int* __restrict__ csr_j, int* __restrict__ csr_h){
    int p = blockIdx.x*256 + threadIdx.x;
    if(p >= N_FULL) return;
    int jp = cif[p];
    unsigned pos = atomicAdd(&vnext[scv[p]], 1u);
    csr_j[pos] = jp;
    csr_h[pos] = inv[jp];
}

// ---- P1 = lrelu(features @ W_in + b_in) @ Wo1a   [N_PREV,64] ----
__global__ void k_p1(const float* __restrict__ feat, const float* __restrict__ Win,
                     const float* __restrict__ bin, const float* __restrict__ Wo1,
                     float* __restrict__ P1){
    __shared__ float wsh[64*64];
    __shared__ float wash[64*64];
    __shared__ float bsh[64];
    __shared__ float fsh[4][65];
    __shared__ float ish[4][65];
    int tid = threadIdx.x;
    for(int q=tid; q<4096; q+=256){ wsh[q]=Win[q]; wash[q]=Wo1[q]; }
    if(tid<64) bsh[tid]=bin[tid];
    __syncthreads();
    int r = tid>>6, cc = tid&63;
    int base = blockIdx.x*128;
    for(int it=0; it<32; ++it){
        int row = base + it*4 + r;
        __syncthreads();
        if(row < N_PREV) fsh[r][cc] = feat[row*64+cc];
        __syncthreads();
        if(row < N_PREV){
            float acc = 0.f;
            #pragma unroll
            for(int k=0;k<64;++k) acc += fsh[r][k]*wsh[k*64+cc];
            acc += bsh[cc];
            ish[r][cc] = lrelu(acc);
        }
        __syncthreads();
        if(row < N_PREV){
            float acc = 0.f;
            #pragma unroll
            for(int k=0;k<64;++k) acc += ish[r][k]*wash[k*64+cc];
            P1[row*64+cc] = acc;
        }
    }
}

// ---- x1 = lrelu((pooled/cnt) @ W1 + b1), accumulate BN1 stats ----
__global__ void k_ppm1(const float* __restrict__ pooled, const float* __restrict__ cnt,
                       const unsigned* __restrict__ Ucnt, const float* __restrict__ W1,
                       const float* __restrict__ b1, float* __restrict__ x1,
                       float* __restrict__ stats){
    __shared__ float wsh[64*32];
    __shared__ float bsh[32];
    __shared__ float fsh[8][65];
    int tid = threadIdx.x;
    for(int q=tid; q<2048; q+=256) wsh[q]=W1[q];
    if(tid<32) bsh[tid]=b1[tid];
    __syncthreads();
    int U = (int)Ucnt[0];
    int r = tid>>5, cc = tid&31;
    float s_acc=0.f, q_acc=0.f;
    int base = blockIdx.x*256;
    for(int it=0; it<32; ++it){
        int rowL = base + it*8;
        __syncthreads();
        for(int q2=tid; q2<512; q2+=256){
            int rr=q2>>6, kk=q2&63; int rw=rowL+rr;
            if(rw<U) fsh[rr][kk] = pooled[rw*64+kk];
        }
        __syncthreads();
        int row = rowL + r;
        if(row<U){
            float rinv = 1.0f/cnt[row];
            float acc = 0.f;
            #pragma unroll
            for(int k=0;k<64;++k) acc += fsh[r][k]*wsh[k*32+cc];
            acc = acc*rinv + bsh[cc];
            float v = lrelu(acc);
            x1[row*32+cc] = v;
            s_acc += v; q_acc += v*v;
        }
    }
    __syncthreads();
    fsh[r][cc] = s_acc; fsh[r][cc+32] = q_acc;
    __syncthreads();
    if(r==0){
        float ts=0.f, tq=0.f;
        for(int rr=0; rr<8; ++rr){ ts+=fsh[rr][cc]; tq+=fsh[rr][cc+32]; }
        atomicAdd(&stats[cc], ts);
        atomicAdd(&stats[32+cc], tq);
    }
}

// ---- finalize BN params ----
__global__ void k_bnfin(const unsigned* __restrict__ Ucnt, const float* __restrict__ g,
                        float* __restrict__ stats, int off){
    int c = threadIdx.x;
    if(c>=32) return;
    float n = (float)max(Ucnt[0], 1u);
    float mu = stats[off+c]/n;
    float var = stats[off+32+c]/n - mu*mu;
    stats[off+64+c] = mu;
    stats[off+96+c] = g[c]*rsqrtf(var + EPSF);
}

// ---- x2 = lrelu(BN1(x1) @ W2 + b2), accumulate BN2 stats ----
__global__ void k_ppm2(const float* __restrict__ x1, const unsigned* __restrict__ Ucnt,
                       const float* __restrict__ W2, const float* __restrict__ b2,
                       const float* __restrict__ be1, float* __restrict__ x2,
                       float* __restrict__ stats){
    __shared__ float wsh[32*32];
    __shared__ float bsh[32], besh[32], mush[32], scsh[32];
    __shared__ float fsh[8][33];
    int tid = threadIdx.x;
    for(int q=tid; q<1024; q+=256) wsh[q]=W2[q];
    if(tid<32){ bsh[tid]=b2[tid]; besh[tid]=be1[tid]; mush[tid]=stats[64+tid]; scsh[tid]=stats[96+tid]; }
    __syncthreads();
    int U = (int)Ucnt[0];
    int r = tid>>5, cc = tid&31;
    float s_acc=0.f, q_acc=0.f;
    int base = blockIdx.x*256;
    for(int it=0; it<32; ++it){
        int rowL = base + it*8;
        __syncthreads();
        { int rr=tid>>5, kk=tid&31; int rw=rowL+rr;
          if(rw<U) fsh[rr][kk] = (x1[rw*32+kk]-mush[kk])*scsh[kk] + besh[kk]; }
        __syncthreads();
        int row = rowL + r;
        if(row<U){
            float acc=0.f;
            #pragma unroll
            for(int k=0;k<32;++k) acc += fsh[r][k]*wsh[k*32+cc];
            acc += bsh[cc];
            float v = lrelu(acc);
            x2[row*32+cc] = v;
            s_acc += v; q_acc += v*v;
        }
    }
    __syncthreads();
    fsh[r][cc] = s_acc;
    __syncthreads();
    if(r==0){ float ts=0.f; for(int rr=0;rr<8;++rr) ts+=fsh[rr][cc]; atomicAdd(&stats[128+cc], ts); }
    __syncthreads();
    fsh[r][cc] = q_acc;
    __syncthreads();
    if(r==0){ float tq=0.f; for(int rr=0;rr<8;++rr) tq+=fsh[rr][cc]; atomicAdd(&stats[160+cc], tq); }
}

// ---- P2 = ( lrelu(BN2(x2) @ W3 + b3) ) @ Wo1b   [U,64] ----
__global__ void k_ppm3(const float* __restrict__ x2, const unsigned* __restrict__ Ucnt,
                       const float* __restrict__ W3, const float* __restrict__ b3,
                       const float* __restrict__ be2, const float* __restrict__ Wo1,
                       float* __restrict__ P2, const float* __restrict__ stats){
    __shared__ float w3sh[32*64];
    __shared__ float wbsh[64*64];
    __shared__ float b3sh[64];
    __shared__ float besh[32], mush[32], scsh[32];
    __shared__ float fsh[4][33];
    __shared__ float hsh[4][65];
    int tid = threadIdx.x;
    for(int q=tid; q<2048; q+=256) w3sh[q]=W3[q];
    for(int q=tid; q<4096; q+=256) wbsh[q]=Wo1[4096+q];  // rows 64..127 of Wo1
    if(tid<64) b3sh[tid]=b3[tid];
    if(tid<32){ besh[tid]=be2[tid]; mush[tid]=stats[192+tid]; scsh[tid]=stats[224+tid]; }
    __syncthreads();
    int U = (int)Ucnt[0];
    int r = tid>>6, cc = tid&63;
    int base = blockIdx.x*128;
    for(int it=0; it<32; ++it){
        int rowL = base + it*4;
        __syncthreads();
        if(tid<128){ int rr=tid>>5, kk=tid&31; int rw=rowL+rr;
            if(rw<U) fsh[rr][kk] = (x2[rw*32+kk]-mush[kk])*scsh[kk] + besh[kk]; }
        __syncthreads();
        int row = rowL + r;
        if(row<U){
            float acc=0.f;
            #pragma unroll
            for(int k=0;k<32;++k) acc += fsh[r][k]*w3sh[k*64+cc];
            acc += b3sh[cc];
            hsh[r][cc] = lrelu(acc);
        }
        __syncthreads();
        if(row<U){
            float acc=0.f;
            #pragma unroll
            for(int k=0;k<64;++k) acc += hsh[r][k]*wbsh[k*64+cc];
            P2[row*64+cc] = acc;
        }
    }
}

// ---- one wave per voxel: T = Σ lrelu(P1[j]+P2[h]+bo1); out = (T@Wo2 + cnt*bo2)/max(cnt,1) ----
__global__ void __launch_bounds__(256) k_vox(const unsigned* __restrict__ vstart,
        const int* __restrict__ csr_j, const int* __restrict__ csr_h,
        const float* __restrict__ P1, const float* __restrict__ P2,
        const float* __restrict__ bo1, const float* __restrict__ Wo2,
        const float* __restrict__ bo2, float* __restrict__ out){
    __shared__ float tsh[4][64];
    int tid = threadIdx.x;
    int wib = tid>>6, lane = tid&63;
    // column `lane` of Wo2 in registers
    float wreg[64];
    #pragma unroll
    for(int k=0;k<64;++k) wreg[k] = Wo2[k*64+lane];
    float b1 = bo1[lane], b2 = bo2[lane];
    int wglobal = blockIdx.x*4 + wib;
    for(int vq=0; vq<4; ++vq){
        int vox = wglobal*4 + vq;
        int s = (int)vstart[vox], e = (int)vstart[vox+1];
        float acc = 0.f;
        for(int i=s; i<e; i+=64){
            int n = min(e-i, 64);
            int jv=0, hv=0;
            if(lane<n){ jv = csr_j[i+lane]; hv = csr_h[i+lane]; }
            for(int q=0;q<n;++q){
                int j = __shfl(jv,q), h = __shfl(hv,q);
                float g = P1[j*64+lane] + P2[h*64+lane] + b1;
                acc += (g>0.f) ? g : 0.1f*g;
            }
        }
        tsh[wib][lane] = acc;
        float dot = 0.f;
        const float4* t4 = (const float4*)tsh[wib];
        #pragma unroll
        for(int k4=0;k4<16;++k4){
            float4 t = t4[k4];
            dot += t.x*wreg[4*k4] + t.y*wreg[4*k4+1] + t.z*wreg[4*k4+2] + t.w*wreg[4*k4+3];
        }
        float cntv = (float)(e - s);
        out[vox*64+lane] = (dot + cntv*b2) / fmaxf(cntv, 1.f);
    }
}

extern "C" void kernel_launch(void* const* d_in, const int* in_sizes, int n_in,
                              void* d_out, int out_size, void* d_ws, size_t ws_size,
                              hipStream_t stream) {
    if(ws_size < WS_NEEDED) return;

    const float* features = (const float*)d_in[0];
    const int*   coors    = (const int*)d_in[1];
    const int*   cif      = (const int*)d_in[2];
    const int*   scv      = (const int*)d_in[3];
    const float* W_in     = (const float*)d_in[4];
    const float* b_in     = (const float*)d_in[5];
    const float* W1       = (const float*)d_in[6];
    const float* b1       = (const float*)d_in[7];
    const float* g1       = (const float*)d_in[8];
    const float* be1      = (const float*)d_in[9];
    const float* W2       = (const float*)d_in[10];
    const float* b2       = (const float*)d_in[11];
    const float* g2       = (const float*)d_in[12];
    const float* be2      = (const float*)d_in[13];
    const float* W3       = (const float*)d_in[14];
    const float* b3       = (const float*)d_in[15];
    const float* Wo1      = (const float*)d_in[16];
    const float* bo1      = (const float*)d_in[17];
    const float* Wo2      = (const float*)d_in[18];
    const float* bo2      = (const float*)d_in[19];

    char* ws = (char*)d_ws;
    unsigned* bitmap = (unsigned*)(ws + OFF_BITMAP);
    float*    stats  = (float*)(ws + OFF_STATS);
    float*    cnt    = (float*)(ws + OFF_CNT);
    unsigned* vh     = (unsigned*)(ws + OFF_VH);
    float*    pooled = (float*)(ws + OFF_POOLED);
    unsigned* pref   = (unsigned*)(ws + OFF_PREF);
    unsigned* bsum   = (unsigned*)(ws + OFF_BSUM);
    unsigned* boff   = (unsigned*)(ws + OFF_BOFF);
    unsigned* Ucnt   = (unsigned*)(ws + OFF_UCNT);
    int*      inv    = (int*)(ws + OFF_INV);
    float*    x1     = (float*)(ws + OFF_X1);
    float*    x2     = (float*)(ws + OFF_X2);
    float*    P1     = (float*)(ws + OFF_X1);
    float*    P2     = pooled;
    // aliases (live only after k_rank):
    int*      csr_j  = (int*)(ws + OFF_CSRJ);
    int*      csr_h  = (int*)(ws + OFF_CSRH);
    unsigned* vstart = (unsigned*)(ws + OFF_VSTART);
    unsigned* vnext  = (unsigned*)(ws + OFF_VNEXT);
    unsigned* vpart  = (unsigned*)(ws + OFF_VPART);
    unsigned* vbsum  = (unsigned*)(ws + OFF_VBSUM);

    hipMemsetAsync(d_ws, 0, ZERO_BYTES, stream);

    k_mark  <<<(N_PREV+255)/256, 256, 0, stream>>>(coors, bitmap);
    k_scanA <<<1024, 1024, 0, stream>>>(bitmap, pref, bsum);
    k_scanB <<<1, 1024, 0, stream>>>(bsum, boff, Ucnt);
    k_rank  <<<N_PREV/4, 256, 0, stream>>>(coors, features, bitmap, pref, boff, inv, cnt, pooled);
    // CSR build (overwrites bitmap/pref regions — safe after k_rank)
    k_vhist <<<(N_FULL+255)/256, 256, 0, stream>>>(scv, vh);
    k_vscanA<<<64, 1024, 0, stream>>>(vh, vpart, vbsum);
    k_vscanB<<<1, 64, 0, stream>>>(vbsum);
    k_vfix  <<<64, 1024, 0, stream>>>(vpart, vbsum, vstart, vnext);
    k_fill  <<<(N_FULL+255)/256, 256, 0, stream>>>(cif, scv, inv, vnext, csr_j, csr_h);
    // MLPs
    k_ppm1 <<<(N_PREV+255)/256, 256, 0, stream>>>(pooled, cnt, Ucnt, W1, b1, x1, stats);
    k_bnfin<<<1, 32, 0, stream>>>(Ucnt, g1, stats, 0);
    k_ppm2 <<<(N_PREV+255)/256, 256, 0, stream>>>(x1, Ucnt, W2, b2, be1, x2, stats);
    k_bnfin<<<1, 32, 0, stream>>>(Ucnt, g2, stats, 128);
    k_ppm3 <<<(N_PREV+127)/128, 256, 0, stream>>>(x2, Ucnt, W3, b3, be2, Wo1, P2, stats);
    k_p1   <<<(N_PREV+127)/128, 256, 0, stream>>>(features, W_in, b_in, Wo1, P1);
    // output stage: gather + accumulate per voxel, fused final GEMM
    k_vox  <<<NVOX/16, 256, 0, stream>>>(vstart, csr_j, csr_h, P1, P2, bo1, Wo2, bo2, (float*)d_out);
}

// Round 3
// 597.507 us; speedup vs baseline: 1.6245x; 1.3959x over previous
//
#include <hip/hip_runtime.h>

#define N_PREV 250000
#define N_FULL 500000
#define NVOX   65536
#define NWORDS (1u<<20)          // bitmap words; keyspace < 2^25 bits
#define EPSF   1e-5f

__device__ __forceinline__ float lrelu(float x){ return x > 0.0f ? x : 0.1f*x; }
__device__ __forceinline__ void fma4(float4& a, float s, const float4 w){
    a.x += s*w.x; a.y += s*w.y; a.z += s*w.z; a.w += s*w.w;
}

// ---------------- ws layout (bytes) ----------------
#define OFF_BITMAP   0ul            // u32[NWORDS] (aliased as csr_j/csr_h after k_rank)
#define OFF_STATS    4194304ul      // f32[256]
#define OFF_CNT      4195328ul      // f32[N_PREV]
#define OFF_VH       5195328ul      // u32[NVOX]
#define OFF_POOLED   5457472ul      // f32[N_PREV*64] (later aliased as P2)
#define ZERO_BYTES   69457472ul
#define OFF_PREF     69457472ul     // u32[NWORDS] (aliased as vstart/vnext/vpart/vbsum)
#define OFF_BSUM     73651776ul
#define OFF_BOFF     73655872ul
#define OFF_UCNT     73659968ul
#define OFF_INV      73660224ul     // i32[N_PREV]
#define OFF_X1       74660224ul     // f32[N_PREV*32] (P1 spans x1+x2)
#define OFF_X2       106660224ul
#define WS_NEEDED    138660224ul
#define OFF_CSRJ     0ul
#define OFF_CSRH     2000000ul
#define OFF_VSTART   69457472ul
#define OFF_VNEXT    (OFF_VSTART+262400ul)
#define OFF_VPART    (OFF_VNEXT+262144ul)
#define OFF_VBSUM    (OFF_VPART+262144ul)

__device__ __forceinline__ int voxel_key(int4 c){
    return ((c.x*501 + (c.y>>1))*501 + (c.z>>1))*31 + (c.w>>1);
}

// ---- mark present keys ----
__global__ void k_mark(const int* __restrict__ coors, unsigned* __restrict__ bitmap){
    int i = blockIdx.x*256 + threadIdx.x;
    if(i >= N_PREV) return;
    int4 c = ((const int4*)coors)[i];
    int key = voxel_key(c);
    atomicOr(&bitmap[key>>5], 1u<<(key&31));
}

__global__ void __launch_bounds__(1024) k_scanA(const unsigned* __restrict__ bitmap,
                                                unsigned* __restrict__ pref,
                                                unsigned* __restrict__ bsum){
    __shared__ unsigned sh[1024];
    int tid = threadIdx.x;
    int w = blockIdx.x*1024 + tid;
    unsigned p = __popc(bitmap[w]);
    sh[tid] = p; __syncthreads();
    for(int off=1; off<1024; off<<=1){
        unsigned v = (tid>=off) ? sh[tid-off] : 0u;
        __syncthreads();
        sh[tid] += v;
        __syncthreads();
    }
    pref[w] = sh[tid] - p;
    if(tid==1023) bsum[blockIdx.x] = sh[tid];
}

__global__ void __launch_bounds__(1024) k_scanB(const unsigned* __restrict__ bsum,
                                                unsigned* __restrict__ boff,
                                                unsigned* __restrict__ Ucnt){
    __shared__ unsigned sh[1024];
    int tid = threadIdx.x;
    unsigned p = bsum[tid];
    sh[tid] = p; __syncthreads();
    for(int off=1; off<1024; off<<=1){
        unsigned v = (tid>=off) ? sh[tid-off] : 0u;
        __syncthreads();
        sh[tid] += v;
        __syncthreads();
    }
    boff[tid] = sh[tid] - p;
    if(tid==1023) Ucnt[0] = sh[tid];
}

__global__ void k_rank(const int* __restrict__ coors, const float* __restrict__ feat,
                       const unsigned* __restrict__ bitmap, const unsigned* __restrict__ pref,
                       const unsigned* __restrict__ boff, int* __restrict__ inv,
                       float* __restrict__ cnt, float* __restrict__ pooled){
    int wave = (blockIdx.x*256 + threadIdx.x) >> 6;
    int lane = threadIdx.x & 63;
    if(wave >= N_PREV) return;
    int4 c = ((const int4*)coors)[wave];
    int key = voxel_key(c);
    int w = key>>5, b = key&31;
    int rank = (int)(boff[w>>10] + pref[w]) + __popc(bitmap[w] & ((1u<<b)-1u));
    if(lane==0){
        inv[wave] = rank;
        atomicAdd(&cnt[rank], 1.0f);
    }
    atomicAdd(&pooled[rank*64 + lane], feat[wave*64 + lane]);
}

// ---- CSR build over scale voxels ----
__global__ void k_vhist(const int* __restrict__ scv, unsigned* __restrict__ vh){
    int p = blockIdx.x*256 + threadIdx.x;
    if(p < N_FULL) atomicAdd(&vh[scv[p]], 1u);
}

__global__ void __launch_bounds__(1024) k_vscanA(const unsigned* __restrict__ vh,
                                                 unsigned* __restrict__ vpart,
                                                 unsigned* __restrict__ vbsum){
    __shared__ unsigned sh[1024];
    int tid = threadIdx.x;
    int w = blockIdx.x*1024 + tid;
    unsigned p = vh[w];
    sh[tid] = p; __syncthreads();
    for(int off=1; off<1024; off<<=1){
        unsigned v = (tid>=off) ? sh[tid-off] : 0u;
        __syncthreads();
        sh[tid] += v;
        __syncthreads();
    }
    vpart[w] = sh[tid] - p;
    if(tid==1023) vbsum[blockIdx.x] = sh[tid];
}

__global__ void k_vscanB(unsigned* __restrict__ vbsum){
    int l = threadIdx.x;
    unsigned v = vbsum[l], orig = v;
    for(int off=1; off<64; off<<=1){
        unsigned o = __shfl_up(v, off);
        if(l>=off) v += o;
    }
    vbsum[l] = v - orig;
}

__global__ void __launch_bounds__(1024) k_vfix(const unsigned* __restrict__ vpart,
                                               const unsigned* __restrict__ vbsum,
                                               unsigned* __restrict__ vstart,
                                               unsigned* __restrict__ vnext){
    int w = blockIdx.x*1024 + threadIdx.x;
    unsigned s = vpart[w] + vbsum[w>>10];
    vstart[w] = s; vnext[w] = s;
    if(w == NVOX-1) vstart[NVOX] = N_FULL;
}

__global__ void k_fill(const int* __restrict__ cif, const int* __restrict__ scv,
                       const int* __restrict__ inv, unsigned* __restrict__ vnext,
                       int* __restrict__ csr_j, int* __restrict__ csr_h){
    int p = blockIdx.x*256 + threadIdx.x;
    if(p >= N_FULL) return;
    int jp = cif[p];
    unsigned pos = atomicAdd(&vnext[scv[p]], 1u);
    csr_j[pos] = jp;
    csr_h[pos] = inv[jp];
}

// ---- P1 = lrelu(features @ W_in + b_in) @ Wo1a   [N_PREV,64] ----
// 64x64 tile/block, 4x4 register blocking, b128 LDS reads, in-place intermediate
__global__ void __launch_bounds__(256) k_p1(const float* __restrict__ feat,
        const float* __restrict__ Win, const float* __restrict__ bin,
        const float* __restrict__ Wo1, float* __restrict__ P1){
    __shared__ float wsh[4096];
    __shared__ float w2sh[4096];
    __shared__ float bsh[64];
    __shared__ float fsh[64][68];
    int tid = threadIdx.x;
    for(int q=tid; q<4096; q+=256){ wsh[q]=Win[q]; w2sh[q]=Wo1[q]; }
    if(tid<64) bsh[tid]=bin[tid];
    int ri = tid>>4, ci = tid&15;
    const int NT = (N_PREV+63)/64;
    for(int tile=blockIdx.x; tile<NT; tile+=gridDim.x){
        int base = tile*64;
        __syncthreads();
        for(int q=tid; q<1024; q+=256){
            int rr=q>>4, c4=q&15; int row=base+rr;
            float4 v = (row<N_PREV) ? ((const float4*)feat)[row*16+c4]
                                    : make_float4(0.f,0.f,0.f,0.f);
            *(float4*)&fsh[rr][c4*4] = v;
        }
        __syncthreads();
        float4 acc[4];
        #pragma unroll
        for(int r=0;r<4;++r) acc[r]=make_float4(0.f,0.f,0.f,0.f);
        #pragma unroll
        for(int kc=0;kc<16;++kc){
            float4 a0 = *(const float4*)&fsh[4*ri+0][kc*4];
            float4 a1 = *(const float4*)&fsh[4*ri+1][kc*4];
            float4 a2 = *(const float4*)&fsh[4*ri+2][kc*4];
            float4 a3 = *(const float4*)&fsh[4*ri+3][kc*4];
            float4 w0 = *(const float4*)&wsh[(4*kc+0)*64+4*ci];
            float4 w1 = *(const float4*)&wsh[(4*kc+1)*64+4*ci];
            float4 w2 = *(const float4*)&wsh[(4*kc+2)*64+4*ci];
            float4 w3 = *(const float4*)&wsh[(4*kc+3)*64+4*ci];
            fma4(acc[0],a0.x,w0); fma4(acc[0],a0.y,w1); fma4(acc[0],a0.z,w2); fma4(acc[0],a0.w,w3);
            fma4(acc[1],a1.x,w0); fma4(acc[1],a1.y,w1); fma4(acc[1],a1.z,w2); fma4(acc[1],a1.w,w3);
            fma4(acc[2],a2.x,w0); fma4(acc[2],a2.y,w1); fma4(acc[2],a2.z,w2); fma4(acc[2],a2.w,w3);
            fma4(acc[3],a3.x,w0); fma4(acc[3],a3.y,w1); fma4(acc[3],a3.z,w2); fma4(acc[3],a3.w,w3);
        }
        __syncthreads();
        float4 bb = *(const float4*)&bsh[4*ci];
        #pragma unroll
        for(int r=0;r<4;++r){
            float4 v = acc[r];
            v.x = lrelu(v.x+bb.x); v.y = lrelu(v.y+bb.y);
            v.z = lrelu(v.z+bb.z); v.w = lrelu(v.w+bb.w);
            *(float4*)&fsh[4*ri+r][4*ci] = v;
        }
        __syncthreads();
        float4 acc2[4];
        #pragma unroll
        for(int r=0;r<4;++r) acc2[r]=make_float4(0.f,0.f,0.f,0.f);
        #pragma unroll
        for(int kc=0;kc<16;++kc){
            float4 a0 = *(const float4*)&fsh[4*ri+0][kc*4];
            float4 a1 = *(const float4*)&fsh[4*ri+1][kc*4];
            float4 a2 = *(const float4*)&fsh[4*ri+2][kc*4];
            float4 a3 = *(const float4*)&fsh[4*ri+3][kc*4];
            float4 w0 = *(const float4*)&w2sh[(4*kc+0)*64+4*ci];
            float4 w1 = *(const float4*)&w2sh[(4*kc+1)*64+4*ci];
            float4 w2 = *(const float4*)&w2sh[(4*kc+2)*64+4*ci];
            float4 w3 = *(const float4*)&w2sh[(4*kc+3)*64+4*ci];
            fma4(acc2[0],a0.x,w0); fma4(acc2[0],a0.y,w1); fma4(acc2[0],a0.z,w2); fma4(acc2[0],a0.w,w3);
            fma4(acc2[1],a1.x,w0); fma4(acc2[1],a1.y,w1); fma4(acc2[1],a1.z,w2); fma4(acc2[1],a1.w,w3);
            fma4(acc2[2],a2.x,w0); fma4(acc2[2],a2.y,w1); fma4(acc2[2],a2.z,w2); fma4(acc2[2],a2.w,w3);
            fma4(acc2[3],a3.x,w0); fma4(acc2[3],a3.y,w1); fma4(acc2[3],a3.z,w2); fma4(acc2[3],a3.w,w3);
        }
        #pragma unroll
        for(int r=0;r<4;++r){
            int row = base + 4*ri + r;
            if(row<N_PREV) ((float4*)P1)[row*16+ci] = acc2[r];
        }
    }
}

// ---- x1 = lrelu((pooled@W1)/cnt + b1), BN1 stats.  64x32 tile, 2x4 blocking ----
__global__ void __launch_bounds__(256) k_ppm1(const float* __restrict__ pooled,
        const float* __restrict__ cnt, const unsigned* __restrict__ Ucnt,
        const float* __restrict__ W1, const float* __restrict__ b1,
        float* __restrict__ x1, float* __restrict__ stats){
    __shared__ float wsh[2048];
    __shared__ float b1sh[32];
    __shared__ float rsh[64];
    __shared__ float fsh[64][68];
    int tid = threadIdx.x;
    for(int q=tid; q<2048; q+=256) wsh[q]=W1[q];
    if(tid<32) b1sh[tid]=b1[tid];
    int U = (int)Ucnt[0];
    int rg = tid>>3, ci = tid&7;
    float4 s4=make_float4(0.f,0.f,0.f,0.f), q4=make_float4(0.f,0.f,0.f,0.f);
    const int NT = (N_PREV+63)/64;
    for(int tile=blockIdx.x; tile<NT; tile+=gridDim.x){
        int base = tile*64;
        if(base>=U) break;
        __syncthreads();
        for(int q=tid; q<1024; q+=256){
            int rr=q>>4, c4=q&15; int row=base+rr;
            float4 v = (row<U) ? ((const float4*)pooled)[row*16+c4]
                               : make_float4(0.f,0.f,0.f,0.f);
            *(float4*)&fsh[rr][c4*4] = v;
        }
        if(tid<64){ int row=base+tid; rsh[tid] = (row<U) ? 1.0f/cnt[row] : 0.f; }
        __syncthreads();
        float4 acc[2];
        acc[0]=make_float4(0.f,0.f,0.f,0.f); acc[1]=make_float4(0.f,0.f,0.f,0.f);
        #pragma unroll
        for(int kc=0;kc<16;++kc){
            float4 a0 = *(const float4*)&fsh[2*rg+0][kc*4];
            float4 a1 = *(const float4*)&fsh[2*rg+1][kc*4];
            float4 w0 = *(const float4*)&wsh[(4*kc+0)*32+4*ci];
            float4 w1 = *(const float4*)&wsh[(4*kc+1)*32+4*ci];
            float4 w2 = *(const float4*)&wsh[(4*kc+2)*32+4*ci];
            float4 w3 = *(const float4*)&wsh[(4*kc+3)*32+4*ci];
            fma4(acc[0],a0.x,w0); fma4(acc[0],a0.y,w1); fma4(acc[0],a0.z,w2); fma4(acc[0],a0.w,w3);
            fma4(acc[1],a1.x,w0); fma4(acc[1],a1.y,w1); fma4(acc[1],a1.z,w2); fma4(acc[1],a1.w,w3);
        }
        float4 bb = *(const float4*)&b1sh[4*ci];
        #pragma unroll
        for(int r=0;r<2;++r){
            int row = base + 2*rg + r;
            if(row<U){
                float rv = rsh[2*rg+r];
                float4 v;
                v.x = lrelu(acc[r].x*rv + bb.x);
                v.y = lrelu(acc[r].y*rv + bb.y);
                v.z = lrelu(acc[r].z*rv + bb.z);
                v.w = lrelu(acc[r].w*rv + bb.w);
                ((float4*)x1)[row*8+ci] = v;
                s4.x+=v.x; s4.y+=v.y; s4.z+=v.z; s4.w+=v.w;
                q4.x+=v.x*v.x; q4.y+=v.y*v.y; q4.z+=v.z*v.z; q4.w+=v.w*v.w;
            }
        }
    }
    __syncthreads();
    float* red = &fsh[0][0];
    red[rg*33+4*ci+0]=s4.x; red[rg*33+4*ci+1]=s4.y;
    red[rg*33+4*ci+2]=s4.z; red[rg*33+4*ci+3]=s4.w;
    __syncthreads();
    if(tid<32){ float t=0.f; for(int g=0;g<32;++g) t+=red[g*33+tid]; atomicAdd(&stats[tid], t); }
    __syncthreads();
    red[rg*33+4*ci+0]=q4.x; red[rg*33+4*ci+1]=q4.y;
    red[rg*33+4*ci+2]=q4.z; red[rg*33+4*ci+3]=q4.w;
    __syncthreads();
    if(tid<32){ float t=0.f; for(int g=0;g<32;++g) t+=red[g*33+tid]; atomicAdd(&stats[32+tid], t); }
}

__global__ void k_bnfin(const unsigned* __restrict__ Ucnt, const float* __restrict__ g,
                        float* __restrict__ stats, int off){
    int c = threadIdx.x;
    if(c>=32) return;
    float n = (float)max(Ucnt[0], 1u);
    float mu = stats[off+c]/n;
    float var = stats[off+32+c]/n - mu*mu;
    stats[off+64+c] = mu;
    stats[off+96+c] = g[c]*rsqrtf(var + EPSF);
}

// ---- x2 = lrelu(BN1(x1) @ W2 + b2), BN2 stats.  64x32 tile, 2x4 blocking ----
__global__ void __launch_bounds__(256) k_ppm2(const float* __restrict__ x1,
        const unsigned* __restrict__ Ucnt, const float* __restrict__ W2,
        const float* __restrict__ b2, const float* __restrict__ be1,
        float* __restrict__ x2, float* __restrict__ stats){
    __shared__ float wsh[1024];
    __shared__ float bsh[32], ash[32], bbsh[32];
    __shared__ float fsh[64][36];
    __shared__ float red[32*33];
    int tid = threadIdx.x;
    for(int q=tid; q<1024; q+=256) wsh[q]=W2[q];
    if(tid<32){
        bsh[tid]=b2[tid];
        float mu=stats[64+tid], sc=stats[96+tid];
        ash[tid]=sc; bbsh[tid]=be1[tid]-mu*sc;
    }
    int U = (int)Ucnt[0];
    int rg = tid>>3, ci = tid&7;
    float4 s4=make_float4(0.f,0.f,0.f,0.f), q4=make_float4(0.f,0.f,0.f,0.f);
    const int NT = (N_PREV+63)/64;
    for(int tile=blockIdx.x; tile<NT; tile+=gridDim.x){
        int base = tile*64;
        if(base>=U) break;
        __syncthreads();
        for(int q=tid; q<512; q+=256){
            int rr=q>>3, c4=q&7; int row=base+rr;
            float4 v = (row<U) ? ((const float4*)x1)[row*8+c4]
                               : make_float4(0.f,0.f,0.f,0.f);
            float4 aa = *(const float4*)&ash[4*c4];
            float4 bb = *(const float4*)&bbsh[4*c4];
            v.x=v.x*aa.x+bb.x; v.y=v.y*aa.y+bb.y; v.z=v.z*aa.z+bb.z; v.w=v.w*aa.w+bb.w;
            *(float4*)&fsh[rr][c4*4] = v;
        }
        __syncthreads();
        float4 acc[2];
        acc[0]=make_float4(0.f,0.f,0.f,0.f); acc[1]=make_float4(0.f,0.f,0.f,0.f);
        #pragma unroll
        for(int kc=0;kc<8;++kc){
            float4 a0 = *(const float4*)&fsh[2*rg+0][kc*4];
            float4 a1 = *(const float4*)&fsh[2*rg+1][kc*4];
            float4 w0 = *(const float4*)&wsh[(4*kc+0)*32+4*ci];
            float4 w1 = *(const float4*)&wsh[(4*kc+1)*32+4*ci];
            float4 w2 = *(const float4*)&wsh[(4*kc+2)*32+4*ci];
            float4 w3 = *(const float4*)&wsh[(4*kc+3)*32+4*ci];
            fma4(acc[0],a0.x,w0); fma4(acc[0],a0.y,w1); fma4(acc[0],a0.z,w2); fma4(acc[0],a0.w,w3);
            fma4(acc[1],a1.x,w0); fma4(acc[1],a1.y,w1); fma4(acc[1],a1.z,w2); fma4(acc[1],a1.w,w3);
        }
        float4 bb = *(const float4*)&bsh[4*ci];
        #pragma unroll
        for(int r=0;r<2;++r){
            int row = base + 2*rg + r;
            if(row<U){
                float4 v;
                v.x = lrelu(acc[r].x + bb.x);
                v.y = lrelu(acc[r].y + bb.y);
                v.z = lrelu(acc[r].z + bb.z);
                v.w = lrelu(acc[r].w + bb.w);
                ((float4*)x2)[row*8+ci] = v;
                s4.x+=v.x; s4.y+=v.y; s4.z+=v.z; s4.w+=v.w;
                q4.x+=v.x*v.x; q4.y+=v.y*v.y; q4.z+=v.z*v.z; q4.w+=v.w*v.w;
            }
        }
    }
    __syncthreads();
    red[rg*33+4*ci+0]=s4.x; red[rg*33+4*ci+1]=s4.y;
    red[rg*33+4*ci+2]=s4.z; red[rg*33+4*ci+3]=s4.w;
    __syncthreads();
    if(tid<32){ float t=0.f; for(int g=0;g<32;++g) t+=red[g*33+tid]; atomicAdd(&stats[128+tid], t); }
    __syncthreads();
    red[rg*33+4*ci+0]=q4.x; red[rg*33+4*ci+1]=q4.y;
    red[rg*33+4*ci+2]=q4.z; red[rg*33+4*ci+3]=q4.w;
    __syncthreads();
    if(tid<32){ float t=0.f; for(int g=0;g<32;++g) t+=red[g*33+tid]; atomicAdd(&stats[160+tid], t); }
}

// ---- P2 = lrelu(BN2(x2) @ W3 + b3) @ Wo1b  [U,64].  64-row tile, 4x4 blocking ----
__global__ void __launch_bounds__(256) k_ppm3(const float* __restrict__ x2,
        const unsigned* __restrict__ Ucnt, const float* __restrict__ W3,
        const float* __restrict__ b3, const float* __restrict__ be2,
        const float* __restrict__ Wo1, float* __restrict__ P2,
        const float* __restrict__ stats){
    __shared__ float w3sh[2048];
    __shared__ float w2sh[4096];
    __shared__ float b3sh[64], ash[32], bbsh[32];
    __shared__ float fsh[64][36];
    __shared__ float ish[64][68];
    int tid = threadIdx.x;
    for(int q=tid; q<2048; q+=256) w3sh[q]=W3[q];
    for(int q=tid; q<4096; q+=256) w2sh[q]=Wo1[4096+q];
    if(tid<64) b3sh[tid]=b3[tid];
    if(tid<32){
        float mu=stats[192+tid], sc=stats[224+tid];
        ash[tid]=sc; bbsh[tid]=be2[tid]-mu*sc;
    }
    int U = (int)Ucnt[0];
    int ri = tid>>4, ci = tid&15;
    const int NT = (N_PREV+63)/64;
    for(int tile=blockIdx.x; tile<NT; tile+=gridDim.x){
        int base = tile*64;
        if(base>=U) break;
        __syncthreads();
        for(int q=tid; q<512; q+=256){
            int rr=q>>3, c4=q&7; int row=base+rr;
            float4 v = (row<U) ? ((const float4*)x2)[row*8+c4]
                               : make_float4(0.f,0.f,0.f,0.f);
            float4 aa = *(const float4*)&ash[4*c4];
            float4 bb = *(const float4*)&bbsh[4*c4];
            v.x=v.x*aa.x+bb.x; v.y=v.y*aa.y+bb.y; v.z=v.z*aa.z+bb.z; v.w=v.w*aa.w+bb.w;
            *(float4*)&fsh[rr][c4*4] = v;
        }
        __syncthreads();
        float4 acc[4];
        #pragma unroll
        for(int r=0;r<4;++r) acc[r]=make_float4(0.f,0.f,0.f,0.f);
        #pragma unroll
        for(int kc=0;kc<8;++kc){
            float4 a0 = *(const float4*)&fsh[4*ri+0][kc*4];
            float4 a1 = *(const float4*)&fsh[4*ri+1][kc*4];
            float4 a2 = *(const float4*)&fsh[4*ri+2][kc*4];
            float4 a3 = *(const float4*)&fsh[4*ri+3][kc*4];
            float4 w0 = *(const float4*)&w3sh[(4*kc+0)*64+4*ci];
            float4 w1 = *(const float4*)&w3sh[(4*kc+1)*64+4*ci];
            float4 w2 = *(const float4*)&w3sh[(4*kc+2)*64+4*ci];
            float4 w3_ = *(const float4*)&w3sh[(4*kc+3)*64+4*ci];
            fma4(acc[0],a0.x,w0); fma4(acc[0],a0.y,w1); fma4(acc[0],a0.z,w2); fma4(acc[0],a0.w,w3_);
            fma4(acc[1],a1.x,w0); fma4(acc[1],a1.y,w1); fma4(acc[1],a1.z,w2); fma4(acc[1],a1.w,w3_);
            fma4(acc[2],a2.x,w0); fma4(acc[2],a2.y,w1); fma4(acc[2],a2.z,w2); fma4(acc[2],a2.w,w3_);
            fma4(acc[3],a3.x,w0); fma4(acc[3],a3.y,w1); fma4(acc[3],a3.z,w2); fma4(acc[3],a3.w,w3_);
        }
        float4 bb = *(const float4*)&b3sh[4*ci];
        #pragma unroll
        for(int r=0;r<4;++r){
            float4 v = acc[r];
            v.x = lrelu(v.x+bb.x); v.y = lrelu(v.y+bb.y);
            v.z = lrelu(v.z+bb.z); v.w = lrelu(v.w+bb.w);
            *(float4*)&ish[4*ri+r][4*ci] = v;
        }
        __syncthreads();
        float4 acc2[4];
        #pragma unroll
        for(int r=0;r<4;++r) acc2[r]=make_float4(0.f,0.f,0.f,0.f);
        #pragma unroll
        for(int kc=0;kc<16;++kc){
            float4 a0 = *(const float4*)&ish[4*ri+0][kc*4];
            float4 a1 = *(const float4*)&ish[4*ri+1][kc*4];
            float4 a2 = *(const float4*)&ish[4*ri+2][kc*4];
            float4 a3 = *(const float4*)&ish[4*ri+3][kc*4];
            float4 w0 = *(const float4*)&w2sh[(4*kc+0)*64+4*ci];
            float4 w1 = *(const float4*)&w2sh[(4*kc+1)*64+4*ci];
            float4 w2 = *(const float4*)&w2sh[(4*kc+2)*64+4*ci];
            float4 w3_ = *(const float4*)&w2sh[(4*kc+3)*64+4*ci];
            fma4(acc2[0],a0.x,w0); fma4(acc2[0],a0.y,w1); fma4(acc2[0],a0.z,w2); fma4(acc2[0],a0.w,w3_);
            fma4(acc2[1],a1.x,w0); fma4(acc2[1],a1.y,w1); fma4(acc2[1],a1.z,w2); fma4(acc2[1],a1.w,w3_);
            fma4(acc2[2],a2.x,w0); fma4(acc2[2],a2.y,w1); fma4(acc2[2],a2.z,w2); fma4(acc2[2],a2.w,w3_);
            fma4(acc2[3],a3.x,w0); fma4(acc2[3],a3.y,w1); fma4(acc2[3],a3.z,w2); fma4(acc2[3],a3.w,w3_);
        }
        #pragma unroll
        for(int r=0;r<4;++r){
            int row = base + 4*ri + r;
            if(row<U) ((float4*)P2)[row*16+ci] = acc2[r];
        }
    }
}

// ---- one wave per voxel: T = Σ lrelu(P1[j]+P2[h]+bo1); out = (T@Wo2 + cnt*bo2)/max(cnt,1) ----
__global__ void __launch_bounds__(256) k_vox(const unsigned* __restrict__ vstart,
        const int* __restrict__ csr_j, const int* __restrict__ csr_h,
        const float* __restrict__ P1, const float* __restrict__ P2,
        const float* __restrict__ bo1, const float* __restrict__ Wo2,
        const float* __restrict__ bo2, float* __restrict__ out){
    __shared__ float tsh[4][64];
    int tid = threadIdx.x;
    int wib = tid>>6, lane = tid&63;
    float wreg[64];
    #pragma unroll
    for(int k=0;k<64;++k) wreg[k] = Wo2[k*64+lane];
    float b1 = bo1[lane], b2 = bo2[lane];
    int wglobal = blockIdx.x*4 + wib;
    for(int vq=0; vq<4; ++vq){
        int vox = wglobal*4 + vq;
        int s = (int)vstart[vox], e = (int)vstart[vox+1];
        float acc = 0.f;
        for(int i=s; i<e; i+=64){
            int n = min(e-i, 64);
            int jv=0, hv=0;
            if(lane<n){ jv = csr_j[i+lane]; hv = csr_h[i+lane]; }
            for(int q=0;q<n;++q){
                int j = __shfl(jv,q), h = __shfl(hv,q);
                float g = P1[j*64+lane] + P2[h*64+lane] + b1;
                acc += (g>0.f) ? g : 0.1f*g;
            }
        }
        tsh[wib][lane] = acc;
        float dot = 0.f;
        const float4* t4 = (const float4*)tsh[wib];
        #pragma unroll
        for(int k4=0;k4<16;++k4){
            float4 t = t4[k4];
            dot += t.x*wreg[4*k4] + t.y*wreg[4*k4+1] + t.z*wreg[4*k4+2] + t.w*wreg[4*k4+3];
        }
        float cntv = (float)(e - s);
        out[vox*64+lane] = (dot + cntv*b2) / fmaxf(cntv, 1.f);
    }
}

extern "C" void kernel_launch(void* const* d_in, const int* in_sizes, int n_in,
                              void* d_out, int out_size, void* d_ws, size_t ws_size,
                              hipStream_t stream) {
    if(ws_size < WS_NEEDED) return;

    const float* features = (const float*)d_in[0];
    const int*   coors    = (const int*)d_in[1];
    const int*   cif      = (const int*)d_in[2];
    const int*   scv      = (const int*)d_in[3];
    const float* W_in     = (const float*)d_in[4];
    const float* b_in     = (const float*)d_in[5];
    const float* W1       = (const float*)d_in[6];
    const float* b1       = (const float*)d_in[7];
    const float* g1       = (const float*)d_in[8];
    const float* be1      = (const float*)d_in[9];
    const float* W2       = (const float*)d_in[10];
    const float* b2       = (const float*)d_in[11];
    const float* g2       = (const float*)d_in[12];
    const float* be2      = (const float*)d_in[13];
    const float* W3       = (const float*)d_in[14];
    const float* b3       = (const float*)d_in[15];
    const float* Wo1      = (const float*)d_in[16];
    const float* bo1      = (const float*)d_in[17];
    const float* Wo2      = (const float*)d_in[18];
    const float* bo2      = (const float*)d_in[19];

    char* ws = (char*)d_ws;
    unsigned* bitmap = (unsigned*)(ws + OFF_BITMAP);
    float*    stats  = (float*)(ws + OFF_STATS);
    float*    cnt    = (float*)(ws + OFF_CNT);
    unsigned* vh     = (unsigned*)(ws + OFF_VH);
    float*    pooled = (float*)(ws + OFF_POOLED);
    unsigned* pref   = (unsigned*)(ws + OFF_PREF);
    unsigned* bsum   = (unsigned*)(ws + OFF_BSUM);
    unsigned* boff   = (unsigned*)(ws + OFF_BOFF);
    unsigned* Ucnt   = (unsigned*)(ws + OFF_UCNT);
    float*    x1     = (float*)(ws + OFF_X1);
    float*    x2     = (float*)(ws + OFF_X2);
    int*      inv    = (int*)(ws + OFF_INV);
    float*    P1     = (float*)(ws + OFF_X1);
    float*    P2     = pooled;
    int*      csr_j  = (int*)(ws + OFF_CSRJ);
    int*      csr_h  = (int*)(ws + OFF_CSRH);
    unsigned* vstart = (unsigned*)(ws + OFF_VSTART);
    unsigned* vnext  = (unsigned*)(ws + OFF_VNEXT);
    unsigned* vpart  = (unsigned*)(ws + OFF_VPART);
    unsigned* vbsum  = (unsigned*)(ws + OFF_VBSUM);

    hipMemsetAsync(d_ws, 0, ZERO_BYTES, stream);

    k_mark  <<<(N_PREV+255)/256, 256, 0, stream>>>(coors, bitmap);
    k_scanA <<<1024, 1024, 0, stream>>>(bitmap, pref, bsum);
    k_scanB <<<1, 1024, 0, stream>>>(bsum, boff, Ucnt);
    k_rank  <<<N_PREV/4, 256, 0, stream>>>(coors, features, bitmap, pref, boff, inv, cnt, pooled);
    k_vhist <<<(N_FULL+255)/256, 256, 0, stream>>>(scv, vh);
    k_vscanA<<<64, 1024, 0, stream>>>(vh, vpart, vbsum);
    k_vscanB<<<1, 64, 0, stream>>>(vbsum);
    k_vfix  <<<64, 1024, 0, stream>>>(vpart, vbsum, vstart, vnext);
    k_fill  <<<(N_FULL+255)/256, 256, 0, stream>>>(cif, scv, inv, vnext, csr_j, csr_h);
    k_ppm1 <<<1024, 256, 0, stream>>>(pooled, cnt, Ucnt, W1, b1, x1, stats);
    k_bnfin<<<1, 32, 0, stream>>>(Ucnt, g1, stats, 0);
    k_ppm2 <<<1024, 256, 0, stream>>>(x1, Ucnt, W2, b2, be1, x2, stats);
    k_bnfin<<<1, 32, 0, stream>>>(Ucnt, g2, stats, 128);
    k_ppm3 <<<1024, 256, 0, stream>>>(x2, Ucnt, W3, b3, be2, Wo1, P2, stats);
    k_p1   <<<1024, 256, 0, stream>>>(features, W_in, b_in, Wo1, P1);
    k_vox  <<<NVOX/16, 256, 0, stream>>>(vstart, csr_j, csr_h, P1, P2, bo1, Wo2, bo2, (float*)d_out);
}

// Round 4
// 497.761 us; speedup vs baseline: 1.9500x; 1.2004x over previous
//
#include <hip/hip_runtime.h>

#define N_PREV 250000
#define N_FULL 500000
#define NVOX   65536
#define NWORDS (1u<<20)          // bitmap words; keyspace < 2^25 bits
#define EPSF   1e-5f

typedef __attribute__((ext_vector_type(4)))  short short4v;
typedef __attribute__((ext_vector_type(8)))  short short8v;
typedef __attribute__((ext_vector_type(16))) float f32x16;

__device__ __forceinline__ float lrelu(float x){ return x > 0.0f ? x : 0.1f*x; }
__device__ __forceinline__ void fma4(float4& a, float s, const float4 w){
    a.x += s*w.x; a.y += s*w.y; a.z += s*w.z; a.w += s*w.w;
}
__device__ __forceinline__ short f2bf_rne(float v){
    unsigned u = __float_as_uint(v);
    unsigned r = (u + 0x7fffu + ((u>>16)&1u)) >> 16;
    return (short)r;
}
__device__ __forceinline__ float bf2f(short s){
    return __uint_as_float(((unsigned)(unsigned short)s) << 16);
}

// ---------------- ws layout (bytes) ----------------
#define OFF_BITMAP   0ul            // u32[NWORDS] (aliased as csr_j/csr_h after k_rank)
#define OFF_STATS    4194304ul      // f32[256]
#define OFF_CNT      4195328ul      // f32[N_PREV]
#define OFF_VH       5195328ul      // u32[NVOX]
#define OFF_POOLED   5457472ul      // f32[N_PREV*64] (later aliased as P2)
#define ZERO_BYTES   69457472ul
#define OFF_PREF     69457472ul     // u32[NWORDS] (aliased as vstart/vnext/vpart/vbsum)
#define OFF_BSUM     73651776ul
#define OFF_BOFF     73655872ul
#define OFF_UCNT     73659968ul
#define OFF_INV      73660224ul     // i32[N_PREV]
#define OFF_X1       74660224ul     // f32[N_PREV*32] (P1 spans x1+x2)
#define OFF_X2       106660224ul
#define WS_NEEDED    138660224ul
#define OFF_CSRJ     0ul
#define OFF_CSRH     2000000ul
#define OFF_VSTART   69457472ul
#define OFF_VNEXT    (OFF_VSTART+262400ul)
#define OFF_VPART    (OFF_VNEXT+262144ul)
#define OFF_VBSUM    (OFF_VPART+262144ul)

__device__ __forceinline__ int voxel_key(int4 c){
    return ((c.x*501 + (c.y>>1))*501 + (c.z>>1))*31 + (c.w>>1);
}

// ---- mark present keys ----
__global__ void k_mark(const int* __restrict__ coors, unsigned* __restrict__ bitmap){
    int i = blockIdx.x*256 + threadIdx.x;
    if(i >= N_PREV) return;
    int4 c = ((const int4*)coors)[i];
    int key = voxel_key(c);
    atomicOr(&bitmap[key>>5], 1u<<(key&31));
}

__global__ void __launch_bounds__(1024) k_scanA(const unsigned* __restrict__ bitmap,
                                                unsigned* __restrict__ pref,
                                                unsigned* __restrict__ bsum){
    __shared__ unsigned sh[1024];
    int tid = threadIdx.x;
    int w = blockIdx.x*1024 + tid;
    unsigned p = __popc(bitmap[w]);
    sh[tid] = p; __syncthreads();
    for(int off=1; off<1024; off<<=1){
        unsigned v = (tid>=off) ? sh[tid-off] : 0u;
        __syncthreads();
        sh[tid] += v;
        __syncthreads();
    }
    pref[w] = sh[tid] - p;
    if(tid==1023) bsum[blockIdx.x] = sh[tid];
}

__global__ void __launch_bounds__(1024) k_scanB(const unsigned* __restrict__ bsum,
                                                unsigned* __restrict__ boff,
                                                unsigned* __restrict__ Ucnt){
    __shared__ unsigned sh[1024];
    int tid = threadIdx.x;
    unsigned p = bsum[tid];
    sh[tid] = p; __syncthreads();
    for(int off=1; off<1024; off<<=1){
        unsigned v = (tid>=off) ? sh[tid-off] : 0u;
        __syncthreads();
        sh[tid] += v;
        __syncthreads();
    }
    boff[tid] = sh[tid] - p;
    if(tid==1023) Ucnt[0] = sh[tid];
}

__global__ void k_rank(const int* __restrict__ coors, const float* __restrict__ feat,
                       const unsigned* __restrict__ bitmap, const unsigned* __restrict__ pref,
                       const unsigned* __restrict__ boff, int* __restrict__ inv,
                       float* __restrict__ cnt, float* __restrict__ pooled){
    int wave = (blockIdx.x*256 + threadIdx.x) >> 6;
    int lane = threadIdx.x & 63;
    if(wave >= N_PREV) return;
    int4 c = ((const int4*)coors)[wave];
    int key = voxel_key(c);
    int w = key>>5, b = key&31;
    int rank = (int)(boff[w>>10] + pref[w]) + __popc(bitmap[w] & ((1u<<b)-1u));
    if(lane==0){
        inv[wave] = rank;
        atomicAdd(&cnt[rank], 1.0f);
    }
    atomicAdd(&pooled[rank*64 + lane], feat[wave*64 + lane]);
}

// ---- CSR build over scale voxels ----
__global__ void k_vhist(const int* __restrict__ scv, unsigned* __restrict__ vh){
    int p = blockIdx.x*256 + threadIdx.x;
    if(p < N_FULL) atomicAdd(&vh[scv[p]], 1u);
}

__global__ void __launch_bounds__(1024) k_vscanA(const unsigned* __restrict__ vh,
                                                 unsigned* __restrict__ vpart,
                                                 unsigned* __restrict__ vbsum){
    __shared__ unsigned sh[1024];
    int tid = threadIdx.x;
    int w = blockIdx.x*1024 + tid;
    unsigned p = vh[w];
    sh[tid] = p; __syncthreads();
    for(int off=1; off<1024; off<<=1){
        unsigned v = (tid>=off) ? sh[tid-off] : 0u;
        __syncthreads();
        sh[tid] += v;
        __syncthreads();
    }
    vpart[w] = sh[tid] - p;
    if(tid==1023) vbsum[blockIdx.x] = sh[tid];
}

__global__ void k_vscanB(unsigned* __restrict__ vbsum){
    int l = threadIdx.x;
    unsigned v = vbsum[l], orig = v;
    for(int off=1; off<64; off<<=1){
        unsigned o = __shfl_up(v, off);
        if(l>=off) v += o;
    }
    vbsum[l] = v - orig;
}

__global__ void __launch_bounds__(1024) k_vfix(const unsigned* __restrict__ vpart,
                                               const unsigned* __restrict__ vbsum,
                                               unsigned* __restrict__ vstart,
                                               unsigned* __restrict__ vnext){
    int w = blockIdx.x*1024 + threadIdx.x;
    unsigned s = vpart[w] + vbsum[w>>10];
    vstart[w] = s; vnext[w] = s;
    if(w == NVOX-1) vstart[NVOX] = N_FULL;
}

__global__ void k_fill(const int* __restrict__ cif, const int* __restrict__ scv,
                       const int* __restrict__ inv, unsigned* __restrict__ vnext,
                       int* __restrict__ csr_j, int* __restrict__ csr_h){
    int p = blockIdx.x*256 + threadIdx.x;
    if(p >= N_FULL) return;
    int jp = cif[p];
    unsigned pos = atomicAdd(&vnext[scv[p]], 1u);
    csr_j[pos] = jp;
    csr_h[pos] = inv[jp];
}

// ---- P1 = lrelu(features @ W_in + b_in) @ Wo1a   [N_PREV,64] ----
// MFMA 32x32x16 bf16, split hi/lo (3-pass) for f32-grade accuracy.
// Block: 256 thr = 4 waves; tile 64 rows x 64 cols; wave (rowhalf, colhalf).
// Weights hoisted to registers (frags tile-invariant); LDS holds A-tiles only.
__global__ void __launch_bounds__(256) k_p1(const float* __restrict__ feat,
        const float* __restrict__ Win, const float* __restrict__ bin,
        const float* __restrict__ Wo1, float* __restrict__ P1){
    __shared__ __align__(16) short Ah[64*68];
    __shared__ __align__(16) short Al[64*68];
    int tid = threadIdx.x;
    int wave = tid >> 6, l = tid & 63;
    int g = l >> 5, c = l & 31;
    int rowhalf = (wave >> 1) * 32, colhalf = (wave & 1) * 32;

    // ---- stage Win^T (hi/lo) as [col][k], then hoist this wave's B-frags ----
    {
        int col = tid >> 2, kseg = (tid & 3) * 16;
        short hi[16], lo[16];
        #pragma unroll
        for(int j=0;j<16;++j){
            float v = Win[(kseg+j)*64 + col];
            short h = f2bf_rne(v);
            hi[j] = h; lo[j] = f2bf_rne(v - bf2f(h));
        }
        #pragma unroll
        for(int i=0;i<4;++i){
            *(short4v*)&Ah[col*68 + kseg + 4*i] = *(short4v*)&hi[4*i];
            *(short4v*)&Al[col*68 + kseg + 4*i] = *(short4v*)&lo[4*i];
        }
    }
    __syncthreads();
    short8v w1h[4], w1l[4];
    #pragma unroll
    for(int s=0;s<4;++s){
        int base = (colhalf + c)*68 + s*16 + g*4;
        ((short4v*)&w1h[s])[0] = *(short4v*)&Ah[base];
        ((short4v*)&w1h[s])[1] = *(short4v*)&Ah[base + 8];
        ((short4v*)&w1l[s])[0] = *(short4v*)&Al[base];
        ((short4v*)&w1l[s])[1] = *(short4v*)&Al[base + 8];
    }
    __syncthreads();
    // ---- stage Wo1a^T, hoist ----
    {
        int col = tid >> 2, kseg = (tid & 3) * 16;
        short hi[16], lo[16];
        #pragma unroll
        for(int j=0;j<16;++j){
            float v = Wo1[(kseg+j)*64 + col];
            short h = f2bf_rne(v);
            hi[j] = h; lo[j] = f2bf_rne(v - bf2f(h));
        }
        #pragma unroll
        for(int i=0;i<4;++i){
            *(short4v*)&Ah[col*68 + kseg + 4*i] = *(short4v*)&hi[4*i];
            *(short4v*)&Al[col*68 + kseg + 4*i] = *(short4v*)&lo[4*i];
        }
    }
    __syncthreads();
    short8v w2h[4], w2l[4];
    #pragma unroll
    for(int s=0;s<4;++s){
        int base = (colhalf + c)*68 + s*16 + g*4;
        ((short4v*)&w2h[s])[0] = *(short4v*)&Ah[base];
        ((short4v*)&w2h[s])[1] = *(short4v*)&Ah[base + 8];
        ((short4v*)&w2l[s])[0] = *(short4v*)&Al[base];
        ((short4v*)&w2l[s])[1] = *(short4v*)&Al[base + 8];
    }
    __syncthreads();

    float bc1 = bin[colhalf + c];

    const int NT = (N_PREV + 63) / 64;
    for(int tile = blockIdx.x; tile < NT; tile += gridDim.x){
        int rbase = tile * 64;
        // ---- stage F tile (hi/lo bf16) into Ah/Al as [row][k] ----
        {
            int row = tid >> 2, kseg = (tid & 3) * 16;
            int grow = rbase + row;
            float fv[16];
            if(grow < N_PREV){
                const float4* fp = (const float4*)&feat[grow*64 + kseg];
                *(float4*)&fv[0]  = fp[0];
                *(float4*)&fv[4]  = fp[1];
                *(float4*)&fv[8]  = fp[2];
                *(float4*)&fv[12] = fp[3];
            } else {
                #pragma unroll
                for(int j=0;j<16;++j) fv[j]=0.f;
            }
            short hi[16], lo[16];
            #pragma unroll
            for(int j=0;j<16;++j){
                short h = f2bf_rne(fv[j]);
                hi[j] = h; lo[j] = f2bf_rne(fv[j] - bf2f(h));
            }
            #pragma unroll
            for(int i=0;i<4;++i){
                *(short4v*)&Ah[row*68 + kseg + 4*i] = *(short4v*)&hi[4*i];
                *(short4v*)&Al[row*68 + kseg + 4*i] = *(short4v*)&lo[4*i];
            }
        }
        __syncthreads();
        // ---- GEMM1: I = lrelu(F @ Win + b) ----
        f32x16 acc;
        #pragma unroll
        for(int i=0;i<16;++i) acc[i]=0.f;
        #pragma unroll
        for(int s=0;s<4;++s){
            int abase = (rowhalf + c)*68 + s*16 + g*4;
            short8v ah, al;
            ((short4v*)&ah)[0] = *(short4v*)&Ah[abase];
            ((short4v*)&ah)[1] = *(short4v*)&Ah[abase + 8];
            ((short4v*)&al)[0] = *(short4v*)&Al[abase];
            ((short4v*)&al)[1] = *(short4v*)&Al[abase + 8];
            acc = __builtin_amdgcn_mfma_f32_32x32x16_bf16(ah, w1h[s], acc, 0,0,0);
            acc = __builtin_amdgcn_mfma_f32_32x32x16_bf16(al, w1h[s], acc, 0,0,0);
            acc = __builtin_amdgcn_mfma_f32_32x32x16_bf16(ah, w1l[s], acc, 0,0,0);
        }
        __syncthreads();
        // ---- I epilogue: bias + lrelu, split to bf16 hi/lo, back into LDS ----
        #pragma unroll
        for(int r=0;r<16;++r){
            int row = rowhalf + (r&3) + 8*(r>>2) + 4*g;
            float v = acc[r] + bc1;
            v = v > 0.f ? v : 0.1f*v;
            short h = f2bf_rne(v);
            Ah[row*68 + colhalf + c] = h;
            Al[row*68 + colhalf + c] = f2bf_rne(v - bf2f(h));
        }
        __syncthreads();
        // ---- GEMM2: P1 = I @ Wo1a ----
        f32x16 acc2;
        #pragma unroll
        for(int i=0;i<16;++i) acc2[i]=0.f;
        #pragma unroll
        for(int s=0;s<4;++s){
            int abase = (rowhalf + c)*68 + s*16 + g*4;
            short8v ah, al;
            ((short4v*)&ah)[0] = *(short4v*)&Ah[abase];
            ((short4v*)&ah)[1] = *(short4v*)&Ah[abase + 8];
            ((short4v*)&al)[0] = *(short4v*)&Al[abase];
            ((short4v*)&al)[1] = *(short4v*)&Al[abase + 8];
            acc2 = __builtin_amdgcn_mfma_f32_32x32x16_bf16(ah, w2h[s], acc2, 0,0,0);
            acc2 = __builtin_amdgcn_mfma_f32_32x32x16_bf16(al, w2h[s], acc2, 0,0,0);
            acc2 = __builtin_amdgcn_mfma_f32_32x32x16_bf16(ah, w2l[s], acc2, 0,0,0);
        }
        // ---- store ----
        #pragma unroll
        for(int r=0;r<16;++r){
            int grow = rbase + rowhalf + (r&3) + 8*(r>>2) + 4*g;
            if(grow < N_PREV) P1[grow*64 + colhalf + c] = acc2[r];
        }
        __syncthreads();   // protect Ah/Al before next tile's stage
    }
}

// ---- x1 = lrelu((pooled@W1)/cnt + b1), BN1 stats.  64x32 tile, 2x4 blocking ----
__global__ void __launch_bounds__(256) k_ppm1(const float* __restrict__ pooled,
        const float* __restrict__ cnt, const unsigned* __restrict__ Ucnt,
        const float* __restrict__ W1, const float* __restrict__ b1,
        float* __restrict__ x1, float* __restrict__ stats){
    __shared__ float wsh[2048];
    __shared__ float b1sh[32];
    __shared__ float rsh[64];
    __shared__ float fsh[64][68];
    int tid = threadIdx.x;
    for(int q=tid; q<2048; q+=256) wsh[q]=W1[q];
    if(tid<32) b1sh[tid]=b1[tid];
    int U = (int)Ucnt[0];
    int rg = tid>>3, ci = tid&7;
    float4 s4=make_float4(0.f,0.f,0.f,0.f), q4=make_float4(0.f,0.f,0.f,0.f);
    const int NT = (N_PREV+63)/64;
    for(int tile=blockIdx.x; tile<NT; tile+=gridDim.x){
        int base = tile*64;
        if(base>=U) break;
        __syncthreads();
        for(int q=tid; q<1024; q+=256){
            int rr=q>>4, c4=q&15; int row=base+rr;
            float4 v = (row<U) ? ((const float4*)pooled)[row*16+c4]
                               : make_float4(0.f,0.f,0.f,0.f);
            *(float4*)&fsh[rr][c4*4] = v;
        }
        if(tid<64){ int row=base+tid; rsh[tid] = (row<U) ? 1.0f/cnt[row] : 0.f; }
        __syncthreads();
        float4 acc[2];
        acc[0]=make_float4(0.f,0.f,0.f,0.f); acc[1]=make_float4(0.f,0.f,0.f,0.f);
        #pragma unroll
        for(int kc=0;kc<16;++kc){
            float4 a0 = *(const float4*)&fsh[2*rg+0][kc*4];
            float4 a1 = *(const float4*)&fsh[2*rg+1][kc*4];
            float4 w0 = *(const float4*)&wsh[(4*kc+0)*32+4*ci];
            float4 w1 = *(const float4*)&wsh[(4*kc+1)*32+4*ci];
            float4 w2 = *(const float4*)&wsh[(4*kc+2)*32+4*ci];
            float4 w3 = *(const float4*)&wsh[(4*kc+3)*32+4*ci];
            fma4(acc[0],a0.x,w0); fma4(acc[0],a0.y,w1); fma4(acc[0],a0.z,w2); fma4(acc[0],a0.w,w3);
            fma4(acc[1],a1.x,w0); fma4(acc[1],a1.y,w1); fma4(acc[1],a1.z,w2); fma4(acc[1],a1.w,w3);
        }
        float4 bb = *(const float4*)&b1sh[4*ci];
        #pragma unroll
        for(int r=0;r<2;++r){
            int row = base + 2*rg + r;
            if(row<U){
                float rv = rsh[2*rg+r];
                float4 v;
                v.x = lrelu(acc[r].x*rv + bb.x);
                v.y = lrelu(acc[r].y*rv + bb.y);
                v.z = lrelu(acc[r].z*rv + bb.z);
                v.w = lrelu(acc[r].w*rv + bb.w);
                ((float4*)x1)[row*8+ci] = v;
                s4.x+=v.x; s4.y+=v.y; s4.z+=v.z; s4.w+=v.w;
                q4.x+=v.x*v.x; q4.y+=v.y*v.y; q4.z+=v.z*v.z; q4.w+=v.w*v.w;
            }
        }
    }
    __syncthreads();
    float* red = &fsh[0][0];
    red[rg*33+4*ci+0]=s4.x; red[rg*33+4*ci+1]=s4.y;
    red[rg*33+4*ci+2]=s4.z; red[rg*33+4*ci+3]=s4.w;
    __syncthreads();
    if(tid<32){ float t=0.f; for(int g=0;g<32;++g) t+=red[g*33+tid]; atomicAdd(&stats[tid], t); }
    __syncthreads();
    red[rg*33+4*ci+0]=q4.x; red[rg*33+4*ci+1]=q4.y;
    red[rg*33+4*ci+2]=q4.z; red[rg*33+4*ci+3]=q4.w;
    __syncthreads();
    if(tid<32){ float t=0.f; for(int g=0;g<32;++g) t+=red[g*33+tid]; atomicAdd(&stats[32+tid], t); }
}

__global__ void k_bnfin(const unsigned* __restrict__ Ucnt, const float* __restrict__ g,
                        float* __restrict__ stats, int off){
    int c = threadIdx.x;
    if(c>=32) return;
    float n = (float)max(Ucnt[0], 1u);
    float mu = stats[off+c]/n;
    float var = stats[off+32+c]/n - mu*mu;
    stats[off+64+c] = mu;
    stats[off+96+c] = g[c]*rsqrtf(var + EPSF);
}

// ---- x2 = lrelu(BN1(x1) @ W2 + b2), BN2 stats.  64x32 tile, 2x4 blocking ----
__global__ void __launch_bounds__(256) k_ppm2(const float* __restrict__ x1,
        const unsigned* __restrict__ Ucnt, const float* __restrict__ W2,
        const float* __restrict__ b2, const float* __restrict__ be1,
        float* __restrict__ x2, float* __restrict__ stats){
    __shared__ float wsh[1024];
    __shared__ float bsh[32], ash[32], bbsh[32];
    __shared__ float fsh[64][36];
    __shared__ float red[32*33];
    int tid = threadIdx.x;
    for(int q=tid; q<1024; q+=256) wsh[q]=W2[q];
    if(tid<32){
        bsh[tid]=b2[tid];
        float mu=stats[64+tid], sc=stats[96+tid];
        ash[tid]=sc; bbsh[tid]=be1[tid]-mu*sc;
    }
    int U = (int)Ucnt[0];
    int rg = tid>>3, ci = tid&7;
    float4 s4=make_float4(0.f,0.f,0.f,0.f), q4=make_float4(0.f,0.f,0.f,0.f);
    const int NT = (N_PREV+63)/64;
    for(int tile=blockIdx.x; tile<NT; tile+=gridDim.x){
        int base = tile*64;
        if(base>=U) break;
        __syncthreads();
        for(int q=tid; q<512; q+=256){
            int rr=q>>3, c4=q&7; int row=base+rr;
            float4 v = (row<U) ? ((const float4*)x1)[row*8+c4]
                               : make_float4(0.f,0.f,0.f,0.f);
            float4 aa = *(const float4*)&ash[4*c4];
            float4 bb = *(const float4*)&bbsh[4*c4];
            v.x=v.x*aa.x+bb.x; v.y=v.y*aa.y+bb.y; v.z=v.z*aa.z+bb.z; v.w=v.w*aa.w+bb.w;
            *(float4*)&fsh[rr][c4*4] = v;
        }
        __syncthreads();
        float4 acc[2];
        acc[0]=make_float4(0.f,0.f,0.f,0.f); acc[1]=make_float4(0.f,0.f,0.f,0.f);
        #pragma unroll
        for(int kc=0;kc<8;++kc){
            float4 a0 = *(const float4*)&fsh[2*rg+0][kc*4];
            float4 a1 = *(const float4*)&fsh[2*rg+1][kc*4];
            float4 w0 = *(const float4*)&wsh[(4*kc+0)*32+4*ci];
            float4 w1 = *(const float4*)&wsh[(4*kc+1)*32+4*ci];
            float4 w2 = *(const float4*)&wsh[(4*kc+2)*32+4*ci];
            float4 w3 = *(const float4*)&wsh[(4*kc+3)*32+4*ci];
            fma4(acc[0],a0.x,w0); fma4(acc[0],a0.y,w1); fma4(acc[0],a0.z,w2); fma4(acc[0],a0.w,w3);
            fma4(acc[1],a1.x,w0); fma4(acc[1],a1.y,w1); fma4(acc[1],a1.z,w2); fma4(acc[1],a1.w,w3);
        }
        float4 bb = *(const float4*)&bsh[4*ci];
        #pragma unroll
        for(int r=0;r<2;++r){
            int row = base + 2*rg + r;
            if(row<U){
                float4 v;
                v.x = lrelu(acc[r].x + bb.x);
                v.y = lrelu(acc[r].y + bb.y);
                v.z = lrelu(acc[r].z + bb.z);
                v.w = lrelu(acc[r].w + bb.w);
                ((float4*)x2)[row*8+ci] = v;
                s4.x+=v.x; s4.y+=v.y; s4.z+=v.z; s4.w+=v.w;
                q4.x+=v.x*v.x; q4.y+=v.y*v.y; q4.z+=v.z*v.z; q4.w+=v.w*v.w;
            }
        }
    }
    __syncthreads();
    red[rg*33+4*ci+0]=s4.x; red[rg*33+4*ci+1]=s4.y;
    red[rg*33+4*ci+2]=s4.z; red[rg*33+4*ci+3]=s4.w;
    __syncthreads();
    if(tid<32){ float t=0.f; for(int g=0;g<32;++g) t+=red[g*33+tid]; atomicAdd(&stats[128+tid], t); }
    __syncthreads();
    red[rg*33+4*ci+0]=q4.x; red[rg*33+4*ci+1]=q4.y;
    red[rg*33+4*ci+2]=q4.z; red[rg*33+4*ci+3]=q4.w;
    __syncthreads();
    if(tid<32){ float t=0.f; for(int g=0;g<32;++g) t+=red[g*33+tid]; atomicAdd(&stats[160+tid], t); }
}

// ---- P2 = lrelu(BN2(x2) @ W3 + b3) @ Wo1b  [U,64].  64-row tile, 4x4 blocking ----
__global__ void __launch_bounds__(256) k_ppm3(const float* __restrict__ x2,
        const unsigned* __restrict__ Ucnt, const float* __restrict__ W3,
        const float* __restrict__ b3, const float* __restrict__ be2,
        const float* __restrict__ Wo1, float* __restrict__ P2,
        const float* __restrict__ stats){
    __shared__ float w3sh[2048];
    __shared__ float w2sh[4096];
    __shared__ float b3sh[64], ash[32], bbsh[32];
    __shared__ float fsh[64][36];
    __shared__ float ish[64][68];
    int tid = threadIdx.x;
    for(int q=tid; q<2048; q+=256) w3sh[q]=W3[q];
    for(int q=tid; q<4096; q+=256) w2sh[q]=Wo1[4096+q];
    if(tid<64) b3sh[tid]=b3[tid];
    if(tid<32){
        float mu=stats[192+tid], sc=stats[224+tid];
        ash[tid]=sc; bbsh[tid]=be2[tid]-mu*sc;
    }
    int U = (int)Ucnt[0];
    int ri = tid>>4, ci = tid&15;
    const int NT = (N_PREV+63)/64;
    for(int tile=blockIdx.x; tile<NT; tile+=gridDim.x){
        int base = tile*64;
        if(base>=U) break;
        __syncthreads();
        for(int q=tid; q<512; q+=256){
            int rr=q>>3, c4=q&7; int row=base+rr;
            float4 v = (row<U) ? ((const float4*)x2)[row*8+c4]
                               : make_float4(0.f,0.f,0.f,0.f);
            float4 aa = *(const float4*)&ash[4*c4];
            float4 bb = *(const float4*)&bbsh[4*c4];
            v.x=v.x*aa.x+bb.x; v.y=v.y*aa.y+bb.y; v.z=v.z*aa.z+bb.z; v.w=v.w*aa.w+bb.w;
            *(float4*)&fsh[rr][c4*4] = v;
        }
        __syncthreads();
        float4 acc[4];
        #pragma unroll
        for(int r=0;r<4;++r) acc[r]=make_float4(0.f,0.f,0.f,0.f);
        #pragma unroll
        for(int kc=0;kc<8;++kc){
            float4 a0 = *(const float4*)&fsh[4*ri+0][kc*4];
            float4 a1 = *(const float4*)&fsh[4*ri+1][kc*4];
            float4 a2 = *(const float4*)&fsh[4*ri+2][kc*4];
            float4 a3 = *(const float4*)&fsh[4*ri+3][kc*4];
            float4 w0 = *(const float4*)&w3sh[(4*kc+0)*64+4*ci];
            float4 w1 = *(const float4*)&w3sh[(4*kc+1)*64+4*ci];
            float4 w2 = *(const float4*)&w3sh[(4*kc+2)*64+4*ci];
            float4 w3_ = *(const float4*)&w3sh[(4*kc+3)*64+4*ci];
            fma4(acc[0],a0.x,w0); fma4(acc[0],a0.y,w1); fma4(acc[0],a0.z,w2); fma4(acc[0],a0.w,w3_);
            fma4(acc[1],a1.x,w0); fma4(acc[1],a1.y,w1); fma4(acc[1],a1.z,w2); fma4(acc[1],a1.w,w3_);
            fma4(acc[2],a2.x,w0); fma4(acc[2],a2.y,w1); fma4(acc[2],a2.z,w2); fma4(acc[2],a2.w,w3_);
            fma4(acc[3],a3.x,w0); fma4(acc[3],a3.y,w1); fma4(acc[3],a3.z,w2); fma4(acc[3],a3.w,w3_);
        }
        float4 bb = *(const float4*)&b3sh[4*ci];
        #pragma unroll
        for(int r=0;r<4;++r){
            float4 v = acc[r];
            v.x = lrelu(v.x+bb.x); v.y = lrelu(v.y+bb.y);
            v.z = lrelu(v.z+bb.z); v.w = lrelu(v.w+bb.w);
            *(float4*)&ish[4*ri+r][4*ci] = v;
        }
        __syncthreads();
        float4 acc2[4];
        #pragma unroll
        for(int r=0;r<4;++r) acc2[r]=make_float4(0.f,0.f,0.f,0.f);
        #pragma unroll
        for(int kc=0;kc<16;++kc){
            float4 a0 = *(const float4*)&ish[4*ri+0][kc*4];
            float4 a1 = *(const float4*)&ish[4*ri+1][kc*4];
            float4 a2 = *(const float4*)&ish[4*ri+2][kc*4];
            float4 a3 = *(const float4*)&ish[4*ri+3][kc*4];
            float4 w0 = *(const float4*)&w2sh[(4*kc+0)*64+4*ci];
            float4 w1 = *(const float4*)&w2sh[(4*kc+1)*64+4*ci];
            float4 w2 = *(const float4*)&w2sh[(4*kc+2)*64+4*ci];
            float4 w3_ = *(const float4*)&w2sh[(4*kc+3)*64+4*ci];
            fma4(acc2[0],a0.x,w0); fma4(acc2[0],a0.y,w1); fma4(acc2[0],a0.z,w2); fma4(acc2[0],a0.w,w3_);
            fma4(acc2[1],a1.x,w0); fma4(acc2[1],a1.y,w1); fma4(acc2[1],a1.z,w2); fma4(acc2[1],a1.w,w3_);
            fma4(acc2[2],a2.x,w0); fma4(acc2[2],a2.y,w1); fma4(acc2[2],a2.z,w2); fma4(acc2[2],a2.w,w3_);
            fma4(acc2[3],a3.x,w0); fma4(acc2[3],a3.y,w1); fma4(acc2[3],a3.z,w2); fma4(acc2[3],a3.w,w3_);
        }
        #pragma unroll
        for(int r=0;r<4;++r){
            int row = base + 4*ri + r;
            if(row<U) ((float4*)P2)[row*16+ci] = acc2[r];
        }
    }
}

// ---- one wave per voxel: T = Σ lrelu(P1[j]+P2[h]+bo1); out = (T@Wo2 + cnt*bo2)/max(cnt,1) ----
__global__ void __launch_bounds__(256) k_vox(const unsigned* __restrict__ vstart,
        const int* __restrict__ csr_j, const int* __restrict__ csr_h,
        const float* __restrict__ P1, const float* __restrict__ P2,
        const float* __restrict__ bo1, const float* __restrict__ Wo2,
        const float* __restrict__ bo2, float* __restrict__ out){
    __shared__ float tsh[4][64];
    int tid = threadIdx.x;
    int wib = tid>>6, lane = tid&63;
    float wreg[64];
    #pragma unroll
    for(int k=0;k<64;++k) wreg[k] = Wo2[k*64+lane];
    float b1 = bo1[lane], b2 = bo2[lane];
    int wglobal = blockIdx.x*4 + wib;
    for(int vq=0; vq<4; ++vq){
        int vox = wglobal*4 + vq;
        int s = (int)vstart[vox], e = (int)vstart[vox+1];
        float acc = 0.f;
        for(int i=s; i<e; i+=64){
            int n = min(e-i, 64);
            int jv=0, hv=0;
            if(lane<n){ jv = csr_j[i+lane]; hv = csr_h[i+lane]; }
            for(int q=0;q<n;++q){
                int j = __shfl(jv,q), h = __shfl(hv,q);
                float g = P1[j*64+lane] + P2[h*64+lane] + b1;
                acc += (g>0.f) ? g : 0.1f*g;
            }
        }
        tsh[wib][lane] = acc;
        float dot = 0.f;
        const float4* t4 = (const float4*)tsh[wib];
        #pragma unroll
        for(int k4=0;k4<16;++k4){
            float4 t = t4[k4];
            dot += t.x*wreg[4*k4] + t.y*wreg[4*k4+1] + t.z*wreg[4*k4+2] + t.w*wreg[4*k4+3];
        }
        float cntv = (float)(e - s);
        out[vox*64+lane] = (dot + cntv*b2) / fmaxf(cntv, 1.f);
    }
}

extern "C" void kernel_launch(void* const* d_in, const int* in_sizes, int n_in,
                              void* d_out, int out_size, void* d_ws, size_t ws_size,
                              hipStream_t stream) {
    if(ws_size < WS_NEEDED) return;

    const float* features = (const float*)d_in[0];
    const int*   coors    = (const int*)d_in[1];
    const int*   cif      = (const int*)d_in[2];
    const int*   scv      = (const int*)d_in[3];
    const float* W_in     = (const float*)d_in[4];
    const float* b_in     = (const float*)d_in[5];
    const float* W1       = (const float*)d_in[6];
    const float* b1       = (const float*)d_in[7];
    const float* g1       = (const float*)d_in[8];
    const float* be1      = (const float*)d_in[9];
    const float* W2       = (const float*)d_in[10];
    const float* b2       = (const float*)d_in[11];
    const float* g2       = (const float*)d_in[12];
    const float* be2      = (const float*)d_in[13];
    const float* W3       = (const float*)d_in[14];
    const float* b3       = (const float*)d_in[15];
    const float* Wo1      = (const float*)d_in[16];
    const float* bo1      = (const float*)d_in[17];
    const float* Wo2      = (const float*)d_in[18];
    const float* bo2      = (const float*)d_in[19];

    char* ws = (char*)d_ws;
    unsigned* bitmap = (unsigned*)(ws + OFF_BITMAP);
    float*    stats  = (float*)(ws + OFF_STATS);
    float*    cnt    = (float*)(ws + OFF_CNT);
    unsigned* vh     = (unsigned*)(ws + OFF_VH);
    float*    pooled = (float*)(ws + OFF_POOLED);
    unsigned* pref   = (unsigned*)(ws + OFF_PREF);
    unsigned* bsum   = (unsigned*)(ws + OFF_BSUM);
    unsigned* boff   = (unsigned*)(ws + OFF_BOFF);
    unsigned* Ucnt   = (unsigned*)(ws + OFF_UCNT);
    float*    x1     = (float*)(ws + OFF_X1);
    float*    x2     = (float*)(ws + OFF_X2);
    int*      inv    = (int*)(ws + OFF_INV);
    float*    P1     = (float*)(ws + OFF_X1);
    float*    P2     = pooled;
    int*      csr_j  = (int*)(ws + OFF_CSRJ);
    int*      csr_h  = (int*)(ws + OFF_CSRH);
    unsigned* vstart = (unsigned*)(ws + OFF_VSTART);
    unsigned* vnext  = (unsigned*)(ws + OFF_VNEXT);
    unsigned* vpart  = (unsigned*)(ws + OFF_VPART);
    unsigned* vbsum  = (unsigned*)(ws + OFF_VBSUM);

    hipMemsetAsync(d_ws, 0, ZERO_BYTES, stream);

    k_mark  <<<(N_PREV+255)/256, 256, 0, stream>>>(coors, bitmap);
    k_scanA <<<1024, 1024, 0, stream>>>(bitmap, pref, bsum);
    k_scanB <<<1, 1024, 0, stream>>>(bsum, boff, Ucnt);
    k_rank  <<<N_PREV/4, 256, 0, stream>>>(coors, features, bitmap, pref, boff, inv, cnt, pooled);
    k_vhist <<<(N_FULL+255)/256, 256, 0, stream>>>(scv, vh);
    k_vscanA<<<64, 1024, 0, stream>>>(vh, vpart, vbsum);
    k_vscanB<<<1, 64, 0, stream>>>(vbsum);
    k_vfix  <<<64, 1024, 0, stream>>>(vpart, vbsum, vstart, vnext);
    k_fill  <<<(N_FULL+255)/256, 256, 0, stream>>>(cif, scv, inv, vnext, csr_j, csr_h);
    k_ppm1 <<<1024, 256, 0, stream>>>(pooled, cnt, Ucnt, W1, b1, x1, stats);
    k_bnfin<<<1, 32, 0, stream>>>(Ucnt, g1, stats, 0);
    k_ppm2 <<<1024, 256, 0, stream>>>(x1, Ucnt, W2, b2, be1, x2, stats);
    k_bnfin<<<1, 32, 0, stream>>>(Ucnt, g2, stats, 128);
    k_ppm3 <<<1024, 256, 0, stream>>>(x2, Ucnt, W3, b3, be2, Wo1, P2, stats);
    k_p1   <<<1024, 256, 0, stream>>>(features, W_in, b_in, Wo1, P1);
    k_vox  <<<NVOX/16, 256, 0, stream>>>(vstart, csr_j, csr_h, P1, P2, bo1, Wo2, bo2, (float*)d_out);
}

// Round 5
// 392.874 us; speedup vs baseline: 2.4706x; 1.2670x over previous
//
#include <hip/hip_runtime.h>

#define N_PREV 250000
#define N_FULL 500000
#define NVOX   65536
#define NWORDS (1u<<20)          // bitmap words; keyspace < 2^25 bits
#define EPSF   1e-5f

typedef __attribute__((ext_vector_type(4)))  short short4v;
typedef __attribute__((ext_vector_type(8)))  short short8v;
typedef __attribute__((ext_vector_type(16))) float f32x16;

__device__ __forceinline__ float lrelu(float x){ return x > 0.0f ? x : 0.1f*x; }
__device__ __forceinline__ short f2bf_rne(float v){
    unsigned u = __float_as_uint(v);
    unsigned r = (u + 0x7fffu + ((u>>16)&1u)) >> 16;
    return (short)r;
}
__device__ __forceinline__ float bf2f(short s){
    return __uint_as_float(((unsigned)(unsigned short)s) << 16);
}

// ---------------- ws layout (bytes) ----------------
#define OFF_BITMAP   0ul            // u32[NWORDS] (aliased as csr_j/csr_h after k_rank)
#define OFF_STATS    4194304ul      // f32[256]
#define OFF_CNT      4195328ul      // f32[N_PREV]
#define OFF_VH       5195328ul      // u32[NVOX]
#define OFF_POOLED   5457472ul      // f32[N_PREV*64] (later aliased as P2)
#define ZERO_BYTES   69457472ul
#define OFF_PREF     69457472ul     // u32[NWORDS] (aliased as vstart/vnext/vpart/vbsum)
#define OFF_BSUM     73651776ul
#define OFF_BOFF     73655872ul
#define OFF_UCNT     73659968ul
#define OFF_INV      73660224ul     // i32[N_PREV]
#define OFF_X1       74660224ul     // f32[N_PREV*32] (P1 spans x1+x2)
#define OFF_X2       106660224ul
#define WS_NEEDED    138660224ul
#define OFF_CSRJ     0ul
#define OFF_CSRH     2000000ul
#define OFF_VSTART   69457472ul
#define OFF_VNEXT    (OFF_VSTART+262400ul)
#define OFF_VPART    (OFF_VNEXT+262144ul)
#define OFF_VBSUM    (OFF_VPART+262144ul)

__device__ __forceinline__ int voxel_key(int4 c){
    return ((c.x*501 + (c.y>>1))*501 + (c.z>>1))*31 + (c.w>>1);
}

// ---- mark present keys ----
__global__ void k_mark(const int* __restrict__ coors, unsigned* __restrict__ bitmap){
    int i = blockIdx.x*256 + threadIdx.x;
    if(i >= N_PREV) return;
    int4 c = ((const int4*)coors)[i];
    int key = voxel_key(c);
    atomicOr(&bitmap[key>>5], 1u<<(key&31));
}

__global__ void __launch_bounds__(1024) k_scanA(const unsigned* __restrict__ bitmap,
                                                unsigned* __restrict__ pref,
                                                unsigned* __restrict__ bsum){
    __shared__ unsigned sh[1024];
    int tid = threadIdx.x;
    int w = blockIdx.x*1024 + tid;
    unsigned p = __popc(bitmap[w]);
    sh[tid] = p; __syncthreads();
    for(int off=1; off<1024; off<<=1){
        unsigned v = (tid>=off) ? sh[tid-off] : 0u;
        __syncthreads();
        sh[tid] += v;
        __syncthreads();
    }
    pref[w] = sh[tid] - p;
    if(tid==1023) bsum[blockIdx.x] = sh[tid];
}

__global__ void __launch_bounds__(1024) k_scanB(const unsigned* __restrict__ bsum,
                                                unsigned* __restrict__ boff,
                                                unsigned* __restrict__ Ucnt){
    __shared__ unsigned sh[1024];
    int tid = threadIdx.x;
    unsigned p = bsum[tid];
    sh[tid] = p; __syncthreads();
    for(int off=1; off<1024; off<<=1){
        unsigned v = (tid>=off) ? sh[tid-off] : 0u;
        __syncthreads();
        sh[tid] += v;
        __syncthreads();
    }
    boff[tid] = sh[tid] - p;
    if(tid==1023) Ucnt[0] = sh[tid];
}

__global__ void k_rank(const int* __restrict__ coors, const float* __restrict__ feat,
                       const unsigned* __restrict__ bitmap, const unsigned* __restrict__ pref,
                       const unsigned* __restrict__ boff, int* __restrict__ inv,
                       float* __restrict__ cnt, float* __restrict__ pooled){
    int wave = (blockIdx.x*256 + threadIdx.x) >> 6;
    int lane = threadIdx.x & 63;
    if(wave >= N_PREV) return;
    int4 c = ((const int4*)coors)[wave];
    int key = voxel_key(c);
    int w = key>>5, b = key&31;
    int rank = (int)(boff[w>>10] + pref[w]) + __popc(bitmap[w] & ((1u<<b)-1u));
    if(lane==0){
        inv[wave] = rank;
        atomicAdd(&cnt[rank], 1.0f);
    }
    atomicAdd(&pooled[rank*64 + lane], feat[wave*64 + lane]);
}

// ---- CSR build over scale voxels ----
__global__ void k_vhist(const int* __restrict__ scv, unsigned* __restrict__ vh){
    int p = blockIdx.x*256 + threadIdx.x;
    if(p < N_FULL) atomicAdd(&vh[scv[p]], 1u);
}

__global__ void __launch_bounds__(1024) k_vscanA(const unsigned* __restrict__ vh,
                                                 unsigned* __restrict__ vpart,
                                                 unsigned* __restrict__ vbsum){
    __shared__ unsigned sh[1024];
    int tid = threadIdx.x;
    int w = blockIdx.x*1024 + tid;
    unsigned p = vh[w];
    sh[tid] = p; __syncthreads();
    for(int off=1; off<1024; off<<=1){
        unsigned v = (tid>=off) ? sh[tid-off] : 0u;
        __syncthreads();
        sh[tid] += v;
        __syncthreads();
    }
    vpart[w] = sh[tid] - p;
    if(tid==1023) vbsum[blockIdx.x] = sh[tid];
}

__global__ void k_vscanB(unsigned* __restrict__ vbsum){
    int l = threadIdx.x;
    unsigned v = vbsum[l], orig = v;
    for(int off=1; off<64; off<<=1){
        unsigned o = __shfl_up(v, off);
        if(l>=off) v += o;
    }
    vbsum[l] = v - orig;
}

__global__ void __launch_bounds__(1024) k_vfix(const unsigned* __restrict__ vpart,
                                               const unsigned* __restrict__ vbsum,
                                               unsigned* __restrict__ vstart,
                                               unsigned* __restrict__ vnext){
    int w = blockIdx.x*1024 + threadIdx.x;
    unsigned s = vpart[w] + vbsum[w>>10];
    vstart[w] = s; vnext[w] = s;
    if(w == NVOX-1) vstart[NVOX] = N_FULL;
}

__global__ void k_fill(const int* __restrict__ cif, const int* __restrict__ scv,
                       const int* __restrict__ inv, unsigned* __restrict__ vnext,
                       int* __restrict__ csr_j, int* __restrict__ csr_h){
    int p = blockIdx.x*256 + threadIdx.x;
    if(p >= N_FULL) return;
    int jp = cif[p];
    unsigned pos = atomicAdd(&vnext[scv[p]], 1u);
    csr_j[pos] = jp;
    csr_h[pos] = inv[jp];
}

// ---- P1 = lrelu(features @ W_in + b_in) @ Wo1a   [N_PREV,64] ----
// MFMA 32x32x16 bf16, split hi/lo (3-pass). VERIFIED pattern (R4).
__global__ void __launch_bounds__(256) k_p1(const float* __restrict__ feat,
        const float* __restrict__ Win, const float* __restrict__ bin,
        const float* __restrict__ Wo1, float* __restrict__ P1){
    __shared__ __align__(16) short Ah[64*68];
    __shared__ __align__(16) short Al[64*68];
    int tid = threadIdx.x;
    int wave = tid >> 6, l = tid & 63;
    int g = l >> 5, c = l & 31;
    int rowhalf = (wave >> 1) * 32, colhalf = (wave & 1) * 32;

    {
        int col = tid >> 2, kseg = (tid & 3) * 16;
        short hi[16], lo[16];
        #pragma unroll
        for(int j=0;j<16;++j){
            float v = Win[(kseg+j)*64 + col];
            short h = f2bf_rne(v);
            hi[j] = h; lo[j] = f2bf_rne(v - bf2f(h));
        }
        #pragma unroll
        for(int i=0;i<4;++i){
            *(short4v*)&Ah[col*68 + kseg + 4*i] = *(short4v*)&hi[4*i];
            *(short4v*)&Al[col*68 + kseg + 4*i] = *(short4v*)&lo[4*i];
        }
    }
    __syncthreads();
    short8v w1h[4], w1l[4];
    #pragma unroll
    for(int s=0;s<4;++s){
        int base = (colhalf + c)*68 + s*16 + g*4;
        ((short4v*)&w1h[s])[0] = *(short4v*)&Ah[base];
        ((short4v*)&w1h[s])[1] = *(short4v*)&Ah[base + 8];
        ((short4v*)&w1l[s])[0] = *(short4v*)&Al[base];
        ((short4v*)&w1l[s])[1] = *(short4v*)&Al[base + 8];
    }
    __syncthreads();
    {
        int col = tid >> 2, kseg = (tid & 3) * 16;
        short hi[16], lo[16];
        #pragma unroll
        for(int j=0;j<16;++j){
            float v = Wo1[(kseg+j)*64 + col];
            short h = f2bf_rne(v);
            hi[j] = h; lo[j] = f2bf_rne(v - bf2f(h));
        }
        #pragma unroll
        for(int i=0;i<4;++i){
            *(short4v*)&Ah[col*68 + kseg + 4*i] = *(short4v*)&hi[4*i];
            *(short4v*)&Al[col*68 + kseg + 4*i] = *(short4v*)&lo[4*i];
        }
    }
    __syncthreads();
    short8v w2h[4], w2l[4];
    #pragma unroll
    for(int s=0;s<4;++s){
        int base = (colhalf + c)*68 + s*16 + g*4;
        ((short4v*)&w2h[s])[0] = *(short4v*)&Ah[base];
        ((short4v*)&w2h[s])[1] = *(short4v*)&Ah[base + 8];
        ((short4v*)&w2l[s])[0] = *(short4v*)&Al[base];
        ((short4v*)&w2l[s])[1] = *(short4v*)&Al[base + 8];
    }
    __syncthreads();

    float bc1 = bin[colhalf + c];

    const int NT = (N_PREV + 63) / 64;
    for(int tile = blockIdx.x; tile < NT; tile += gridDim.x){
        int rbase = tile * 64;
        {
            int row = tid >> 2, kseg = (tid & 3) * 16;
            int grow = rbase + row;
            float fv[16];
            if(grow < N_PREV){
                const float4* fp = (const float4*)&feat[grow*64 + kseg];
                *(float4*)&fv[0]  = fp[0];
                *(float4*)&fv[4]  = fp[1];
                *(float4*)&fv[8]  = fp[2];
                *(float4*)&fv[12] = fp[3];
            } else {
                #pragma unroll
                for(int j=0;j<16;++j) fv[j]=0.f;
            }
            short hi[16], lo[16];
            #pragma unroll
            for(int j=0;j<16;++j){
                short h = f2bf_rne(fv[j]);
                hi[j] = h; lo[j] = f2bf_rne(fv[j] - bf2f(h));
            }
            #pragma unroll
            for(int i=0;i<4;++i){
                *(short4v*)&Ah[row*68 + kseg + 4*i] = *(short4v*)&hi[4*i];
                *(short4v*)&Al[row*68 + kseg + 4*i] = *(short4v*)&lo[4*i];
            }
        }
        __syncthreads();
        f32x16 acc;
        #pragma unroll
        for(int i=0;i<16;++i) acc[i]=0.f;
        #pragma unroll
        for(int s=0;s<4;++s){
            int abase = (rowhalf + c)*68 + s*16 + g*4;
            short8v ah, al;
            ((short4v*)&ah)[0] = *(short4v*)&Ah[abase];
            ((short4v*)&ah)[1] = *(short4v*)&Ah[abase + 8];
            ((short4v*)&al)[0] = *(short4v*)&Al[abase];
            ((short4v*)&al)[1] = *(short4v*)&Al[abase + 8];
            acc = __builtin_amdgcn_mfma_f32_32x32x16_bf16(ah, w1h[s], acc, 0,0,0);
            acc = __builtin_amdgcn_mfma_f32_32x32x16_bf16(al, w1h[s], acc, 0,0,0);
            acc = __builtin_amdgcn_mfma_f32_32x32x16_bf16(ah, w1l[s], acc, 0,0,0);
        }
        __syncthreads();
        #pragma unroll
        for(int r=0;r<16;++r){
            int row = rowhalf + (r&3) + 8*(r>>2) + 4*g;
            float v = acc[r] + bc1;
            v = v > 0.f ? v : 0.1f*v;
            short h = f2bf_rne(v);
            Ah[row*68 + colhalf + c] = h;
            Al[row*68 + colhalf + c] = f2bf_rne(v - bf2f(h));
        }
        __syncthreads();
        f32x16 acc2;
        #pragma unroll
        for(int i=0;i<16;++i) acc2[i]=0.f;
        #pragma unroll
        for(int s=0;s<4;++s){
            int abase = (rowhalf + c)*68 + s*16 + g*4;
            short8v ah, al;
            ((short4v*)&ah)[0] = *(short4v*)&Ah[abase];
            ((short4v*)&ah)[1] = *(short4v*)&Ah[abase + 8];
            ((short4v*)&al)[0] = *(short4v*)&Al[abase];
            ((short4v*)&al)[1] = *(short4v*)&Al[abase + 8];
            acc2 = __builtin_amdgcn_mfma_f32_32x32x16_bf16(ah, w2h[s], acc2, 0,0,0);
            acc2 = __builtin_amdgcn_mfma_f32_32x32x16_bf16(al, w2h[s], acc2, 0,0,0);
            acc2 = __builtin_amdgcn_mfma_f32_32x32x16_bf16(ah, w2l[s], acc2, 0,0,0);
        }
        #pragma unroll
        for(int r=0;r<16;++r){
            int grow = rbase + rowhalf + (r&3) + 8*(r>>2) + 4*g;
            if(grow < N_PREV) P1[grow*64 + colhalf + c] = acc2[r];
        }
        __syncthreads();
    }
}

// ---- x1 = lrelu((pooled@W1)*rinv + b1), BN1 stats.  MFMA, 128x32 tile ----
__global__ void __launch_bounds__(256) k_ppm1(const float* __restrict__ pooled,
        const float* __restrict__ cnt, const unsigned* __restrict__ Ucnt,
        const float* __restrict__ W1, const float* __restrict__ b1,
        float* __restrict__ x1, float* __restrict__ stats){
    __shared__ __align__(16) short Ah[128*68];
    __shared__ __align__(16) short Al[128*68];
    __shared__ float rsh[128];
    __shared__ float red[4][64];
    int tid = threadIdx.x;
    int wave = tid >> 6, l = tid & 63;
    int g = l >> 5, c = l & 31;

    // stage W1^T [32 col][64 k] into Ah/Al scratch, hoist frags
    if(tid < 128){
        int col = tid >> 2, kseg = (tid & 3) * 16;
        short hi[16], lo[16];
        #pragma unroll
        for(int j=0;j<16;++j){
            float v = W1[(kseg+j)*32 + col];
            short h = f2bf_rne(v);
            hi[j] = h; lo[j] = f2bf_rne(v - bf2f(h));
        }
        #pragma unroll
        for(int i=0;i<4;++i){
            *(short4v*)&Ah[col*68 + kseg + 4*i] = *(short4v*)&hi[4*i];
            *(short4v*)&Al[col*68 + kseg + 4*i] = *(short4v*)&lo[4*i];
        }
    }
    __syncthreads();
    short8v wh[4], wl[4];
    #pragma unroll
    for(int s=0;s<4;++s){
        int base = c*68 + s*16 + g*4;
        ((short4v*)&wh[s])[0] = *(short4v*)&Ah[base];
        ((short4v*)&wh[s])[1] = *(short4v*)&Ah[base + 8];
        ((short4v*)&wl[s])[0] = *(short4v*)&Al[base];
        ((short4v*)&wl[s])[1] = *(short4v*)&Al[base + 8];
    }
    __syncthreads();

    int U = (int)Ucnt[0];
    float bc = b1[c];
    float s_acc = 0.f, q_acc = 0.f;

    const int NT = (N_PREV + 127) / 128;
    for(int tile = blockIdx.x; tile < NT; tile += gridDim.x){
        int rbase = tile * 128;
        if(rbase >= U) break;
        #pragma unroll
        for(int half=0; half<2; ++half){
            int row = (tid >> 2) + 64*half;
            int kseg = (tid & 3) * 16;
            int grow = rbase + row;
            float fv[16];
            if(grow < N_PREV){
                const float4* fp = (const float4*)&pooled[grow*64 + kseg];
                *(float4*)&fv[0]=fp[0]; *(float4*)&fv[4]=fp[1];
                *(float4*)&fv[8]=fp[2]; *(float4*)&fv[12]=fp[3];
            } else {
                #pragma unroll
                for(int j=0;j<16;++j) fv[j]=0.f;
            }
            short hi[16], lo[16];
            #pragma unroll
            for(int j=0;j<16;++j){
                short h = f2bf_rne(fv[j]);
                hi[j] = h; lo[j] = f2bf_rne(fv[j] - bf2f(h));
            }
            #pragma unroll
            for(int i=0;i<4;++i){
                *(short4v*)&Ah[row*68 + kseg + 4*i] = *(short4v*)&hi[4*i];
                *(short4v*)&Al[row*68 + kseg + 4*i] = *(short4v*)&lo[4*i];
            }
        }
        if(tid < 128){ int grow = rbase + tid; rsh[tid] = (grow<U) ? 1.0f/cnt[grow] : 0.f; }
        __syncthreads();
        f32x16 acc;
        #pragma unroll
        for(int i=0;i<16;++i) acc[i]=0.f;
        #pragma unroll
        for(int s=0;s<4;++s){
            int abase = (wave*32 + c)*68 + s*16 + g*4;
            short8v ah, al;
            ((short4v*)&ah)[0] = *(short4v*)&Ah[abase];
            ((short4v*)&ah)[1] = *(short4v*)&Ah[abase + 8];
            ((short4v*)&al)[0] = *(short4v*)&Al[abase];
            ((short4v*)&al)[1] = *(short4v*)&Al[abase + 8];
            acc = __builtin_amdgcn_mfma_f32_32x32x16_bf16(ah, wh[s], acc, 0,0,0);
            acc = __builtin_amdgcn_mfma_f32_32x32x16_bf16(al, wh[s], acc, 0,0,0);
            acc = __builtin_amdgcn_mfma_f32_32x32x16_bf16(ah, wl[s], acc, 0,0,0);
        }
        #pragma unroll
        for(int r=0;r<16;++r){
            int rl = wave*32 + (r&3) + 8*(r>>2) + 4*g;
            int grow = rbase + rl;
            if(grow < U){
                float v = acc[r]*rsh[rl] + bc;
                v = v > 0.f ? v : 0.1f*v;
                x1[grow*32 + c] = v;
                s_acc += v; q_acc += v*v;
            }
        }
        __syncthreads();
    }
    s_acc += __shfl_xor(s_acc, 32);
    q_acc += __shfl_xor(q_acc, 32);
    if(l < 32){ red[wave][c] = s_acc; red[wave][32+c] = q_acc; }
    __syncthreads();
    if(tid < 64){
        float t = red[0][tid]+red[1][tid]+red[2][tid]+red[3][tid];
        atomicAdd(&stats[tid], t);
    }
}

__global__ void k_bnfin(const unsigned* __restrict__ Ucnt, const float* __restrict__ g,
                        float* __restrict__ stats, int off){
    int c = threadIdx.x;
    if(c>=32) return;
    float n = (float)max(Ucnt[0], 1u);
    float mu = stats[off+c]/n;
    float var = stats[off+32+c]/n - mu*mu;
    stats[off+64+c] = mu;
    stats[off+96+c] = g[c]*rsqrtf(var + EPSF);
}

// ---- x2 = lrelu(BN1(x1) @ W2 + b2), BN2 stats.  MFMA, 128x32 tile, k=32 ----
__global__ void __launch_bounds__(256) k_ppm2(const float* __restrict__ x1,
        const unsigned* __restrict__ Ucnt, const float* __restrict__ W2,
        const float* __restrict__ b2, const float* __restrict__ be1,
        float* __restrict__ x2, float* __restrict__ stats){
    __shared__ __align__(16) short Ah[128*36];
    __shared__ __align__(16) short Al[128*36];
    __shared__ float ash[32], bbsh[32];
    __shared__ float red[4][64];
    int tid = threadIdx.x;
    int wave = tid >> 6, l = tid & 63;
    int g = l >> 5, c = l & 31;

    if(tid < 32){
        float mu=stats[64+tid], sc=stats[96+tid];
        ash[tid]=sc; bbsh[tid]=be1[tid]-mu*sc;
    }
    // stage W2^T [32 col][32 k], hoist
    if(tid < 64){
        int col = tid >> 1, kseg = (tid & 1) * 16;
        short hi[16], lo[16];
        #pragma unroll
        for(int j=0;j<16;++j){
            float v = W2[(kseg+j)*32 + col];
            short h = f2bf_rne(v);
            hi[j] = h; lo[j] = f2bf_rne(v - bf2f(h));
        }
        #pragma unroll
        for(int i=0;i<4;++i){
            *(short4v*)&Ah[col*36 + kseg + 4*i] = *(short4v*)&hi[4*i];
            *(short4v*)&Al[col*36 + kseg + 4*i] = *(short4v*)&lo[4*i];
        }
    }
    __syncthreads();
    short8v wh[2], wl[2];
    #pragma unroll
    for(int s=0;s<2;++s){
        int base = c*36 + s*16 + g*4;
        ((short4v*)&wh[s])[0] = *(short4v*)&Ah[base];
        ((short4v*)&wh[s])[1] = *(short4v*)&Ah[base + 8];
        ((short4v*)&wl[s])[0] = *(short4v*)&Al[base];
        ((short4v*)&wl[s])[1] = *(short4v*)&Al[base + 8];
    }
    __syncthreads();

    int U = (int)Ucnt[0];
    float bc = b2[c];
    float s_acc = 0.f, q_acc = 0.f;

    const int NT = (N_PREV + 127) / 128;
    for(int tile = blockIdx.x; tile < NT; tile += gridDim.x){
        int rbase = tile * 128;
        if(rbase >= U) break;
        {
            int row = tid >> 1, kseg = (tid & 1) * 16;
            int grow = rbase + row;
            float fv[16];
            if(grow < U){
                const float4* fp = (const float4*)&x1[grow*32 + kseg];
                *(float4*)&fv[0]=fp[0]; *(float4*)&fv[4]=fp[1];
                *(float4*)&fv[8]=fp[2]; *(float4*)&fv[12]=fp[3];
                #pragma unroll
                for(int j=0;j<16;++j) fv[j] = fv[j]*ash[kseg+j] + bbsh[kseg+j];
            } else {
                #pragma unroll
                for(int j=0;j<16;++j) fv[j]=0.f;
            }
            short hi[16], lo[16];
            #pragma unroll
            for(int j=0;j<16;++j){
                short h = f2bf_rne(fv[j]);
                hi[j] = h; lo[j] = f2bf_rne(fv[j] - bf2f(h));
            }
            #pragma unroll
            for(int i=0;i<4;++i){
                *(short4v*)&Ah[row*36 + kseg + 4*i] = *(short4v*)&hi[4*i];
                *(short4v*)&Al[row*36 + kseg + 4*i] = *(short4v*)&lo[4*i];
            }
        }
        __syncthreads();
        f32x16 acc;
        #pragma unroll
        for(int i=0;i<16;++i) acc[i]=0.f;
        #pragma unroll
        for(int s=0;s<2;++s){
            int abase = (wave*32 + c)*36 + s*16 + g*4;
            short8v ah, al;
            ((short4v*)&ah)[0] = *(short4v*)&Ah[abase];
            ((short4v*)&ah)[1] = *(short4v*)&Ah[abase + 8];
            ((short4v*)&al)[0] = *(short4v*)&Al[abase];
            ((short4v*)&al)[1] = *(short4v*)&Al[abase + 8];
            acc = __builtin_amdgcn_mfma_f32_32x32x16_bf16(ah, wh[s], acc, 0,0,0);
            acc = __builtin_amdgcn_mfma_f32_32x32x16_bf16(al, wh[s], acc, 0,0,0);
            acc = __builtin_amdgcn_mfma_f32_32x32x16_bf16(ah, wl[s], acc, 0,0,0);
        }
        #pragma unroll
        for(int r=0;r<16;++r){
            int rl = wave*32 + (r&3) + 8*(r>>2) + 4*g;
            int grow = rbase + rl;
            if(grow < U){
                float v = acc[r] + bc;
                v = v > 0.f ? v : 0.1f*v;
                x2[grow*32 + c] = v;
                s_acc += v; q_acc += v*v;
            }
        }
        __syncthreads();
    }
    s_acc += __shfl_xor(s_acc, 32);
    q_acc += __shfl_xor(q_acc, 32);
    if(l < 32){ red[wave][c] = s_acc; red[wave][32+c] = q_acc; }
    __syncthreads();
    if(tid < 64){
        float t = red[0][tid]+red[1][tid]+red[2][tid]+red[3][tid];
        atomicAdd(&stats[128+tid], t);
    }
}

// ---- P2 = lrelu(BN2(x2) @ W3 + b3) @ Wo1b  [U,64].  MFMA, 64x64 tile ----
__global__ void __launch_bounds__(256) k_ppm3(const float* __restrict__ x2,
        const unsigned* __restrict__ Ucnt, const float* __restrict__ W3,
        const float* __restrict__ b3, const float* __restrict__ be2,
        const float* __restrict__ Wo1, float* __restrict__ P2,
        const float* __restrict__ stats){
    __shared__ __align__(16) short Ah[64*36];
    __shared__ __align__(16) short Al[64*36];
    __shared__ __align__(16) short Ih[64*68];
    __shared__ __align__(16) short Il[64*68];
    __shared__ float ash[32], bbsh[32];
    int tid = threadIdx.x;
    int wave = tid >> 6, l = tid & 63;
    int g = l >> 5, c = l & 31;
    int rowhalf = (wave >> 1) * 32, colhalf = (wave & 1) * 32;

    if(tid < 32){
        float mu=stats[192+tid], sc=stats[224+tid];
        ash[tid]=sc; bbsh[tid]=be2[tid]-mu*sc;
    }
    // stage W3^T [64 col][32 k] into Ih/Il scratch, hoist
    if(tid < 128){
        int col = tid >> 1, kseg = (tid & 1) * 16;
        short hi[16], lo[16];
        #pragma unroll
        for(int j=0;j<16;++j){
            float v = W3[(kseg+j)*64 + col];
            short h = f2bf_rne(v);
            hi[j] = h; lo[j] = f2bf_rne(v - bf2f(h));
        }
        #pragma unroll
        for(int i=0;i<4;++i){
            *(short4v*)&Ih[col*36 + kseg + 4*i] = *(short4v*)&hi[4*i];
            *(short4v*)&Il[col*36 + kseg + 4*i] = *(short4v*)&lo[4*i];
        }
    }
    __syncthreads();
    short8v w3h[2], w3l[2];
    #pragma unroll
    for(int s=0;s<2;++s){
        int base = (colhalf + c)*36 + s*16 + g*4;
        ((short4v*)&w3h[s])[0] = *(short4v*)&Ih[base];
        ((short4v*)&w3h[s])[1] = *(short4v*)&Ih[base + 8];
        ((short4v*)&w3l[s])[0] = *(short4v*)&Il[base];
        ((short4v*)&w3l[s])[1] = *(short4v*)&Il[base + 8];
    }
    __syncthreads();
    // stage Wo1b^T [64 col][64 k] into Ih/Il scratch, hoist
    {
        int col = tid >> 2, kseg = (tid & 3) * 16;
        short hi[16], lo[16];
        #pragma unroll
        for(int j=0;j<16;++j){
            float v = Wo1[4096 + (kseg+j)*64 + col];
            short h = f2bf_rne(v);
            hi[j] = h; lo[j] = f2bf_rne(v - bf2f(h));
        }
        #pragma unroll
        for(int i=0;i<4;++i){
            *(short4v*)&Ih[col*68 + kseg + 4*i] = *(short4v*)&hi[4*i];
            *(short4v*)&Il[col*68 + kseg + 4*i] = *(short4v*)&lo[4*i];
        }
    }
    __syncthreads();
    short8v w2h[4], w2l[4];
    #pragma unroll
    for(int s=0;s<4;++s){
        int base = (colhalf + c)*68 + s*16 + g*4;
        ((short4v*)&w2h[s])[0] = *(short4v*)&Ih[base];
        ((short4v*)&w2h[s])[1] = *(short4v*)&Ih[base + 8];
        ((short4v*)&w2l[s])[0] = *(short4v*)&Il[base];
        ((short4v*)&w2l[s])[1] = *(short4v*)&Il[base + 8];
    }
    __syncthreads();

    int U = (int)Ucnt[0];
    float bc3 = b3[colhalf + c];

    const int NT = (N_PREV + 63) / 64;
    for(int tile = blockIdx.x; tile < NT; tile += gridDim.x){
        int rbase = tile * 64;
        if(rbase >= U) break;
        if(tid < 128){
            int row = tid >> 1, kseg = (tid & 1) * 16;
            int grow = rbase + row;
            float fv[16];
            if(grow < U){
                const float4* fp = (const float4*)&x2[grow*32 + kseg];
                *(float4*)&fv[0]=fp[0]; *(float4*)&fv[4]=fp[1];
                *(float4*)&fv[8]=fp[2]; *(float4*)&fv[12]=fp[3];
                #pragma unroll
                for(int j=0;j<16;++j) fv[j] = fv[j]*ash[kseg+j] + bbsh[kseg+j];
            } else {
                #pragma unroll
                for(int j=0;j<16;++j) fv[j]=0.f;
            }
            short hi[16], lo[16];
            #pragma unroll
            for(int j=0;j<16;++j){
                short h = f2bf_rne(fv[j]);
                hi[j] = h; lo[j] = f2bf_rne(fv[j] - bf2f(h));
            }
            #pragma unroll
            for(int i=0;i<4;++i){
                *(short4v*)&Ah[row*36 + kseg + 4*i] = *(short4v*)&hi[4*i];
                *(short4v*)&Al[row*36 + kseg + 4*i] = *(short4v*)&lo[4*i];
            }
        }
        __syncthreads();
        f32x16 acc;
        #pragma unroll
        for(int i=0;i<16;++i) acc[i]=0.f;
        #pragma unroll
        for(int s=0;s<2;++s){
            int abase = (rowhalf + c)*36 + s*16 + g*4;
            short8v ah, al;
            ((short4v*)&ah)[0] = *(short4v*)&Ah[abase];
            ((short4v*)&ah)[1] = *(short4v*)&Ah[abase + 8];
            ((short4v*)&al)[0] = *(short4v*)&Al[abase];
            ((short4v*)&al)[1] = *(short4v*)&Al[abase + 8];
            acc = __builtin_amdgcn_mfma_f32_32x32x16_bf16(ah, w3h[s], acc, 0,0,0);
            acc = __builtin_amdgcn_mfma_f32_32x32x16_bf16(al, w3h[s], acc, 0,0,0);
            acc = __builtin_amdgcn_mfma_f32_32x32x16_bf16(ah, w3l[s], acc, 0,0,0);
        }
        #pragma unroll
        for(int r=0;r<16;++r){
            int row = rowhalf + (r&3) + 8*(r>>2) + 4*g;
            float v = acc[r] + bc3;
            v = v > 0.f ? v : 0.1f*v;
            short h = f2bf_rne(v);
            Ih[row*68 + colhalf + c] = h;
            Il[row*68 + colhalf + c] = f2bf_rne(v - bf2f(h));
        }
        __syncthreads();
        f32x16 acc2;
        #pragma unroll
        for(int i=0;i<16;++i) acc2[i]=0.f;
        #pragma unroll
        for(int s=0;s<4;++s){
            int abase = (rowhalf + c)*68 + s*16 + g*4;
            short8v ah, al;
            ((short4v*)&ah)[0] = *(short4v*)&Ih[abase];
            ((short4v*)&ah)[1] = *(short4v*)&Ih[abase + 8];
            ((short4v*)&al)[0] = *(short4v*)&Il[abase];
            ((short4v*)&al)[1] = *(short4v*)&Il[abase + 8];
            acc2 = __builtin_amdgcn_mfma_f32_32x32x16_bf16(ah, w2h[s], acc2, 0,0,0);
            acc2 = __builtin_amdgcn_mfma_f32_32x32x16_bf16(al, w2h[s], acc2, 0,0,0);
            acc2 = __builtin_amdgcn_mfma_f32_32x32x16_bf16(ah, w2l[s], acc2, 0,0,0);
        }
        #pragma unroll
        for(int r=0;r<16;++r){
            int grow = rbase + rowhalf + (r&3) + 8*(r>>2) + 4*g;
            if(grow < U) P2[grow*64 + colhalf + c] = acc2[r];
        }
        __syncthreads();
    }
}

// ---- one wave per voxel: T = Σ lrelu(P1[j]+P2[h]+bo1); out = (T@Wo2 + cnt*bo2)/max(cnt,1) ----
__global__ void __launch_bounds__(256) k_vox(const unsigned* __restrict__ vstart,
        const int* __restrict__ csr_j, const int* __restrict__ csr_h,
        const float* __restrict__ P1, const float* __restrict__ P2,
        const float* __restrict__ bo1, const float* __restrict__ Wo2,
        const float* __restrict__ bo2, float* __restrict__ out){
    __shared__ float tsh[4][64];
    int tid = threadIdx.x;
    int wib = tid>>6, lane = tid&63;
    float wreg[64];
    #pragma unroll
    for(int k=0;k<64;++k) wreg[k] = Wo2[k*64+lane];
    float b1 = bo1[lane], b2 = bo2[lane];
    int wglobal = blockIdx.x*4 + wib;
    for(int vq=0; vq<4; ++vq){
        int vox = wglobal*4 + vq;
        int s = (int)vstart[vox], e = (int)vstart[vox+1];
        float acc = 0.f;
        for(int i=s; i<e; i+=64){
            int n = min(e-i, 64);
            int jv=0, hv=0;
            if(lane<n){ jv = csr_j[i+lane]; hv = csr_h[i+lane]; }
            for(int q=0;q<n;++q){
                int j = __shfl(jv,q), h = __shfl(hv,q);
                float g = P1[j*64+lane] + P2[h*64+lane] + b1;
                acc += (g>0.f) ? g : 0.1f*g;
            }
        }
        tsh[wib][lane] = acc;
        float dot = 0.f;
        const float4* t4 = (const float4*)tsh[wib];
        #pragma unroll
        for(int k4=0;k4<16;++k4){
            float4 t = t4[k4];
            dot += t.x*wreg[4*k4] + t.y*wreg[4*k4+1] + t.z*wreg[4*k4+2] + t.w*wreg[4*k4+3];
        }
        float cntv = (float)(e - s);
        out[vox*64+lane] = (dot + cntv*b2) / fmaxf(cntv, 1.f);
    }
}

extern "C" void kernel_launch(void* const* d_in, const int* in_sizes, int n_in,
                              void* d_out, int out_size, void* d_ws, size_t ws_size,
                              hipStream_t stream) {
    if(ws_size < WS_NEEDED) return;

    const float* features = (const float*)d_in[0];
    const int*   coors    = (const int*)d_in[1];
    const int*   cif      = (const int*)d_in[2];
    const int*   scv      = (const int*)d_in[3];
    const float* W_in     = (const float*)d_in[4];
    const float* b_in     = (const float*)d_in[5];
    const float* W1       = (const float*)d_in[6];
    const float* b1       = (const float*)d_in[7];
    const float* g1       = (const float*)d_in[8];
    const float* be1      = (const float*)d_in[9];
    const float* W2       = (const float*)d_in[10];
    const float* b2       = (const float*)d_in[11];
    const float* g2       = (const float*)d_in[12];
    const float* be2      = (const float*)d_in[13];
    const float* W3       = (const float*)d_in[14];
    const float* b3       = (const float*)d_in[15];
    const float* Wo1      = (const float*)d_in[16];
    const float* bo1      = (const float*)d_in[17];
    const float* Wo2      = (const float*)d_in[18];
    const float* bo2      = (const float*)d_in[19];

    char* ws = (char*)d_ws;
    unsigned* bitmap = (unsigned*)(ws + OFF_BITMAP);
    float*    stats  = (float*)(ws + OFF_STATS);
    float*    cnt    = (float*)(ws + OFF_CNT);
    unsigned* vh     = (unsigned*)(ws + OFF_VH);
    float*    pooled = (float*)(ws + OFF_POOLED);
    unsigned* pref   = (unsigned*)(ws + OFF_PREF);
    unsigned* bsum   = (unsigned*)(ws + OFF_BSUM);
    unsigned* boff   = (unsigned*)(ws + OFF_BOFF);
    unsigned* Ucnt   = (unsigned*)(ws + OFF_UCNT);
    float*    x1     = (float*)(ws + OFF_X1);
    float*    x2     = (float*)(ws + OFF_X2);
    int*      inv    = (int*)(ws + OFF_INV);
    float*    P1     = (float*)(ws + OFF_X1);
    float*    P2     = pooled;
    int*      csr_j  = (int*)(ws + OFF_CSRJ);
    int*      csr_h  = (int*)(ws + OFF_CSRH);
    unsigned* vstart = (unsigned*)(ws + OFF_VSTART);
    unsigned* vnext  = (unsigned*)(ws + OFF_VNEXT);
    unsigned* vpart  = (unsigned*)(ws + OFF_VPART);
    unsigned* vbsum  = (unsigned*)(ws + OFF_VBSUM);

    hipMemsetAsync(d_ws, 0, ZERO_BYTES, stream);

    k_mark  <<<(N_PREV+255)/256, 256, 0, stream>>>(coors, bitmap);
    k_scanA <<<1024, 1024, 0, stream>>>(bitmap, pref, bsum);
    k_scanB <<<1, 1024, 0, stream>>>(bsum, boff, Ucnt);
    k_rank  <<<N_PREV/4, 256, 0, stream>>>(coors, features, bitmap, pref, boff, inv, cnt, pooled);
    k_vhist <<<(N_FULL+255)/256, 256, 0, stream>>>(scv, vh);
    k_vscanA<<<64, 1024, 0, stream>>>(vh, vpart, vbsum);
    k_vscanB<<<1, 64, 0, stream>>>(vbsum);
    k_vfix  <<<64, 1024, 0, stream>>>(vpart, vbsum, vstart, vnext);
    k_fill  <<<(N_FULL+255)/256, 256, 0, stream>>>(cif, scv, inv, vnext, csr_j, csr_h);
    k_ppm1 <<<1024, 256, 0, stream>>>(pooled, cnt, Ucnt, W1, b1, x1, stats);
    k_bnfin<<<1, 32, 0, stream>>>(Ucnt, g1, stats, 0);
    k_ppm2 <<<1024, 256, 0, stream>>>(x1, Ucnt, W2, b2, be1, x2, stats);
    k_bnfin<<<1, 32, 0, stream>>>(Ucnt, g2, stats, 128);
    k_ppm3 <<<1024, 256, 0, stream>>>(x2, Ucnt, W3, b3, be2, Wo1, P2, stats);
    k_p1   <<<1024, 256, 0, stream>>>(features, W_in, b_in, Wo1, P1);
    k_vox  <<<NVOX/16, 256, 0, stream>>>(vstart, csr_j, csr_h, P1, P2, bo1, Wo2, bo2, (float*)d_out);
}

// Round 6
// 337.033 us; speedup vs baseline: 2.8799x; 1.1657x over previous
//
#include <hip/hip_runtime.h>

#define N_PREV 250000
#define N_FULL 500000
#define NVOX   65536
#define NWORDS (1u<<20)          // bitmap words; keyspace < 2^25 bits
#define EPSF   1e-5f

typedef __attribute__((ext_vector_type(4)))  short short4v;
typedef __attribute__((ext_vector_type(8)))  short short8v;
typedef __attribute__((ext_vector_type(16))) float f32x16;

__device__ __forceinline__ float lrelu(float x){ return x > 0.0f ? x : 0.1f*x; }
__device__ __forceinline__ short f2bf_rne(float v){
    unsigned u = __float_as_uint(v);
    unsigned r = (u + 0x7fffu + ((u>>16)&1u)) >> 16;
    return (short)r;
}
__device__ __forceinline__ float bf2f(short s){
    return __uint_as_float(((unsigned)(unsigned short)s) << 16);
}

// ---------------- ws layout (bytes) ----------------
// zeroed prefix:
#define OFF_BITMAP   0ul            // u32[NWORDS] (aliased as csr_j/csr_h after k_p1f)
#define OFF_STATS    4194304ul      // f32[256]
#define OFF_CNT      4195328ul      // f32[N_PREV]
#define OFF_VH       5195328ul      // u32[NVOX]
#define OFF_Y        5457472ul      // f32[N_PREV*32]  32 MB  (y = scattered F@W1; dead after ppm2)
#define ZERO_BYTES   37457472ul
// not zeroed:
#define OFF_P2       37457472ul     // bf16[N_PREV*64] 32 MB  (written by ppm3, after y dead)
#define OFF_PREF     69457472ul     // u32[NWORDS] (aliased as vstart/vnext/vpart/vbsum after p1f)
#define OFF_BSUM     73651776ul
#define OFF_BOFF     73655872ul
#define OFF_UCNT     73659968ul
#define OFF_INV      73660224ul     // i32[N_PREV]
#define OFF_P1       74660224ul     // bf16[N_PREV*64] 32 MB (written by p1f, read by vox)
#define OFF_X2       106660224ul    // f32[N_PREV*32]  32 MB (ppm2 -> ppm3)
#define WS_NEEDED    138660224ul
#define OFF_CSRJ     0ul
#define OFF_CSRH     2000000ul
#define OFF_VSTART   69457472ul
#define OFF_VNEXT    (OFF_VSTART+262400ul)
#define OFF_VPART    (OFF_VNEXT+262144ul)
#define OFF_VBSUM    (OFF_VPART+262144ul)

__device__ __forceinline__ int voxel_key(int4 c){
    return ((c.x*501 + (c.y>>1))*501 + (c.z>>1))*31 + (c.w>>1);
}

// ---- mark present keys ----
__global__ void k_mark(const int* __restrict__ coors, unsigned* __restrict__ bitmap){
    int i = blockIdx.x*256 + threadIdx.x;
    if(i >= N_PREV) return;
    int4 c = ((const int4*)coors)[i];
    int key = voxel_key(c);
    atomicOr(&bitmap[key>>5], 1u<<(key&31));
}

__global__ void __launch_bounds__(1024) k_scanA(const unsigned* __restrict__ bitmap,
                                                unsigned* __restrict__ pref,
                                                unsigned* __restrict__ bsum){
    __shared__ unsigned sh[1024];
    int tid = threadIdx.x;
    int w = blockIdx.x*1024 + tid;
    unsigned p = __popc(bitmap[w]);
    sh[tid] = p; __syncthreads();
    for(int off=1; off<1024; off<<=1){
        unsigned v = (tid>=off) ? sh[tid-off] : 0u;
        __syncthreads();
        sh[tid] += v;
        __syncthreads();
    }
    pref[w] = sh[tid] - p;
    if(tid==1023) bsum[blockIdx.x] = sh[tid];
}

__global__ void __launch_bounds__(1024) k_scanB(const unsigned* __restrict__ bsum,
                                                unsigned* __restrict__ boff,
                                                unsigned* __restrict__ Ucnt){
    __shared__ unsigned sh[1024];
    int tid = threadIdx.x;
    unsigned p = bsum[tid];
    sh[tid] = p; __syncthreads();
    for(int off=1; off<1024; off<<=1){
        unsigned v = (tid>=off) ? sh[tid-off] : 0u;
        __syncthreads();
        sh[tid] += v;
        __syncthreads();
    }
    boff[tid] = sh[tid] - p;
    if(tid==1023) Ucnt[0] = sh[tid];
}

// ---- CSR build over scale voxels ----
__global__ void k_vhist(const int* __restrict__ scv, unsigned* __restrict__ vh){
    int p = blockIdx.x*256 + threadIdx.x;
    if(p < N_FULL) atomicAdd(&vh[scv[p]], 1u);
}

__global__ void __launch_bounds__(1024) k_vscanA(const unsigned* __restrict__ vh,
                                                 unsigned* __restrict__ vpart,
                                                 unsigned* __restrict__ vbsum){
    __shared__ unsigned sh[1024];
    int tid = threadIdx.x;
    int w = blockIdx.x*1024 + tid;
    unsigned p = vh[w];
    sh[tid] = p; __syncthreads();
    for(int off=1; off<1024; off<<=1){
        unsigned v = (tid>=off) ? sh[tid-off] : 0u;
        __syncthreads();
        sh[tid] += v;
        __syncthreads();
    }
    vpart[w] = sh[tid] - p;
    if(tid==1023) vbsum[blockIdx.x] = sh[tid];
}

__global__ void k_vscanB(unsigned* __restrict__ vbsum){
    int l = threadIdx.x;
    unsigned v = vbsum[l], orig = v;
    for(int off=1; off<64; off<<=1){
        unsigned o = __shfl_up(v, off);
        if(l>=off) v += o;
    }
    vbsum[l] = v - orig;
}

__global__ void __launch_bounds__(1024) k_vfix(const unsigned* __restrict__ vpart,
                                               const unsigned* __restrict__ vbsum,
                                               unsigned* __restrict__ vstart,
                                               unsigned* __restrict__ vnext){
    int w = blockIdx.x*1024 + threadIdx.x;
    unsigned s = vpart[w] + vbsum[w>>10];
    vstart[w] = s; vnext[w] = s;
    if(w == NVOX-1) vstart[NVOX] = N_FULL;
}

__global__ void k_fill(const int* __restrict__ cif, const int* __restrict__ scv,
                       const int* __restrict__ inv, unsigned* __restrict__ vnext,
                       int* __restrict__ csr_j, int* __restrict__ csr_h){
    int p = blockIdx.x*256 + threadIdx.x;
    if(p >= N_FULL) return;
    int jp = cif[p];
    unsigned pos = atomicAdd(&vnext[scv[p]], 1u);
    csr_j[pos] = jp;
    csr_h[pos] = inv[jp];
}

// ---- fused: P1 = lrelu(F@Win+b)@Wo1a (bf16 out); Y = F@W1 scattered by rank;
//      rank/inv/cnt computed inline.  MFMA 32x32x16 split hi/lo (verified R4/R5). ----
__global__ void __launch_bounds__(256) k_p1f(const float* __restrict__ feat,
        const int* __restrict__ coors, const unsigned* __restrict__ bitmap,
        const unsigned* __restrict__ pref, const unsigned* __restrict__ boff,
        const float* __restrict__ Win, const float* __restrict__ bin,
        const float* __restrict__ Wo1, const float* __restrict__ W1,
        unsigned short* __restrict__ P1, int* __restrict__ inv,
        float* __restrict__ cnt, float* __restrict__ y){
    __shared__ __align__(16) short Ah[64*68];
    __shared__ __align__(16) short Al[64*68];
    __shared__ float ysh[64][33];
    __shared__ int rksh[64];
    int tid = threadIdx.x;
    int wave = tid >> 6, l = tid & 63;
    int g = l >> 5, c = l & 31;
    int rowhalf = (wave >> 1) * 32, colhalf = (wave & 1) * 32;

    // stage Win^T, hoist
    {
        int col = tid >> 2, kseg = (tid & 3) * 16;
        short hi[16], lo[16];
        #pragma unroll
        for(int j=0;j<16;++j){
            float v = Win[(kseg+j)*64 + col];
            short h = f2bf_rne(v);
            hi[j] = h; lo[j] = f2bf_rne(v - bf2f(h));
        }
        #pragma unroll
        for(int i=0;i<4;++i){
            *(short4v*)&Ah[col*68 + kseg + 4*i] = *(short4v*)&hi[4*i];
            *(short4v*)&Al[col*68 + kseg + 4*i] = *(short4v*)&lo[4*i];
        }
    }
    __syncthreads();
    short8v w1h[4], w1l[4];
    #pragma unroll
    for(int s=0;s<4;++s){
        int base = (colhalf + c)*68 + s*16 + g*4;
        ((short4v*)&w1h[s])[0] = *(short4v*)&Ah[base];
        ((short4v*)&w1h[s])[1] = *(short4v*)&Ah[base + 8];
        ((short4v*)&w1l[s])[0] = *(short4v*)&Al[base];
        ((short4v*)&w1l[s])[1] = *(short4v*)&Al[base + 8];
    }
    __syncthreads();
    // stage Wo1a^T, hoist
    {
        int col = tid >> 2, kseg = (tid & 3) * 16;
        short hi[16], lo[16];
        #pragma unroll
        for(int j=0;j<16;++j){
            float v = Wo1[(kseg+j)*64 + col];
            short h = f2bf_rne(v);
            hi[j] = h; lo[j] = f2bf_rne(v - bf2f(h));
        }
        #pragma unroll
        for(int i=0;i<4;++i){
            *(short4v*)&Ah[col*68 + kseg + 4*i] = *(short4v*)&hi[4*i];
            *(short4v*)&Al[col*68 + kseg + 4*i] = *(short4v*)&lo[4*i];
        }
    }
    __syncthreads();
    short8v w2h[4], w2l[4];
    #pragma unroll
    for(int s=0;s<4;++s){
        int base = (colhalf + c)*68 + s*16 + g*4;
        ((short4v*)&w2h[s])[0] = *(short4v*)&Ah[base];
        ((short4v*)&w2h[s])[1] = *(short4v*)&Ah[base + 8];
        ((short4v*)&w2l[s])[0] = *(short4v*)&Al[base];
        ((short4v*)&w2l[s])[1] = *(short4v*)&Al[base + 8];
    }
    __syncthreads();
    // stage W1^T [32 col][64 k], hoist (cols = c for every wave; used by waves 0/1)
    if(tid < 128){
        int col = tid >> 2, kseg = (tid & 3) * 16;
        short hi[16], lo[16];
        #pragma unroll
        for(int j=0;j<16;++j){
            float v = W1[(kseg+j)*32 + col];
            short h = f2bf_rne(v);
            hi[j] = h; lo[j] = f2bf_rne(v - bf2f(h));
        }
        #pragma unroll
        for(int i=0;i<4;++i){
            *(short4v*)&Ah[col*68 + kseg + 4*i] = *(short4v*)&hi[4*i];
            *(short4v*)&Al[col*68 + kseg + 4*i] = *(short4v*)&lo[4*i];
        }
    }
    __syncthreads();
    short8v w0h[4], w0l[4];
    #pragma unroll
    for(int s=0;s<4;++s){
        int base = c*68 + s*16 + g*4;
        ((short4v*)&w0h[s])[0] = *(short4v*)&Ah[base];
        ((short4v*)&w0h[s])[1] = *(short4v*)&Ah[base + 8];
        ((short4v*)&w0l[s])[0] = *(short4v*)&Al[base];
        ((short4v*)&w0l[s])[1] = *(short4v*)&Al[base + 8];
    }
    __syncthreads();

    float bc1 = bin[colhalf + c];

    const int NT = (N_PREV + 63) / 64;
    for(int tile = blockIdx.x; tile < NT; tile += gridDim.x){
        int rbase = tile * 64;
        // stage F tile hi/lo
        {
            int row = tid >> 2, kseg = (tid & 3) * 16;
            int grow = rbase + row;
            float fv[16];
            if(grow < N_PREV){
                const float4* fp = (const float4*)&feat[grow*64 + kseg];
                *(float4*)&fv[0]  = fp[0];
                *(float4*)&fv[4]  = fp[1];
                *(float4*)&fv[8]  = fp[2];
                *(float4*)&fv[12] = fp[3];
            } else {
                #pragma unroll
                for(int j=0;j<16;++j) fv[j]=0.f;
            }
            short hi[16], lo[16];
            #pragma unroll
            for(int j=0;j<16;++j){
                short h = f2bf_rne(fv[j]);
                hi[j] = h; lo[j] = f2bf_rne(fv[j] - bf2f(h));
            }
            #pragma unroll
            for(int i=0;i<4;++i){
                *(short4v*)&Ah[row*68 + kseg + 4*i] = *(short4v*)&hi[4*i];
                *(short4v*)&Al[row*68 + kseg + 4*i] = *(short4v*)&lo[4*i];
            }
        }
        // ranks for this tile's rows
        if(tid < 64){
            int grow = rbase + tid;
            if(grow < N_PREV){
                int4 c4 = ((const int4*)coors)[grow];
                int key = voxel_key(c4);
                int w = key>>5, b = key&31;
                int rank = (int)(boff[w>>10] + pref[w]) + __popc(bitmap[w] & ((1u<<b)-1u));
                rksh[tid] = rank;
                inv[grow] = rank;
                atomicAdd(&cnt[rank], 1.0f);
            } else rksh[tid] = -1;
        }
        __syncthreads();
        // GEMM1: I = lrelu(F@Win + b)  (all waves)
        f32x16 acc;
        #pragma unroll
        for(int i=0;i<16;++i) acc[i]=0.f;
        #pragma unroll
        for(int s=0;s<4;++s){
            int abase = (rowhalf + c)*68 + s*16 + g*4;
            short8v ah, al;
            ((short4v*)&ah)[0] = *(short4v*)&Ah[abase];
            ((short4v*)&ah)[1] = *(short4v*)&Ah[abase + 8];
            ((short4v*)&al)[0] = *(short4v*)&Al[abase];
            ((short4v*)&al)[1] = *(short4v*)&Al[abase + 8];
            acc = __builtin_amdgcn_mfma_f32_32x32x16_bf16(ah, w1h[s], acc, 0,0,0);
            acc = __builtin_amdgcn_mfma_f32_32x32x16_bf16(al, w1h[s], acc, 0,0,0);
            acc = __builtin_amdgcn_mfma_f32_32x32x16_bf16(ah, w1l[s], acc, 0,0,0);
        }
        // GEMM0: Y = F@W1  (waves 0/1: rows wave*32..+31, all 32 cols)
        f32x16 accY;
        #pragma unroll
        for(int i=0;i<16;++i) accY[i]=0.f;
        if(wave < 2){
            #pragma unroll
            for(int s=0;s<4;++s){
                int abase = (wave*32 + c)*68 + s*16 + g*4;
                short8v ah, al;
                ((short4v*)&ah)[0] = *(short4v*)&Ah[abase];
                ((short4v*)&ah)[1] = *(short4v*)&Ah[abase + 8];
                ((short4v*)&al)[0] = *(short4v*)&Al[abase];
                ((short4v*)&al)[1] = *(short4v*)&Al[abase + 8];
                accY = __builtin_amdgcn_mfma_f32_32x32x16_bf16(ah, w0h[s], accY, 0,0,0);
                accY = __builtin_amdgcn_mfma_f32_32x32x16_bf16(al, w0h[s], accY, 0,0,0);
                accY = __builtin_amdgcn_mfma_f32_32x32x16_bf16(ah, w0l[s], accY, 0,0,0);
            }
        }
        __syncthreads();
        // epilogue: I -> LDS hi/lo; Y -> ysh
        #pragma unroll
        for(int r=0;r<16;++r){
            int row = rowhalf + (r&3) + 8*(r>>2) + 4*g;
            float v = acc[r] + bc1;
            v = v > 0.f ? v : 0.1f*v;
            short h = f2bf_rne(v);
            Ah[row*68 + colhalf + c] = h;
            Al[row*68 + colhalf + c] = f2bf_rne(v - bf2f(h));
        }
        if(wave < 2){
            #pragma unroll
            for(int r=0;r<16;++r){
                int row = wave*32 + (r&3) + 8*(r>>2) + 4*g;
                ysh[row][c] = accY[r];
            }
        }
        __syncthreads();
        // GEMM2: P1 = I @ Wo1a
        f32x16 acc2;
        #pragma unroll
        for(int i=0;i<16;++i) acc2[i]=0.f;
        #pragma unroll
        for(int s=0;s<4;++s){
            int abase = (rowhalf + c)*68 + s*16 + g*4;
            short8v ah, al;
            ((short4v*)&ah)[0] = *(short4v*)&Ah[abase];
            ((short4v*)&ah)[1] = *(short4v*)&Ah[abase + 8];
            ((short4v*)&al)[0] = *(short4v*)&Al[abase];
            ((short4v*)&al)[1] = *(short4v*)&Al[abase + 8];
            acc2 = __builtin_amdgcn_mfma_f32_32x32x16_bf16(ah, w2h[s], acc2, 0,0,0);
            acc2 = __builtin_amdgcn_mfma_f32_32x32x16_bf16(al, w2h[s], acc2, 0,0,0);
            acc2 = __builtin_amdgcn_mfma_f32_32x32x16_bf16(ah, w2l[s], acc2, 0,0,0);
        }
        #pragma unroll
        for(int r=0;r<16;++r){
            int grow = rbase + rowhalf + (r&3) + 8*(r>>2) + 4*g;
            if(grow < N_PREV) P1[grow*64 + colhalf + c] = (unsigned short)f2bf_rne(acc2[r]);
        }
        // scatter Y tile into y by rank (f32 atomics)
        #pragma unroll
        for(int q=0;q<8;++q){
            int e = q*256 + tid;
            int row = e >> 5, col = e & 31;
            int rk = rksh[row];
            if(rk >= 0) atomicAdd(&y[rk*32 + col], ysh[row][col]);
        }
        __syncthreads();
    }
}

// ---- BN1 stats over x1 = lrelu(y/cnt + b1)  (stats only, no write) ----
__global__ void __launch_bounds__(256) k_bn1(const float* __restrict__ y,
        const float* __restrict__ cnt, const unsigned* __restrict__ Ucnt,
        const float* __restrict__ b1, float* __restrict__ stats){
    __shared__ float sst[32], qst[32];
    int tid = threadIdx.x;
    if(tid < 32){ sst[tid]=0.f; qst[tid]=0.f; }
    __syncthreads();
    int U = (int)Ucnt[0];
    int total = U*8;
    int col4 = (tid&7)*4;
    float4 bb = *(const float4*)&b1[col4];
    float4 s4 = make_float4(0,0,0,0), q4 = make_float4(0,0,0,0);
    for(int e = blockIdx.x*256 + tid; e < total; e += gridDim.x*256){
        int row = e >> 3;
        float rv = 1.0f/cnt[row];
        float4 v = ((const float4*)y)[e];
        v.x = lrelu(v.x*rv+bb.x); v.y = lrelu(v.y*rv+bb.y);
        v.z = lrelu(v.z*rv+bb.z); v.w = lrelu(v.w*rv+bb.w);
        s4.x+=v.x; s4.y+=v.y; s4.z+=v.z; s4.w+=v.w;
        q4.x+=v.x*v.x; q4.y+=v.y*v.y; q4.z+=v.z*v.z; q4.w+=v.w*v.w;
    }
    atomicAdd(&sst[col4+0], s4.x); atomicAdd(&sst[col4+1], s4.y);
    atomicAdd(&sst[col4+2], s4.z); atomicAdd(&sst[col4+3], s4.w);
    atomicAdd(&qst[col4+0], q4.x); atomicAdd(&qst[col4+1], q4.y);
    atomicAdd(&qst[col4+2], q4.z); atomicAdd(&qst[col4+3], q4.w);
    __syncthreads();
    if(tid < 32){ atomicAdd(&stats[tid], sst[tid]); atomicAdd(&stats[32+tid], qst[tid]); }
}

__global__ void k_bnfin(const unsigned* __restrict__ Ucnt, const float* __restrict__ g,
                        float* __restrict__ stats, int off){
    int c = threadIdx.x;
    if(c>=32) return;
    float n = (float)max(Ucnt[0], 1u);
    float mu = stats[off+c]/n;
    float var = stats[off+32+c]/n - mu*mu;
    stats[off+64+c] = mu;
    stats[off+96+c] = g[c]*rsqrtf(var + EPSF);
}

// ---- x2 = lrelu(BN1(lrelu(y/cnt+b1)) @ W2 + b2), BN2 stats.  MFMA 128x32, k=32 ----
__global__ void __launch_bounds__(256) k_ppm2(const float* __restrict__ y,
        const float* __restrict__ cnt, const unsigned* __restrict__ Ucnt,
        const float* __restrict__ W2, const float* __restrict__ b1i,
        const float* __restrict__ b2, const float* __restrict__ be1,
        float* __restrict__ x2, float* __restrict__ stats){
    __shared__ __align__(16) short Ah[128*36];
    __shared__ __align__(16) short Al[128*36];
    __shared__ float ash[32], bbsh[32], b1sh[32];
    __shared__ float red[4][64];
    int tid = threadIdx.x;
    int wave = tid >> 6, l = tid & 63;
    int g = l >> 5, c = l & 31;

    if(tid < 32){
        float mu=stats[64+tid], sc=stats[96+tid];
        ash[tid]=sc; bbsh[tid]=be1[tid]-mu*sc;
        b1sh[tid]=b1i[tid];
    }
    if(tid >= 64 && tid < 128){
        int t = tid - 64;
        int col = t >> 1, kseg = (t & 1) * 16;
        short hi[16], lo[16];
        #pragma unroll
        for(int j=0;j<16;++j){
            float v = W2[(kseg+j)*32 + col];
            short h = f2bf_rne(v);
            hi[j] = h; lo[j] = f2bf_rne(v - bf2f(h));
        }
        #pragma unroll
        for(int i=0;i<4;++i){
            *(short4v*)&Ah[col*36 + kseg + 4*i] = *(short4v*)&hi[4*i];
            *(short4v*)&Al[col*36 + kseg + 4*i] = *(short4v*)&lo[4*i];
        }
    }
    __syncthreads();
    short8v wh[2], wl[2];
    #pragma unroll
    for(int s=0;s<2;++s){
        int base = c*36 + s*16 + g*4;
        ((short4v*)&wh[s])[0] = *(short4v*)&Ah[base];
        ((short4v*)&wh[s])[1] = *(short4v*)&Ah[base + 8];
        ((short4v*)&wl[s])[0] = *(short4v*)&Al[base];
        ((short4v*)&wl[s])[1] = *(short4v*)&Al[base + 8];
    }
    __syncthreads();

    int U = (int)Ucnt[0];
    float bc = b2[c];
    float s_acc = 0.f, q_acc = 0.f;

    const int NT = (N_PREV + 127) / 128;
    for(int tile = blockIdx.x; tile < NT; tile += gridDim.x){
        int rbase = tile * 128;
        if(rbase >= U) break;
        {
            int row = tid >> 1, kseg = (tid & 1) * 16;
            int grow = rbase + row;
            float fv[16];
            if(grow < U){
                float rv = 1.0f/cnt[grow];
                const float4* fp = (const float4*)&y[grow*32 + kseg];
                *(float4*)&fv[0]=fp[0]; *(float4*)&fv[4]=fp[1];
                *(float4*)&fv[8]=fp[2]; *(float4*)&fv[12]=fp[3];
                #pragma unroll
                for(int j=0;j<16;++j){
                    float v = lrelu(fv[j]*rv + b1sh[kseg+j]);      // x1
                    fv[j] = v*ash[kseg+j] + bbsh[kseg+j];           // BN1
                }
            } else {
                #pragma unroll
                for(int j=0;j<16;++j) fv[j]=0.f;
            }
            short hi[16], lo[16];
            #pragma unroll
            for(int j=0;j<16;++j){
                short h = f2bf_rne(fv[j]);
                hi[j] = h; lo[j] = f2bf_rne(fv[j] - bf2f(h));
            }
            #pragma unroll
            for(int i=0;i<4;++i){
                *(short4v*)&Ah[row*36 + kseg + 4*i] = *(short4v*)&hi[4*i];
                *(short4v*)&Al[row*36 + kseg + 4*i] = *(short4v*)&lo[4*i];
            }
        }
        __syncthreads();
        f32x16 acc;
        #pragma unroll
        for(int i=0;i<16;++i) acc[i]=0.f;
        #pragma unroll
        for(int s=0;s<2;++s){
            int abase = (wave*32 + c)*36 + s*16 + g*4;
            short8v ah, al;
            ((short4v*)&ah)[0] = *(short4v*)&Ah[abase];
            ((short4v*)&ah)[1] = *(short4v*)&Ah[abase + 8];
            ((short4v*)&al)[0] = *(short4v*)&Al[abase];
            ((short4v*)&al)[1] = *(short4v*)&Al[abase + 8];
            acc = __builtin_amdgcn_mfma_f32_32x32x16_bf16(ah, wh[s], acc, 0,0,0);
            acc = __builtin_amdgcn_mfma_f32_32x32x16_bf16(al, wh[s], acc, 0,0,0);
            acc = __builtin_amdgcn_mfma_f32_32x32x16_bf16(ah, wl[s], acc, 0,0,0);
        }
        #pragma unroll
        for(int r=0;r<16;++r){
            int rl = wave*32 + (r&3) + 8*(r>>2) + 4*g;
            int grow = rbase + rl;
            if(grow < U){
                float v = acc[r] + bc;
                v = v > 0.f ? v : 0.1f*v;
                x2[grow*32 + c] = v;
                s_acc += v; q_acc += v*v;
            }
        }
        __syncthreads();
    }
    s_acc += __shfl_xor(s_acc, 32);
    q_acc += __shfl_xor(q_acc, 32);
    if(l < 32){ red[wave][c] = s_acc; red[wave][32+c] = q_acc; }
    __syncthreads();
    if(tid < 64){
        float t = red[0][tid]+red[1][tid]+red[2][tid]+red[3][tid];
        atomicAdd(&stats[128+tid], t);
    }
}

// ---- P2 = lrelu(BN2(x2) @ W3 + b3) @ Wo1b  [U,64] bf16.  MFMA 64x64 ----
__global__ void __launch_bounds__(256) k_ppm3(const float* __restrict__ x2,
        const unsigned* __restrict__ Ucnt, const float* __restrict__ W3,
        const float* __restrict__ b3, const float* __restrict__ be2,
        const float* __restrict__ Wo1, unsigned short* __restrict__ P2,
        const float* __restrict__ stats){
    __shared__ __align__(16) short Ah[64*36];
    __shared__ __align__(16) short Al[64*36];
    __shared__ __align__(16) short Ih[64*68];
    __shared__ __align__(16) short Il[64*68];
    __shared__ float ash[32], bbsh[32];
    int tid = threadIdx.x;
    int wave = tid >> 6, l = tid & 63;
    int g = l >> 5, c = l & 31;
    int rowhalf = (wave >> 1) * 32, colhalf = (wave & 1) * 32;

    if(tid < 32){
        float mu=stats[192+tid], sc=stats[224+tid];
        ash[tid]=sc; bbsh[tid]=be2[tid]-mu*sc;
    }
    if(tid >= 128){
        int t = tid - 128;
        int col = t >> 1, kseg = (t & 1) * 16;
        short hi[16], lo[16];
        #pragma unroll
        for(int j=0;j<16;++j){
            float v = W3[(kseg+j)*64 + col];
            short h = f2bf_rne(v);
            hi[j] = h; lo[j] = f2bf_rne(v - bf2f(h));
        }
        #pragma unroll
        for(int i=0;i<4;++i){
            *(short4v*)&Ih[col*36 + kseg + 4*i] = *(short4v*)&hi[4*i];
            *(short4v*)&Il[col*36 + kseg + 4*i] = *(short4v*)&lo[4*i];
        }
    }
    __syncthreads();
    short8v w3h[2], w3l[2];
    #pragma unroll
    for(int s=0;s<2;++s){
        int base = (colhalf + c)*36 + s*16 + g*4;
        ((short4v*)&w3h[s])[0] = *(short4v*)&Ih[base];
        ((short4v*)&w3h[s])[1] = *(short4v*)&Ih[base + 8];
        ((short4v*)&w3l[s])[0] = *(short4v*)&Il[base];
        ((short4v*)&w3l[s])[1] = *(short4v*)&Il[base + 8];
    }
    __syncthreads();
    {
        int col = tid >> 2, kseg = (tid & 3) * 16;
        short hi[16], lo[16];
        #pragma unroll
        for(int j=0;j<16;++j){
            float v = Wo1[4096 + (kseg+j)*64 + col];
            short h = f2bf_rne(v);
            hi[j] = h; lo[j] = f2bf_rne(v - bf2f(h));
        }
        #pragma unroll
        for(int i=0;i<4;++i){
            *(short4v*)&Ih[col*68 + kseg + 4*i] = *(short4v*)&hi[4*i];
            *(short4v*)&Il[col*68 + kseg + 4*i] = *(short4v*)&lo[4*i];
        }
    }
    __syncthreads();
    short8v w2h[4], w2l[4];
    #pragma unroll
    for(int s=0;s<4;++s){
        int base = (colhalf + c)*68 + s*16 + g*4;
        ((short4v*)&w2h[s])[0] = *(short4v*)&Ih[base];
        ((short4v*)&w2h[s])[1] = *(short4v*)&Ih[base + 8];
        ((short4v*)&w2l[s])[0] = *(short4v*)&Il[base];
        ((short4v*)&w2l[s])[1] = *(short4v*)&Il[base + 8];
    }
    __syncthreads();

    int U = (int)Ucnt[0];
    float bc3 = b3[colhalf + c];

    const int NT = (N_PREV + 63) / 64;
    for(int tile = blockIdx.x; tile < NT; tile += gridDim.x){
        int rbase = tile * 64;
        if(rbase >= U) break;
        if(tid < 128){
            int row = tid >> 1, kseg = (tid & 1) * 16;
            int grow = rbase + row;
            float fv[16];
            if(grow < U){
                const float4* fp = (const float4*)&x2[grow*32 + kseg];
                *(float4*)&fv[0]=fp[0]; *(float4*)&fv[4]=fp[1];
                *(float4*)&fv[8]=fp[2]; *(float4*)&fv[12]=fp[3];
                #pragma unroll
                for(int j=0;j<16;++j) fv[j] = fv[j]*ash[kseg+j] + bbsh[kseg+j];
            } else {
                #pragma unroll
                for(int j=0;j<16;++j) fv[j]=0.f;
            }
            short hi[16], lo[16];
            #pragma unroll
            for(int j=0;j<16;++j){
                short h = f2bf_rne(fv[j]);
                hi[j] = h; lo[j] = f2bf_rne(fv[j] - bf2f(h));
            }
            #pragma unroll
            for(int i=0;i<4;++i){
                *(short4v*)&Ah[row*36 + kseg + 4*i] = *(short4v*)&hi[4*i];
                *(short4v*)&Al[row*36 + kseg + 4*i] = *(short4v*)&lo[4*i];
            }
        }
        __syncthreads();
        f32x16 acc;
        #pragma unroll
        for(int i=0;i<16;++i) acc[i]=0.f;
        #pragma unroll
        for(int s=0;s<2;++s){
            int abase = (rowhalf + c)*36 + s*16 + g*4;
            short8v ah, al;
            ((short4v*)&ah)[0] = *(short4v*)&Ah[abase];
            ((short4v*)&ah)[1] = *(short4v*)&Ah[abase + 8];
            ((short4v*)&al)[0] = *(short4v*)&Al[abase];
            ((short4v*)&al)[1] = *(short4v*)&Al[abase + 8];
            acc = __builtin_amdgcn_mfma_f32_32x32x16_bf16(ah, w3h[s], acc, 0,0,0);
            acc = __builtin_amdgcn_mfma_f32_32x32x16_bf16(al, w3h[s], acc, 0,0,0);
            acc = __builtin_amdgcn_mfma_f32_32x32x16_bf16(ah, w3l[s], acc, 0,0,0);
        }
        #pragma unroll
        for(int r=0;r<16;++r){
            int row = rowhalf + (r&3) + 8*(r>>2) + 4*g;
            float v = acc[r] + bc3;
            v = v > 0.f ? v : 0.1f*v;
            short h = f2bf_rne(v);
            Ih[row*68 + colhalf + c] = h;
            Il[row*68 + colhalf + c] = f2bf_rne(v - bf2f(h));
        }
        __syncthreads();
        f32x16 acc2;
        #pragma unroll
        for(int i=0;i<16;++i) acc2[i]=0.f;
        #pragma unroll
        for(int s=0;s<4;++s){
            int abase = (rowhalf + c)*68 + s*16 + g*4;
            short8v ah, al;
            ((short4v*)&ah)[0] = *(short4v*)&Ih[abase];
            ((short4v*)&ah)[1] = *(short4v*)&Ih[abase + 8];
            ((short4v*)&al)[0] = *(short4v*)&Il[abase];
            ((short4v*)&al)[1] = *(short4v*)&Il[abase + 8];
            acc2 = __builtin_amdgcn_mfma_f32_32x32x16_bf16(ah, w2h[s], acc2, 0,0,0);
            acc2 = __builtin_amdgcn_mfma_f32_32x32x16_bf16(al, w2h[s], acc2, 0,0,0);
            acc2 = __builtin_amdgcn_mfma_f32_32x32x16_bf16(ah, w2l[s], acc2, 0,0,0);
        }
        #pragma unroll
        for(int r=0;r<16;++r){
            int grow = rbase + rowhalf + (r&3) + 8*(r>>2) + 4*g;
            if(grow < U) P2[grow*64 + colhalf + c] = (unsigned short)f2bf_rne(acc2[r]);
        }
        __syncthreads();
    }
}

// ---- one wave per voxel (bf16 P1/P2 gather) ----
__global__ void __launch_bounds__(256) k_vox(const unsigned* __restrict__ vstart,
        const int* __restrict__ csr_j, const int* __restrict__ csr_h,
        const unsigned short* __restrict__ P1, const unsigned short* __restrict__ P2,
        const float* __restrict__ bo1, const float* __restrict__ Wo2,
        const float* __restrict__ bo2, float* __restrict__ out){
    __shared__ float tsh[4][64];
    int tid = threadIdx.x;
    int wib = tid>>6, lane = tid&63;
    float wreg[64];
    #pragma unroll
    for(int k=0;k<64;++k) wreg[k] = Wo2[k*64+lane];
    float b1 = bo1[lane], b2 = bo2[lane];
    int wglobal = blockIdx.x*4 + wib;
    for(int vq=0; vq<4; ++vq){
        int vox = wglobal*4 + vq;
        int s = (int)vstart[vox], e = (int)vstart[vox+1];
        float acc = 0.f;
        for(int i=s; i<e; i+=64){
            int n = min(e-i, 64);
            int jv=0, hv=0;
            if(lane<n){ jv = csr_j[i+lane]; hv = csr_h[i+lane]; }
            for(int q=0;q<n;++q){
                int j = __shfl(jv,q), h = __shfl(hv,q);
                float g = bf2f((short)P1[j*64+lane]) + bf2f((short)P2[h*64+lane]) + b1;
                acc += (g>0.f) ? g : 0.1f*g;
            }
        }
        tsh[wib][lane] = acc;
        float dot = 0.f;
        const float4* t4 = (const float4*)tsh[wib];
        #pragma unroll
        for(int k4=0;k4<16;++k4){
            float4 t = t4[k4];
            dot += t.x*wreg[4*k4] + t.y*wreg[4*k4+1] + t.z*wreg[4*k4+2] + t.w*wreg[4*k4+3];
        }
        float cntv = (float)(e - s);
        out[vox*64+lane] = (dot + cntv*b2) / fmaxf(cntv, 1.f);
    }
}

extern "C" void kernel_launch(void* const* d_in, const int* in_sizes, int n_in,
                              void* d_out, int out_size, void* d_ws, size_t ws_size,
                              hipStream_t stream) {
    if(ws_size < WS_NEEDED) return;

    const float* features = (const float*)d_in[0];
    const int*   coors    = (const int*)d_in[1];
    const int*   cif      = (const int*)d_in[2];
    const int*   scv      = (const int*)d_in[3];
    const float* W_in     = (const float*)d_in[4];
    const float* b_in     = (const float*)d_in[5];
    const float* W1       = (const float*)d_in[6];
    const float* b1       = (const float*)d_in[7];
    const float* g1       = (const float*)d_in[8];
    const float* be1      = (const float*)d_in[9];
    const float* W2       = (const float*)d_in[10];
    const float* b2       = (const float*)d_in[11];
    const float* g2       = (const float*)d_in[12];
    const float* be2      = (const float*)d_in[13];
    const float* W3       = (const float*)d_in[14];
    const float* b3       = (const float*)d_in[15];
    const float* Wo1      = (const float*)d_in[16];
    const float* bo1      = (const float*)d_in[17];
    const float* Wo2      = (const float*)d_in[18];
    const float* bo2      = (const float*)d_in[19];

    char* ws = (char*)d_ws;
    unsigned* bitmap = (unsigned*)(ws + OFF_BITMAP);
    float*    stats  = (float*)(ws + OFF_STATS);
    float*    cnt    = (float*)(ws + OFF_CNT);
    unsigned* vh     = (unsigned*)(ws + OFF_VH);
    float*    y      = (float*)(ws + OFF_Y);
    unsigned short* P2 = (unsigned short*)(ws + OFF_P2);
    unsigned* pref   = (unsigned*)(ws + OFF_PREF);
    unsigned* bsum   = (unsigned*)(ws + OFF_BSUM);
    unsigned* boff   = (unsigned*)(ws + OFF_BOFF);
    unsigned* Ucnt   = (unsigned*)(ws + OFF_UCNT);
    int*      inv    = (int*)(ws + OFF_INV);
    unsigned short* P1 = (unsigned short*)(ws + OFF_P1);
    float*    x2     = (float*)(ws + OFF_X2);
    int*      csr_j  = (int*)(ws + OFF_CSRJ);
    int*      csr_h  = (int*)(ws + OFF_CSRH);
    unsigned* vstart = (unsigned*)(ws + OFF_VSTART);
    unsigned* vnext  = (unsigned*)(ws + OFF_VNEXT);
    unsigned* vpart  = (unsigned*)(ws + OFF_VPART);
    unsigned* vbsum  = (unsigned*)(ws + OFF_VBSUM);

    hipMemsetAsync(d_ws, 0, ZERO_BYTES, stream);

    k_mark  <<<(N_PREV+255)/256, 256, 0, stream>>>(coors, bitmap);
    k_scanA <<<1024, 1024, 0, stream>>>(bitmap, pref, bsum);
    k_scanB <<<1, 1024, 0, stream>>>(bsum, boff, Ucnt);
    k_p1f   <<<1024, 256, 0, stream>>>(features, coors, bitmap, pref, boff,
                                       W_in, b_in, Wo1, W1, P1, inv, cnt, y);
    // CSR build (overwrites bitmap/pref regions — safe after k_p1f)
    k_vhist <<<(N_FULL+255)/256, 256, 0, stream>>>(scv, vh);
    k_vscanA<<<64, 1024, 0, stream>>>(vh, vpart, vbsum);
    k_vscanB<<<1, 64, 0, stream>>>(vbsum);
    k_vfix  <<<64, 1024, 0, stream>>>(vpart, vbsum, vstart, vnext);
    k_fill  <<<(N_FULL+255)/256, 256, 0, stream>>>(cif, scv, inv, vnext, csr_j, csr_h);
    // PPmodel chain
    k_bn1   <<<1024, 256, 0, stream>>>(y, cnt, Ucnt, b1, stats);
    k_bnfin <<<1, 32, 0, stream>>>(Ucnt, g1, stats, 0);
    k_ppm2  <<<1024, 256, 0, stream>>>(y, cnt, Ucnt, W2, b1, b2, be1, x2, stats);
    k_bnfin <<<1, 32, 0, stream>>>(Ucnt, g2, stats, 128);
    k_ppm3  <<<1024, 256, 0, stream>>>(x2, Ucnt, W3, b3, be2, Wo1, P2, stats);
    k_vox   <<<NVOX/16, 256, 0, stream>>>(vstart, csr_j, csr_h, P1, P2, bo1, Wo2, bo2, (float*)d_out);
}

// Round 8
// 301.544 us; speedup vs baseline: 3.2189x; 1.1177x over previous
//
#include <hip/hip_runtime.h>

#define N_PREV 250000
#define N_FULL 500000
#define NVOX   65536
#define NWORDS (1u<<20)          // bitmap words; keyspace < 2^25 bits
#define EPSF   1e-5f

typedef __attribute__((ext_vector_type(4)))  short short4v;
typedef __attribute__((ext_vector_type(8)))  short short8v;
typedef __attribute__((ext_vector_type(16))) float f32x16;

__device__ __forceinline__ float lrelu(float x){ return x > 0.0f ? x : 0.1f*x; }
__device__ __forceinline__ short f2bf_rne(float v){
    unsigned u = __float_as_uint(v);
    unsigned r = (u + 0x7fffu + ((u>>16)&1u)) >> 16;
    return (short)r;
}
__device__ __forceinline__ float bf2f(short s){
    return __uint_as_float(((unsigned)(unsigned short)s) << 16);
}

// ---------------- ws layout (bytes) ----------------
// zeroed prefix:
#define OFF_BITMAP   0ul            // u32[NWORDS] (aliased as csr_j/csr_h after k_p1f)
#define OFF_STATS    4194304ul      // f32[256]
#define OFF_CNT      4195328ul      // f32[N_PREV]
#define OFF_VH       5195328ul      // u32[NVOX]
#define OFF_Y        5457472ul      // f32[N_PREV*32]  32 MB  (y = scattered F@W1; dead after ppm2)
#define ZERO_BYTES   37457472ul
// not zeroed:
#define OFF_P2       37457472ul     // bf16[N_PREV*64] 32 MB  (written by ppm3, after y dead)
#define OFF_PREF     69457472ul     // u32[NWORDS] (aliased as vstart/vnext/vpart/vbsum after p1f)
#define OFF_BSUM     73651776ul
#define OFF_BOFF     73655872ul
#define OFF_UCNT     73659968ul
#define OFF_INV      73660224ul     // i32[N_PREV]
#define OFF_P1       74660224ul     // bf16[N_PREV*64] 32 MB (written by p1f, read by vox)
#define OFF_X2       106660224ul    // f32[N_PREV*32]  32 MB (ppm2 -> ppm3)
#define WS_NEEDED    138660224ul
#define OFF_CSRJ     0ul
#define OFF_CSRH     2000000ul
#define OFF_VSTART   69457472ul
#define OFF_VNEXT    (OFF_VSTART+262400ul)
#define OFF_VPART    (OFF_VNEXT+262144ul)
#define OFF_VBSUM    (OFF_VPART+262144ul)

__device__ __forceinline__ int voxel_key(int4 c){
    return ((c.x*501 + (c.y>>1))*501 + (c.z>>1))*31 + (c.w>>1);
}

// ---- mark present keys ----
__global__ void k_mark(const int* __restrict__ coors, unsigned* __restrict__ bitmap){
    int i = blockIdx.x*256 + threadIdx.x;
    if(i >= N_PREV) return;
    int4 c = ((const int4*)coors)[i];
    int key = voxel_key(c);
    atomicOr(&bitmap[key>>5], 1u<<(key&31));
}

__global__ void __launch_bounds__(1024) k_scanA(const unsigned* __restrict__ bitmap,
                                                unsigned* __restrict__ pref,
                                                unsigned* __restrict__ bsum){
    __shared__ unsigned sh[1024];
    int tid = threadIdx.x;
    int w = blockIdx.x*1024 + tid;
    unsigned p = __popc(bitmap[w]);
    sh[tid] = p; __syncthreads();
    for(int off=1; off<1024; off<<=1){
        unsigned v = (tid>=off) ? sh[tid-off] : 0u;
        __syncthreads();
        sh[tid] += v;
        __syncthreads();
    }
    pref[w] = sh[tid] - p;
    if(tid==1023) bsum[blockIdx.x] = sh[tid];
}

__global__ void __launch_bounds__(1024) k_scanB(const unsigned* __restrict__ bsum,
                                                unsigned* __restrict__ boff,
                                                unsigned* __restrict__ Ucnt){
    __shared__ unsigned sh[1024];
    int tid = threadIdx.x;
    unsigned p = bsum[tid];
    sh[tid] = p; __syncthreads();
    for(int off=1; off<1024; off<<=1){
        unsigned v = (tid>=off) ? sh[tid-off] : 0u;
        __syncthreads();
        sh[tid] += v;
        __syncthreads();
    }
    boff[tid] = sh[tid] - p;
    if(tid==1023) Ucnt[0] = sh[tid];
}

// ---- CSR build over scale voxels ----
__global__ void k_vhist(const int* __restrict__ scv, unsigned* __restrict__ vh){
    int p = blockIdx.x*256 + threadIdx.x;
    if(p < N_FULL) atomicAdd(&vh[scv[p]], 1u);
}

__global__ void __launch_bounds__(1024) k_vscanA(const unsigned* __restrict__ vh,
                                                 unsigned* __restrict__ vpart,
                                                 unsigned* __restrict__ vbsum){
    __shared__ unsigned sh[1024];
    int tid = threadIdx.x;
    int w = blockIdx.x*1024 + tid;
    unsigned p = vh[w];
    sh[tid] = p; __syncthreads();
    for(int off=1; off<1024; off<<=1){
        unsigned v = (tid>=off) ? sh[tid-off] : 0u;
        __syncthreads();
        sh[tid] += v;
        __syncthreads();
    }
    vpart[w] = sh[tid] - p;
    if(tid==1023) vbsum[blockIdx.x] = sh[tid];
}

__global__ void k_vscanB(unsigned* __restrict__ vbsum){
    int l = threadIdx.x;
    unsigned v = vbsum[l], orig = v;
    for(int off=1; off<64; off<<=1){
        unsigned o = __shfl_up(v, off);
        if(l>=off) v += o;
    }
    vbsum[l] = v - orig;
}

__global__ void __launch_bounds__(1024) k_vfix(const unsigned* __restrict__ vpart,
                                               const unsigned* __restrict__ vbsum,
                                               unsigned* __restrict__ vstart,
                                               unsigned* __restrict__ vnext){
    int w = blockIdx.x*1024 + threadIdx.x;
    unsigned s = vpart[w] + vbsum[w>>10];
    vstart[w] = s; vnext[w] = s;
    if(w == NVOX-1) vstart[NVOX] = N_FULL;
}

__global__ void k_fill(const int* __restrict__ cif, const int* __restrict__ scv,
                       const int* __restrict__ inv, unsigned* __restrict__ vnext,
                       int* __restrict__ csr_j, int* __restrict__ csr_h){
    int p = blockIdx.x*256 + threadIdx.x;
    if(p >= N_FULL) return;
    int jp = cif[p];
    unsigned pos = atomicAdd(&vnext[scv[p]], 1u);
    csr_j[pos] = jp;
    csr_h[pos] = inv[jp];
}

// ---- fused: P1 = lrelu(F@Win+b)@Wo1a (bf16 out); Y = F@W1 scattered by rank;
//      rank/inv/cnt computed inline.  MFMA 32x32x16 split hi/lo (verified R4/R5). ----
__global__ void __launch_bounds__(256) k_p1f(const float* __restrict__ feat,
        const int* __restrict__ coors, const unsigned* __restrict__ bitmap,
        const unsigned* __restrict__ pref, const unsigned* __restrict__ boff,
        const float* __restrict__ Win, const float* __restrict__ bin,
        const float* __restrict__ Wo1, const float* __restrict__ W1,
        unsigned short* __restrict__ P1, int* __restrict__ inv,
        float* __restrict__ cnt, float* __restrict__ y){
    __shared__ __align__(16) short Ah[64*68];
    __shared__ __align__(16) short Al[64*68];
    __shared__ float ysh[64][33];
    __shared__ int rksh[64];
    int tid = threadIdx.x;
    int wave = tid >> 6, l = tid & 63;
    int g = l >> 5, c = l & 31;
    int rowhalf = (wave >> 1) * 32, colhalf = (wave & 1) * 32;

    // stage Win^T, hoist
    {
        int col = tid >> 2, kseg = (tid & 3) * 16;
        short hi[16], lo[16];
        #pragma unroll
        for(int j=0;j<16;++j){
            float v = Win[(kseg+j)*64 + col];
            short h = f2bf_rne(v);
            hi[j] = h; lo[j] = f2bf_rne(v - bf2f(h));
        }
        #pragma unroll
        for(int i=0;i<4;++i){
            *(short4v*)&Ah[col*68 + kseg + 4*i] = *(short4v*)&hi[4*i];
            *(short4v*)&Al[col*68 + kseg + 4*i] = *(short4v*)&lo[4*i];
        }
    }
    __syncthreads();
    short8v w1h[4], w1l[4];
    #pragma unroll
    for(int s=0;s<4;++s){
        int base = (colhalf + c)*68 + s*16 + g*4;
        ((short4v*)&w1h[s])[0] = *(short4v*)&Ah[base];
        ((short4v*)&w1h[s])[1] = *(short4v*)&Ah[base + 8];
        ((short4v*)&w1l[s])[0] = *(short4v*)&Al[base];
        ((short4v*)&w1l[s])[1] = *(short4v*)&Al[base + 8];
    }
    __syncthreads();
    // stage Wo1a^T, hoist
    {
        int col = tid >> 2, kseg = (tid & 3) * 16;
        short hi[16], lo[16];
        #pragma unroll
        for(int j=0;j<16;++j){
            float v = Wo1[(kseg+j)*64 + col];
            short h = f2bf_rne(v);
            hi[j] = h; lo[j] = f2bf_rne(v - bf2f(h));
        }
        #pragma unroll
        for(int i=0;i<4;++i){
            *(short4v*)&Ah[col*68 + kseg + 4*i] = *(short4v*)&hi[4*i];
            *(short4v*)&Al[col*68 + kseg + 4*i] = *(short4v*)&lo[4*i];
        }
    }
    __syncthreads();
    short8v w2h[4], w2l[4];
    #pragma unroll
    for(int s=0;s<4;++s){
        int base = (colhalf + c)*68 + s*16 + g*4;
        ((short4v*)&w2h[s])[0] = *(short4v*)&Ah[base];
        ((short4v*)&w2h[s])[1] = *(short4v*)&Ah[base + 8];
        ((short4v*)&w2l[s])[0] = *(short4v*)&Al[base];
        ((short4v*)&w2l[s])[1] = *(short4v*)&Al[base + 8];
    }
    __syncthreads();
    // stage W1^T [32 col][64 k], hoist
    if(tid < 128){
        int col = tid >> 2, kseg = (tid & 3) * 16;
        short hi[16], lo[16];
        #pragma unroll
        for(int j=0;j<16;++j){
            float v = W1[(kseg+j)*32 + col];
            short h = f2bf_rne(v);
            hi[j] = h; lo[j] = f2bf_rne(v - bf2f(h));
        }
        #pragma unroll
        for(int i=0;i<4;++i){
            *(short4v*)&Ah[col*68 + kseg + 4*i] = *(short4v*)&hi[4*i];
            *(short4v*)&Al[col*68 + kseg + 4*i] = *(short4v*)&lo[4*i];
        }
    }
    __syncthreads();
    short8v w0h[4], w0l[4];
    #pragma unroll
    for(int s=0;s<4;++s){
        int base = c*68 + s*16 + g*4;
        ((short4v*)&w0h[s])[0] = *(short4v*)&Ah[base];
        ((short4v*)&w0h[s])[1] = *(short4v*)&Ah[base + 8];
        ((short4v*)&w0l[s])[0] = *(short4v*)&Al[base];
        ((short4v*)&w0l[s])[1] = *(short4v*)&Al[base + 8];
    }
    __syncthreads();

    float bc1 = bin[colhalf + c];

    const int NT = (N_PREV + 63) / 64;
    for(int tile = blockIdx.x; tile < NT; tile += gridDim.x){
        int rbase = tile * 64;
        // stage F tile hi/lo
        {
            int row = tid >> 2, kseg = (tid & 3) * 16;
            int grow = rbase + row;
            float fv[16];
            if(grow < N_PREV){
                const float4* fp = (const float4*)&feat[grow*64 + kseg];
                *(float4*)&fv[0]  = fp[0];
                *(float4*)&fv[4]  = fp[1];
                *(float4*)&fv[8]  = fp[2];
                *(float4*)&fv[12] = fp[3];
            } else {
                #pragma unroll
                for(int j=0;j<16;++j) fv[j]=0.f;
            }
            short hi[16], lo[16];
            #pragma unroll
            for(int j=0;j<16;++j){
                short h = f2bf_rne(fv[j]);
                hi[j] = h; lo[j] = f2bf_rne(fv[j] - bf2f(h));
            }
            #pragma unroll
            for(int i=0;i<4;++i){
                *(short4v*)&Ah[row*68 + kseg + 4*i] = *(short4v*)&hi[4*i];
                *(short4v*)&Al[row*68 + kseg + 4*i] = *(short4v*)&lo[4*i];
            }
        }
        // ranks for this tile's rows
        if(tid < 64){
            int grow = rbase + tid;
            if(grow < N_PREV){
                int4 c4 = ((const int4*)coors)[grow];
                int key = voxel_key(c4);
                int w = key>>5, b = key&31;
                int rank = (int)(boff[w>>10] + pref[w]) + __popc(bitmap[w] & ((1u<<b)-1u));
                rksh[tid] = rank;
                inv[grow] = rank;
                atomicAdd(&cnt[rank], 1.0f);
            } else rksh[tid] = -1;
        }
        __syncthreads();
        // GEMM1: I = lrelu(F@Win + b)  (all waves)
        f32x16 acc;
        #pragma unroll
        for(int i=0;i<16;++i) acc[i]=0.f;
        #pragma unroll
        for(int s=0;s<4;++s){
            int abase = (rowhalf + c)*68 + s*16 + g*4;
            short8v ah, al;
            ((short4v*)&ah)[0] = *(short4v*)&Ah[abase];
            ((short4v*)&ah)[1] = *(short4v*)&Ah[abase + 8];
            ((short4v*)&al)[0] = *(short4v*)&Al[abase];
            ((short4v*)&al)[1] = *(short4v*)&Al[abase + 8];
            acc = __builtin_amdgcn_mfma_f32_32x32x16_bf16(ah, w1h[s], acc, 0,0,0);
            acc = __builtin_amdgcn_mfma_f32_32x32x16_bf16(al, w1h[s], acc, 0,0,0);
            acc = __builtin_amdgcn_mfma_f32_32x32x16_bf16(ah, w1l[s], acc, 0,0,0);
        }
        // GEMM0: Y = F@W1  (waves 0/1)
        f32x16 accY;
        #pragma unroll
        for(int i=0;i<16;++i) accY[i]=0.f;
        if(wave < 2){
            #pragma unroll
            for(int s=0;s<4;++s){
                int abase = (wave*32 + c)*68 + s*16 + g*4;
                short8v ah, al;
                ((short4v*)&ah)[0] = *(short4v*)&Ah[abase];
                ((short4v*)&ah)[1] = *(short4v*)&Ah[abase + 8];
                ((short4v*)&al)[0] = *(short4v*)&Al[abase];
                ((short4v*)&al)[1] = *(short4v*)&Al[abase + 8];
                accY = __builtin_amdgcn_mfma_f32_32x32x16_bf16(ah, w0h[s], accY, 0,0,0);
                accY = __builtin_amdgcn_mfma_f32_32x32x16_bf16(al, w0h[s], accY, 0,0,0);
                accY = __builtin_amdgcn_mfma_f32_32x32x16_bf16(ah, w0l[s], accY, 0,0,0);
            }
        }
        __syncthreads();
        // epilogue: I -> LDS hi/lo; Y -> ysh
        #pragma unroll
        for(int r=0;r<16;++r){
            int row = rowhalf + (r&3) + 8*(r>>2) + 4*g;
            float v = acc[r] + bc1;
            v = v > 0.f ? v : 0.1f*v;
            short h = f2bf_rne(v);
            Ah[row*68 + colhalf + c] = h;
            Al[row*68 + colhalf + c] = f2bf_rne(v - bf2f(h));
        }
        if(wave < 2){
            #pragma unroll
            for(int r=0;r<16;++r){
                int row = wave*32 + (r&3) + 8*(r>>2) + 4*g;
                ysh[row][c] = accY[r];
            }
        }
        __syncthreads();
        // GEMM2: P1 = I @ Wo1a
        f32x16 acc2;
        #pragma unroll
        for(int i=0;i<16;++i) acc2[i]=0.f;
        #pragma unroll
        for(int s=0;s<4;++s){
            int abase = (rowhalf + c)*68 + s*16 + g*4;
            short8v ah, al;
            ((short4v*)&ah)[0] = *(short4v*)&Ah[abase];
            ((short4v*)&ah)[1] = *(short4v*)&Ah[abase + 8];
            ((short4v*)&al)[0] = *(short4v*)&Al[abase];
            ((short4v*)&al)[1] = *(short4v*)&Al[abase + 8];
            acc2 = __builtin_amdgcn_mfma_f32_32x32x16_bf16(ah, w2h[s], acc2, 0,0,0);
            acc2 = __builtin_amdgcn_mfma_f32_32x32x16_bf16(al, w2h[s], acc2, 0,0,0);
            acc2 = __builtin_amdgcn_mfma_f32_32x32x16_bf16(ah, w2l[s], acc2, 0,0,0);
        }
        #pragma unroll
        for(int r=0;r<16;++r){
            int grow = rbase + rowhalf + (r&3) + 8*(r>>2) + 4*g;
            if(grow < N_PREV) P1[grow*64 + colhalf + c] = (unsigned short)f2bf_rne(acc2[r]);
        }
        // scatter Y tile into y by rank (f32 atomics)
        #pragma unroll
        for(int q=0;q<8;++q){
            int e = q*256 + tid;
            int row = e >> 5, col = e & 31;
            int rk = rksh[row];
            if(rk >= 0) atomicAdd(&y[rk*32 + col], ysh[row][col]);
        }
        __syncthreads();
    }
}

// ---- BN1 stats over x1 = lrelu(y/cnt + b1)  (stats only, no write) ----
__global__ void __launch_bounds__(256) k_bn1(const float* __restrict__ y,
        const float* __restrict__ cnt, const unsigned* __restrict__ Ucnt,
        const float* __restrict__ b1, float* __restrict__ stats){
    __shared__ float sst[32], qst[32];
    int tid = threadIdx.x;
    if(tid < 32){ sst[tid]=0.f; qst[tid]=0.f; }
    __syncthreads();
    int U = (int)Ucnt[0];
    int total = U*8;
    int col4 = (tid&7)*4;
    float4 bb = *(const float4*)&b1[col4];
    float4 s4 = make_float4(0,0,0,0), q4 = make_float4(0,0,0,0);
    for(int e = blockIdx.x*256 + tid; e < total; e += gridDim.x*256){
        int row = e >> 3;
        float rv = 1.0f/cnt[row];
        float4 v = ((const float4*)y)[e];
        v.x = lrelu(v.x*rv+bb.x); v.y = lrelu(v.y*rv+bb.y);
        v.z = lrelu(v.z*rv+bb.z); v.w = lrelu(v.w*rv+bb.w);
        s4.x+=v.x; s4.y+=v.y; s4.z+=v.z; s4.w+=v.w;
        q4.x+=v.x*v.x; q4.y+=v.y*v.y; q4.z+=v.z*v.z; q4.w+=v.w*v.w;
    }
    atomicAdd(&sst[col4+0], s4.x); atomicAdd(&sst[col4+1], s4.y);
    atomicAdd(&sst[col4+2], s4.z); atomicAdd(&sst[col4+3], s4.w);
    atomicAdd(&qst[col4+0], q4.x); atomicAdd(&qst[col4+1], q4.y);
    atomicAdd(&qst[col4+2], q4.z); atomicAdd(&qst[col4+3], q4.w);
    __syncthreads();
    if(tid < 32){ atomicAdd(&stats[tid], sst[tid]); atomicAdd(&stats[32+tid], qst[tid]); }
}

__global__ void k_bnfin(const unsigned* __restrict__ Ucnt, const float* __restrict__ g,
                        float* __restrict__ stats, int off){
    int c = threadIdx.x;
    if(c>=32) return;
    float n = (float)max(Ucnt[0], 1u);
    float mu = stats[off+c]/n;
    float var = stats[off+32+c]/n - mu*mu;
    stats[off+64+c] = mu;
    stats[off+96+c] = g[c]*rsqrtf(var + EPSF);
}

// ---- x2 = lrelu(BN1(lrelu(y/cnt+b1)) @ W2 + b2), BN2 stats.  MFMA 128x32, k=32 ----
__global__ void __launch_bounds__(256) k_ppm2(const float* __restrict__ y,
        const float* __restrict__ cnt, const unsigned* __restrict__ Ucnt,
        const float* __restrict__ W2, const float* __restrict__ b1i,
        const float* __restrict__ b2, const float* __restrict__ be1,
        float* __restrict__ x2, float* __restrict__ stats){
    __shared__ __align__(16) short Ah[128*36];
    __shared__ __align__(16) short Al[128*36];
    __shared__ float ash[32], bbsh[32], b1sh[32];
    __shared__ float red[4][64];
    int tid = threadIdx.x;
    int wave = tid >> 6, l = tid & 63;
    int g = l >> 5, c = l & 31;

    if(tid < 32){
        float mu=stats[64+tid], sc=stats[96+tid];
        ash[tid]=sc; bbsh[tid]=be1[tid]-mu*sc;
        b1sh[tid]=b1i[tid];
    }
    if(tid >= 64 && tid < 128){
        int t = tid - 64;
        int col = t >> 1, kseg = (t & 1) * 16;
        short hi[16], lo[16];
        #pragma unroll
        for(int j=0;j<16;++j){
            float v = W2[(kseg+j)*32 + col];
            short h = f2bf_rne(v);
            hi[j] = h; lo[j] = f2bf_rne(v - bf2f(h));
        }
        #pragma unroll
        for(int i=0;i<4;++i){
            *(short4v*)&Ah[col*36 + kseg + 4*i] = *(short4v*)&hi[4*i];
            *(short4v*)&Al[col*36 + kseg + 4*i] = *(short4v*)&lo[4*i];
        }
    }
    __syncthreads();
    short8v wh[2], wl[2];
    #pragma unroll
    for(int s=0;s<2;++s){
        int base = c*36 + s*16 + g*4;
        ((short4v*)&wh[s])[0] = *(short4v*)&Ah[base];
        ((short4v*)&wh[s])[1] = *(short4v*)&Ah[base + 8];
        ((short4v*)&wl[s])[0] = *(short4v*)&Al[base];
        ((short4v*)&wl[s])[1] = *(short4v*)&Al[base + 8];
    }
    __syncthreads();

    int U = (int)Ucnt[0];
    float bc = b2[c];
    float s_acc = 0.f, q_acc = 0.f;

    const int NT = (N_PREV + 127) / 128;
    for(int tile = blockIdx.x; tile < NT; tile += gridDim.x){
        int rbase = tile * 128;
        if(rbase >= U) break;
        {
            int row = tid >> 1, kseg = (tid & 1) * 16;
            int grow = rbase + row;
            float fv[16];
            if(grow < U){
                float rv = 1.0f/cnt[grow];
                const float4* fp = (const float4*)&y[grow*32 + kseg];
                *(float4*)&fv[0]=fp[0]; *(float4*)&fv[4]=fp[1];
                *(float4*)&fv[8]=fp[2]; *(float4*)&fv[12]=fp[3];
                #pragma unroll
                for(int j=0;j<16;++j){
                    float v = lrelu(fv[j]*rv + b1sh[kseg+j]);      // x1
                    fv[j] = v*ash[kseg+j] + bbsh[kseg+j];           // BN1
                }
            } else {
                #pragma unroll
                for(int j=0;j<16;++j) fv[j]=0.f;
            }
            short hi[16], lo[16];
            #pragma unroll
            for(int j=0;j<16;++j){
                short h = f2bf_rne(fv[j]);
                hi[j] = h; lo[j] = f2bf_rne(fv[j] - bf2f(h));
            }
            #pragma unroll
            for(int i=0;i<4;++i){
                *(short4v*)&Ah[row*36 + kseg + 4*i] = *(short4v*)&hi[4*i];
                *(short4v*)&Al[row*36 + kseg + 4*i] = *(short4v*)&lo[4*i];
            }
        }
        __syncthreads();
        f32x16 acc;
        #pragma unroll
        for(int i=0;i<16;++i) acc[i]=0.f;
        #pragma unroll
        for(int s=0;s<2;++s){
            int abase = (wave*32 + c)*36 + s*16 + g*4;
            short8v ah, al;
            ((short4v*)&ah)[0] = *(short4v*)&Ah[abase];
            ((short4v*)&ah)[1] = *(short4v*)&Ah[abase + 8];
            ((short4v*)&al)[0] = *(short4v*)&Al[abase];
            ((short4v*)&al)[1] = *(short4v*)&Al[abase + 8];
            acc = __builtin_amdgcn_mfma_f32_32x32x16_bf16(ah, wh[s], acc, 0,0,0);
            acc = __builtin_amdgcn_mfma_f32_32x32x16_bf16(al, wh[s], acc, 0,0,0);
            acc = __builtin_amdgcn_mfma_f32_32x32x16_bf16(ah, wl[s], acc, 0,0,0);
        }
        #pragma unroll
        for(int r=0;r<16;++r){
            int rl = wave*32 + (r&3) + 8*(r>>2) + 4*g;
            int grow = rbase + rl;
            if(grow < U){
                float v = acc[r] + bc;
                v = v > 0.f ? v : 0.1f*v;
                x2[grow*32 + c] = v;
                s_acc += v; q_acc += v*v;
            }
        }
        __syncthreads();
    }
    s_acc += __shfl_xor(s_acc, 32);
    q_acc += __shfl_xor(q_acc, 32);
    if(l < 32){ red[wave][c] = s_acc; red[wave][32+c] = q_acc; }
    __syncthreads();
    if(tid < 64){
        float t = red[0][tid]+red[1][tid]+red[2][tid]+red[3][tid];
        atomicAdd(&stats[128+tid], t);
    }
}

// ---- P2 = lrelu(BN2(x2) @ W3 + b3) @ Wo1b  [U,64] bf16.  MFMA 64x64 ----
__global__ void __launch_bounds__(256) k_ppm3(const float* __restrict__ x2,
        const unsigned* __restrict__ Ucnt, const float* __restrict__ W3,
        const float* __restrict__ b3, const float* __restrict__ be2,
        const float* __restrict__ Wo1, unsigned short* __restrict__ P2,
        const float* __restrict__ stats){
    __shared__ __align__(16) short Ah[64*36];
    __shared__ __align__(16) short Al[64*36];
    __shared__ __align__(16) short Ih[64*68];
    __shared__ __align__(16) short Il[64*68];
    __shared__ float ash[32], bbsh[32];
    int tid = threadIdx.x;
    int wave = tid >> 6, l = tid & 63;
    int g = l >> 5, c = l & 31;
    int rowhalf = (wave >> 1) * 32, colhalf = (wave & 1) * 32;

    if(tid < 32){
        float mu=stats[192+tid], sc=stats[224+tid];
        ash[tid]=sc; bbsh[tid]=be2[tid]-mu*sc;
    }
    if(tid >= 128){
        int t = tid - 128;
        int col = t >> 1, kseg = (t & 1) * 16;
        short hi[16], lo[16];
        #pragma unroll
        for(int j=0;j<16;++j){
            float v = W3[(kseg+j)*64 + col];
            short h = f2bf_rne(v);
            hi[j] = h; lo[j] = f2bf_rne(v - bf2f(h));
        }
        #pragma unroll
        for(int i=0;i<4;++i){
            *(short4v*)&Ih[col*36 + kseg + 4*i] = *(short4v*)&hi[4*i];
            *(short4v*)&Il[col*36 + kseg + 4*i] = *(short4v*)&lo[4*i];
        }
    }
    __syncthreads();
    short8v w3h[2], w3l[2];
    #pragma unroll
    for(int s=0;s<2;++s){
        int base = (colhalf + c)*36 + s*16 + g*4;
        ((short4v*)&w3h[s])[0] = *(short4v*)&Ih[base];
        ((short4v*)&w3h[s])[1] = *(short4v*)&Ih[base + 8];
        ((short4v*)&w3l[s])[0] = *(short4v*)&Il[base];
        ((short4v*)&w3l[s])[1] = *(short4v*)&Il[base + 8];
    }
    __syncthreads();
    {
        int col = tid >> 2, kseg = (tid & 3) * 16;
        short hi[16], lo[16];
        #pragma unroll
        for(int j=0;j<16;++j){
            float v = Wo1[4096 + (kseg+j)*64 + col];
            short h = f2bf_rne(v);
            hi[j] = h; lo[j] = f2bf_rne(v - bf2f(h));
        }
        #pragma unroll
        for(int i=0;i<4;++i){
            *(short4v*)&Ih[col*68 + kseg + 4*i] = *(short4v*)&hi[4*i];
            *(short4v*)&Il[col*68 + kseg + 4*i] = *(short4v*)&lo[4*i];
        }
    }
    __syncthreads();
    short8v w2h[4], w2l[4];
    #pragma unroll
    for(int s=0;s<4;++s){
        int base = (colhalf + c)*68 + s*16 + g*4;
        ((short4v*)&w2h[s])[0] = *(short4v*)&Ih[base];
        ((short4v*)&w2h[s])[1] = *(short4v*)&Ih[base + 8];
        ((short4v*)&w2l[s])[0] = *(short4v*)&Il[base];
        ((short4v*)&w2l[s])[1] = *(short4v*)&Il[base + 8];
    }
    __syncthreads();

    int U = (int)Ucnt[0];
    float bc3 = b3[colhalf + c];

    const int NT = (N_PREV + 63) / 64;
    for(int tile = blockIdx.x; tile < NT; tile += gridDim.x){
        int rbase = tile * 64;
        if(rbase >= U) break;
        if(tid < 128){
            int row = tid >> 1, kseg = (tid & 1) * 16;
            int grow = rbase + row;
            float fv[16];
            if(grow < U){
                const float4* fp = (const float4*)&x2[grow*32 + kseg];
                *(float4*)&fv[0]=fp[0]; *(float4*)&fv[4]=fp[1];
                *(float4*)&fv[8]=fp[2]; *(float4*)&fv[12]=fp[3];
                #pragma unroll
                for(int j=0;j<16;++j) fv[j] = fv[j]*ash[kseg+j] + bbsh[kseg+j];
            } else {
                #pragma unroll
                for(int j=0;j<16;++j) fv[j]=0.f;
            }
            short hi[16], lo[16];
            #pragma unroll
            for(int j=0;j<16;++j){
                short h = f2bf_rne(fv[j]);
                hi[j] = h; lo[j] = f2bf_rne(fv[j] - bf2f(h));
            }
            #pragma unroll
            for(int i=0;i<4;++i){
                *(short4v*)&Ah[row*36 + kseg + 4*i] = *(short4v*)&hi[4*i];
                *(short4v*)&Al[row*36 + kseg + 4*i] = *(short4v*)&lo[4*i];
            }
        }
        __syncthreads();
        f32x16 acc;
        #pragma unroll
        for(int i=0;i<16;++i) acc[i]=0.f;
        #pragma unroll
        for(int s=0;s<2;++s){
            int abase = (rowhalf + c)*36 + s*16 + g*4;
            short8v ah, al;
            ((short4v*)&ah)[0] = *(short4v*)&Ah[abase];
            ((short4v*)&ah)[1] = *(short4v*)&Ah[abase + 8];
            ((short4v*)&al)[0] = *(short4v*)&Al[abase];
            ((short4v*)&al)[1] = *(short4v*)&Al[abase + 8];
            acc = __builtin_amdgcn_mfma_f32_32x32x16_bf16(ah, w3h[s], acc, 0,0,0);
            acc = __builtin_amdgcn_mfma_f32_32x32x16_bf16(al, w3h[s], acc, 0,0,0);
            acc = __builtin_amdgcn_mfma_f32_32x32x16_bf16(ah, w3l[s], acc, 0,0,0);
        }
        #pragma unroll
        for(int r=0;r<16;++r){
            int row = rowhalf + (r&3) + 8*(r>>2) + 4*g;
            float v = acc[r] + bc3;
            v = v > 0.f ? v : 0.1f*v;
            short h = f2bf_rne(v);
            Ih[row*68 + colhalf + c] = h;
            Il[row*68 + colhalf + c] = f2bf_rne(v - bf2f(h));
        }
        __syncthreads();
        f32x16 acc2;
        #pragma unroll
        for(int i=0;i<16;++i) acc2[i]=0.f;
        #pragma unroll
        for(int s=0;s<4;++s){
            int abase = (rowhalf + c)*68 + s*16 + g*4;
            short8v ah, al;
            ((short4v*)&ah)[0] = *(short4v*)&Ih[abase];
            ((short4v*)&ah)[1] = *(short4v*)&Ih[abase + 8];
            ((short4v*)&al)[0] = *(short4v*)&Il[abase];
            ((short4v*)&al)[1] = *(short4v*)&Il[abase + 8];
            acc2 = __builtin_amdgcn_mfma_f32_32x32x16_bf16(ah, w2h[s], acc2, 0,0,0);
            acc2 = __builtin_amdgcn_mfma_f32_32x32x16_bf16(al, w2h[s], acc2, 0,0,0);
            acc2 = __builtin_amdgcn_mfma_f32_32x32x16_bf16(ah, w2l[s], acc2, 0,0,0);
        }
        #pragma unroll
        for(int r=0;r<16;++r){
            int grow = rbase + rowhalf + (r&3) + 8*(r>>2) + 4*g;
            if(grow < U) P2[grow*64 + colhalf + c] = (unsigned short)f2bf_rne(acc2[r]);
        }
        __syncthreads();
    }
}

// ---- one wave per voxel (R6-verified math; loads software-pipelined in batches of 8) ----
__global__ void __launch_bounds__(256) k_vox(const unsigned* __restrict__ vstart,
        const int* __restrict__ csr_j, const int* __restrict__ csr_h,
        const unsigned short* __restrict__ P1, const unsigned short* __restrict__ P2,
        const float* __restrict__ bo1, const float* __restrict__ Wo2,
        const float* __restrict__ bo2, float* __restrict__ out){
    __shared__ float tsh[4][64];
    int tid = threadIdx.x;
    int wib = tid>>6, lane = tid&63;
    float wreg[64];
    #pragma unroll
    for(int k=0;k<64;++k) wreg[k] = Wo2[k*64+lane];
    float b1c = bo1[lane], b2c = bo2[lane];
    int wglobal = blockIdx.x*4 + wib;
    for(int vq=0; vq<4; ++vq){
        int vox = wglobal*4 + vq;
        int s = (int)vstart[vox], e = (int)vstart[vox+1];
        float acc = 0.f;
        for(int i=s; i<e; i+=64){
            int n = min(e-i, 64);
            int jv=0, hv=0;
            if(lane<n){ jv = csr_j[i+lane]; hv = csr_h[i+lane]; }
            for(int q0=0; q0<n; q0+=8){
                // clamp out-of-range slots to q0 (always valid); mask at accumulate.
                float pa[8], pb[8];
                #pragma unroll
                for(int t=0;t<8;++t){
                    int qq = q0 + t;
                    qq = (qq < n) ? qq : q0;
                    int j = __shfl(jv, qq);
                    int h = __shfl(hv, qq);
                    pa[t] = bf2f((short)P1[(size_t)j*64 + lane]);
                    pb[t] = bf2f((short)P2[(size_t)h*64 + lane]);
                }
                #pragma unroll
                for(int t=0;t<8;++t){
                    if(q0 + t < n){
                        float g = pa[t] + pb[t] + b1c;
                        acc += (g>0.f) ? g : 0.1f*g;
                    }
                }
            }
        }
        tsh[wib][lane] = acc;
        float dot = 0.f;
        const float4* t4 = (const float4*)tsh[wib];
        #pragma unroll
        for(int k4=0;k4<16;++k4){
            float4 t = t4[k4];
            dot += t.x*wreg[4*k4] + t.y*wreg[4*k4+1] + t.z*wreg[4*k4+2] + t.w*wreg[4*k4+3];
        }
        float cntv = (float)(e - s);
        out[vox*64+lane] = (dot + cntv*b2c) / fmaxf(cntv, 1.f);
    }
}

extern "C" void kernel_launch(void* const* d_in, const int* in_sizes, int n_in,
                              void* d_out, int out_size, void* d_ws, size_t ws_size,
                              hipStream_t stream) {
    if(ws_size < WS_NEEDED) return;

    const float* features = (const float*)d_in[0];
    const int*   coors    = (const int*)d_in[1];
    const int*   cif      = (const int*)d_in[2];
    const int*   scv      = (const int*)d_in[3];
    const float* W_in     = (const float*)d_in[4];
    const float* b_in     = (const float*)d_in[5];
    const float* W1       = (const float*)d_in[6];
    const float* b1       = (const float*)d_in[7];
    const float* g1       = (const float*)d_in[8];
    const float* be1      = (const float*)d_in[9];
    const float* W2       = (const float*)d_in[10];
    const float* b2       = (const float*)d_in[11];
    const float* g2       = (const float*)d_in[12];
    const float* be2      = (const float*)d_in[13];
    const float* W3       = (const float*)d_in[14];
    const float* b3       = (const float*)d_in[15];
    const float* Wo1      = (const float*)d_in[16];
    const float* bo1      = (const float*)d_in[17];
    const float* Wo2      = (const float*)d_in[18];
    const float* bo2      = (const float*)d_in[19];

    char* ws = (char*)d_ws;
    unsigned* bitmap = (unsigned*)(ws + OFF_BITMAP);
    float*    stats  = (float*)(ws + OFF_STATS);
    float*    cnt    = (float*)(ws + OFF_CNT);
    unsigned* vh     = (unsigned*)(ws + OFF_VH);
    float*    y      = (float*)(ws + OFF_Y);
    unsigned short* P2 = (unsigned short*)(ws + OFF_P2);
    unsigned* pref   = (unsigned*)(ws + OFF_PREF);
    unsigned* bsum   = (unsigned*)(ws + OFF_BSUM);
    unsigned* boff   = (unsigned*)(ws + OFF_BOFF);
    unsigned* Ucnt   = (unsigned*)(ws + OFF_UCNT);
    int*      inv    = (int*)(ws + OFF_INV);
    unsigned short* P1 = (unsigned short*)(ws + OFF_P1);
    float*    x2     = (float*)(ws + OFF_X2);
    int*      csr_j  = (int*)(ws + OFF_CSRJ);
    int*      csr_h  = (int*)(ws + OFF_CSRH);
    unsigned* vstart = (unsigned*)(ws + OFF_VSTART);
    unsigned* vnext  = (unsigned*)(ws + OFF_VNEXT);
    unsigned* vpart  = (unsigned*)(ws + OFF_VPART);
    unsigned* vbsum  = (unsigned*)(ws + OFF_VBSUM);

    hipMemsetAsync(d_ws, 0, ZERO_BYTES, stream);

    k_mark  <<<(N_PREV+255)/256, 256, 0, stream>>>(coors, bitmap);
    k_scanA <<<1024, 1024, 0, stream>>>(bitmap, pref, bsum);
    k_scanB <<<1, 1024, 0, stream>>>(bsum, boff, Ucnt);
    k_p1f   <<<1024, 256, 0, stream>>>(features, coors, bitmap, pref, boff,
                                       W_in, b_in, Wo1, W1, P1, inv, cnt, y);
    // CSR build (overwrites bitmap/pref regions — safe after k_p1f)
    k_vhist <<<(N_FULL+255)/256, 256, 0, stream>>>(scv, vh);
    k_vscanA<<<64, 1024, 0, stream>>>(vh, vpart, vbsum);
    k_vscanB<<<1, 64, 0, stream>>>(vbsum);
    k_vfix  <<<64, 1024, 0, stream>>>(vpart, vbsum, vstart, vnext);
    k_fill  <<<(N_FULL+255)/256, 256, 0, stream>>>(cif, scv, inv, vnext, csr_j, csr_h);
    // PPmodel chain
    k_bn1   <<<1024, 256, 0, stream>>>(y, cnt, Ucnt, b1, stats);
    k_bnfin <<<1, 32, 0, stream>>>(Ucnt, g1, stats, 0);
    k_ppm2  <<<1024, 256, 0, stream>>>(y, cnt, Ucnt, W2, b1, b2, be1, x2, stats);
    k_bnfin <<<1, 32, 0, stream>>>(Ucnt, g2, stats, 128);
    k_ppm3  <<<1024, 256, 0, stream>>>(x2, Ucnt, W3, b3, be2, Wo1, P2, stats);
    k_vox   <<<NVOX/16, 256, 0, stream>>>(vstart, csr_j, csr_h, P1, P2, bo1, Wo2, bo2, (float*)d_out);
}

// Round 9
// 296.996 us; speedup vs baseline: 3.2682x; 1.0153x over previous
//
#include <hip/hip_runtime.h>

#define N_PREV 250000
#define N_FULL 500000
#define NVOX   65536
#define NWORDS (1u<<20)          // bitmap words; keyspace < 2^25 bits
#define EPSF   1e-5f

typedef __attribute__((ext_vector_type(4)))  short short4v;
typedef __attribute__((ext_vector_type(8)))  short short8v;
typedef __attribute__((ext_vector_type(16))) float f32x16;

__device__ __forceinline__ float lrelu(float x){ return x > 0.0f ? x : 0.1f*x; }
__device__ __forceinline__ short f2bf_rne(float v){
    unsigned u = __float_as_uint(v);
    unsigned r = (u + 0x7fffu + ((u>>16)&1u)) >> 16;
    return (short)r;
}
__device__ __forceinline__ float bf2f(short s){
    return __uint_as_float(((unsigned)(unsigned short)s) << 16);
}

// ---------------- ws layout (bytes) ----------------
// zeroed prefix:
#define OFF_BITMAP   0ul            // u32[NWORDS] (aliased as csr_j/csr_h after k_p1f)
#define OFF_STATS    4194304ul      // f32[256]
#define OFF_CNT      4195328ul      // f32[N_PREV]
#define OFF_VH       5195328ul      // u32[NVOX]
#define OFF_Y        5457472ul      // bf16[N_PREV*32]  16 MB  (y = scattered F@W1; dead after ppm2)
#define ZERO_BYTES   21457472ul
// not zeroed:
#define OFF_P2       37457472ul     // bf16[N_PREV*64] 32 MB
#define OFF_PREF     69457472ul     // u32[NWORDS] (aliased as vstart/vnext/vpart/vbsum after p1f)
#define OFF_BSUM     73651776ul
#define OFF_BOFF     73655872ul
#define OFF_UCNT     73659968ul
#define OFF_INV      73660224ul     // i32[N_PREV]
#define OFF_P1       74660224ul     // bf16[N_PREV*64] 32 MB (written by p1f, read by vox)
#define OFF_X2       106660224ul    // bf16[N_PREV*32]  16 MB (ppm2 -> ppm3)
#define WS_NEEDED    138660224ul
#define OFF_CSRJ     0ul
#define OFF_CSRH     2000000ul
#define OFF_VSTART   69457472ul
#define OFF_VNEXT    (OFF_VSTART+262400ul)
#define OFF_VPART    (OFF_VNEXT+262144ul)
#define OFF_VBSUM    (OFF_VPART+262144ul)

__device__ __forceinline__ int voxel_key(int4 c){
    return ((c.x*501 + (c.y>>1))*501 + (c.z>>1))*31 + (c.w>>1);
}

// ---- mark present keys ----
__global__ void k_mark(const int* __restrict__ coors, unsigned* __restrict__ bitmap){
    int i = blockIdx.x*256 + threadIdx.x;
    if(i >= N_PREV) return;
    int4 c = ((const int4*)coors)[i];
    int key = voxel_key(c);
    atomicOr(&bitmap[key>>5], 1u<<(key&31));
}

__global__ void __launch_bounds__(1024) k_scanA(const unsigned* __restrict__ bitmap,
                                                unsigned* __restrict__ pref,
                                                unsigned* __restrict__ bsum){
    __shared__ unsigned sh[1024];
    int tid = threadIdx.x;
    int w = blockIdx.x*1024 + tid;
    unsigned p = __popc(bitmap[w]);
    sh[tid] = p; __syncthreads();
    for(int off=1; off<1024; off<<=1){
        unsigned v = (tid>=off) ? sh[tid-off] : 0u;
        __syncthreads();
        sh[tid] += v;
        __syncthreads();
    }
    pref[w] = sh[tid] - p;
    if(tid==1023) bsum[blockIdx.x] = sh[tid];
}

__global__ void __launch_bounds__(1024) k_scanB(const unsigned* __restrict__ bsum,
                                                unsigned* __restrict__ boff,
                                                unsigned* __restrict__ Ucnt){
    __shared__ unsigned sh[1024];
    int tid = threadIdx.x;
    unsigned p = bsum[tid];
    sh[tid] = p; __syncthreads();
    for(int off=1; off<1024; off<<=1){
        unsigned v = (tid>=off) ? sh[tid-off] : 0u;
        __syncthreads();
        sh[tid] += v;
        __syncthreads();
    }
    boff[tid] = sh[tid] - p;
    if(tid==1023) Ucnt[0] = sh[tid];
}

// ---- CSR build over scale voxels ----
__global__ void k_vhist(const int* __restrict__ scv, unsigned* __restrict__ vh){
    int p = blockIdx.x*256 + threadIdx.x;
    if(p < N_FULL) atomicAdd(&vh[scv[p]], 1u);
}

__global__ void __launch_bounds__(1024) k_vscanA(const unsigned* __restrict__ vh,
                                                 unsigned* __restrict__ vpart,
                                                 unsigned* __restrict__ vbsum){
    __shared__ unsigned sh[1024];
    int tid = threadIdx.x;
    int w = blockIdx.x*1024 + tid;
    unsigned p = vh[w];
    sh[tid] = p; __syncthreads();
    for(int off=1; off<1024; off<<=1){
        unsigned v = (tid>=off) ? sh[tid-off] : 0u;
        __syncthreads();
        sh[tid] += v;
        __syncthreads();
    }
    vpart[w] = sh[tid] - p;
    if(tid==1023) vbsum[blockIdx.x] = sh[tid];
}

__global__ void k_vscanB(unsigned* __restrict__ vbsum){
    int l = threadIdx.x;
    unsigned v = vbsum[l], orig = v;
    for(int off=1; off<64; off<<=1){
        unsigned o = __shfl_up(v, off);
        if(l>=off) v += o;
    }
    vbsum[l] = v - orig;
}

__global__ void __launch_bounds__(1024) k_vfix(const unsigned* __restrict__ vpart,
                                               const unsigned* __restrict__ vbsum,
                                               unsigned* __restrict__ vstart,
                                               unsigned* __restrict__ vnext){
    int w = blockIdx.x*1024 + threadIdx.x;
    unsigned s = vpart[w] + vbsum[w>>10];
    vstart[w] = s; vnext[w] = s;
    if(w == NVOX-1) vstart[NVOX] = N_FULL;
}

__global__ void k_fill(const int* __restrict__ cif, const int* __restrict__ scv,
                       const int* __restrict__ inv, unsigned* __restrict__ vnext,
                       int* __restrict__ csr_j, int* __restrict__ csr_h){
    int p = blockIdx.x*256 + threadIdx.x;
    if(p >= N_FULL) return;
    int jp = cif[p];
    unsigned pos = atomicAdd(&vnext[scv[p]], 1u);
    csr_j[pos] = jp;
    csr_h[pos] = inv[jp];
}

// ---- fused: P1 = lrelu(F@Win+b)@Wo1a (bf16 out); Y = F@W1 scattered by rank (pk bf16 atomics);
//      rank/inv/cnt computed inline.  MFMA 32x32x16 split hi/lo (verified R4/R5). ----
__global__ void __launch_bounds__(256) k_p1f(const float* __restrict__ feat,
        const int* __restrict__ coors, const unsigned* __restrict__ bitmap,
        const unsigned* __restrict__ pref, const unsigned* __restrict__ boff,
        const float* __restrict__ Win, const float* __restrict__ bin,
        const float* __restrict__ Wo1, const float* __restrict__ W1,
        unsigned short* __restrict__ P1, int* __restrict__ inv,
        float* __restrict__ cnt, unsigned short* __restrict__ yb){
    __shared__ __align__(16) short Ah[64*68];
    __shared__ __align__(16) short Al[64*68];
    __shared__ float ysh[64][33];
    __shared__ int rksh[64];
    int tid = threadIdx.x;
    int wave = tid >> 6, l = tid & 63;
    int g = l >> 5, c = l & 31;
    int rowhalf = (wave >> 1) * 32, colhalf = (wave & 1) * 32;

    // stage Win^T, hoist
    {
        int col = tid >> 2, kseg = (tid & 3) * 16;
        short hi[16], lo[16];
        #pragma unroll
        for(int j=0;j<16;++j){
            float v = Win[(kseg+j)*64 + col];
            short h = f2bf_rne(v);
            hi[j] = h; lo[j] = f2bf_rne(v - bf2f(h));
        }
        #pragma unroll
        for(int i=0;i<4;++i){
            *(short4v*)&Ah[col*68 + kseg + 4*i] = *(short4v*)&hi[4*i];
            *(short4v*)&Al[col*68 + kseg + 4*i] = *(short4v*)&lo[4*i];
        }
    }
    __syncthreads();
    short8v w1h[4], w1l[4];
    #pragma unroll
    for(int s=0;s<4;++s){
        int base = (colhalf + c)*68 + s*16 + g*4;
        ((short4v*)&w1h[s])[0] = *(short4v*)&Ah[base];
        ((short4v*)&w1h[s])[1] = *(short4v*)&Ah[base + 8];
        ((short4v*)&w1l[s])[0] = *(short4v*)&Al[base];
        ((short4v*)&w1l[s])[1] = *(short4v*)&Al[base + 8];
    }
    __syncthreads();
    // stage Wo1a^T, hoist
    {
        int col = tid >> 2, kseg = (tid & 3) * 16;
        short hi[16], lo[16];
        #pragma unroll
        for(int j=0;j<16;++j){
            float v = Wo1[(kseg+j)*64 + col];
            short h = f2bf_rne(v);
            hi[j] = h; lo[j] = f2bf_rne(v - bf2f(h));
        }
        #pragma unroll
        for(int i=0;i<4;++i){
            *(short4v*)&Ah[col*68 + kseg + 4*i] = *(short4v*)&hi[4*i];
            *(short4v*)&Al[col*68 + kseg + 4*i] = *(short4v*)&lo[4*i];
        }
    }
    __syncthreads();
    short8v w2h[4], w2l[4];
    #pragma unroll
    for(int s=0;s<4;++s){
        int base = (colhalf + c)*68 + s*16 + g*4;
        ((short4v*)&w2h[s])[0] = *(short4v*)&Ah[base];
        ((short4v*)&w2h[s])[1] = *(short4v*)&Ah[base + 8];
        ((short4v*)&w2l[s])[0] = *(short4v*)&Al[base];
        ((short4v*)&w2l[s])[1] = *(short4v*)&Al[base + 8];
    }
    __syncthreads();
    // stage W1^T [32 col][64 k], hoist
    if(tid < 128){
        int col = tid >> 2, kseg = (tid & 3) * 16;
        short hi[16], lo[16];
        #pragma unroll
        for(int j=0;j<16;++j){
            float v = W1[(kseg+j)*32 + col];
            short h = f2bf_rne(v);
            hi[j] = h; lo[j] = f2bf_rne(v - bf2f(h));
        }
        #pragma unroll
        for(int i=0;i<4;++i){
            *(short4v*)&Ah[col*68 + kseg + 4*i] = *(short4v*)&hi[4*i];
            *(short4v*)&Al[col*68 + kseg + 4*i] = *(short4v*)&lo[4*i];
        }
    }
    __syncthreads();
    short8v w0h[4], w0l[4];
    #pragma unroll
    for(int s=0;s<4;++s){
        int base = c*68 + s*16 + g*4;
        ((short4v*)&w0h[s])[0] = *(short4v*)&Ah[base];
        ((short4v*)&w0h[s])[1] = *(short4v*)&Ah[base + 8];
        ((short4v*)&w0l[s])[0] = *(short4v*)&Al[base];
        ((short4v*)&w0l[s])[1] = *(short4v*)&Al[base + 8];
    }
    __syncthreads();

    float bc1 = bin[colhalf + c];

    const int NT = (N_PREV + 63) / 64;
    for(int tile = blockIdx.x; tile < NT; tile += gridDim.x){
        int rbase = tile * 64;
        // stage F tile hi/lo
        {
            int row = tid >> 2, kseg = (tid & 3) * 16;
            int grow = rbase + row;
            float fv[16];
            if(grow < N_PREV){
                const float4* fp = (const float4*)&feat[grow*64 + kseg];
                *(float4*)&fv[0]  = fp[0];
                *(float4*)&fv[4]  = fp[1];
                *(float4*)&fv[8]  = fp[2];
                *(float4*)&fv[12] = fp[3];
            } else {
                #pragma unroll
                for(int j=0;j<16;++j) fv[j]=0.f;
            }
            short hi[16], lo[16];
            #pragma unroll
            for(int j=0;j<16;++j){
                short h = f2bf_rne(fv[j]);
                hi[j] = h; lo[j] = f2bf_rne(fv[j] - bf2f(h));
            }
            #pragma unroll
            for(int i=0;i<4;++i){
                *(short4v*)&Ah[row*68 + kseg + 4*i] = *(short4v*)&hi[4*i];
                *(short4v*)&Al[row*68 + kseg + 4*i] = *(short4v*)&lo[4*i];
            }
        }
        // ranks for this tile's rows
        if(tid < 64){
            int grow = rbase + tid;
            if(grow < N_PREV){
                int4 c4 = ((const int4*)coors)[grow];
                int key = voxel_key(c4);
                int w = key>>5, b = key&31;
                int rank = (int)(boff[w>>10] + pref[w]) + __popc(bitmap[w] & ((1u<<b)-1u));
                rksh[tid] = rank;
                inv[grow] = rank;
                atomicAdd(&cnt[rank], 1.0f);
            } else rksh[tid] = -1;
        }
        __syncthreads();
        // GEMM1: I = lrelu(F@Win + b)  (all waves)
        f32x16 acc;
        #pragma unroll
        for(int i=0;i<16;++i) acc[i]=0.f;
        #pragma unroll
        for(int s=0;s<4;++s){
            int abase = (rowhalf + c)*68 + s*16 + g*4;
            short8v ah, al;
            ((short4v*)&ah)[0] = *(short4v*)&Ah[abase];
            ((short4v*)&ah)[1] = *(short4v*)&Ah[abase + 8];
            ((short4v*)&al)[0] = *(short4v*)&Al[abase];
            ((short4v*)&al)[1] = *(short4v*)&Al[abase + 8];
            acc = __builtin_amdgcn_mfma_f32_32x32x16_bf16(ah, w1h[s], acc, 0,0,0);
            acc = __builtin_amdgcn_mfma_f32_32x32x16_bf16(al, w1h[s], acc, 0,0,0);
            acc = __builtin_amdgcn_mfma_f32_32x32x16_bf16(ah, w1l[s], acc, 0,0,0);
        }
        // GEMM0: Y = F@W1  (waves 0/1)
        f32x16 accY;
        #pragma unroll
        for(int i=0;i<16;++i) accY[i]=0.f;
        if(wave < 2){
            #pragma unroll
            for(int s=0;s<4;++s){
                int abase = (wave*32 + c)*68 + s*16 + g*4;
                short8v ah, al;
                ((short4v*)&ah)[0] = *(short4v*)&Ah[abase];
                ((short4v*)&ah)[1] = *(short4v*)&Ah[abase + 8];
                ((short4v*)&al)[0] = *(short4v*)&Al[abase];
                ((short4v*)&al)[1] = *(short4v*)&Al[abase + 8];
                accY = __builtin_amdgcn_mfma_f32_32x32x16_bf16(ah, w0h[s], accY, 0,0,0);
                accY = __builtin_amdgcn_mfma_f32_32x32x16_bf16(al, w0h[s], accY, 0,0,0);
                accY = __builtin_amdgcn_mfma_f32_32x32x16_bf16(ah, w0l[s], accY, 0,0,0);
            }
        }
        __syncthreads();
        // epilogue: I -> LDS hi/lo; Y -> ysh
        #pragma unroll
        for(int r=0;r<16;++r){
            int row = rowhalf + (r&3) + 8*(r>>2) + 4*g;
            float v = acc[r] + bc1;
            v = v > 0.f ? v : 0.1f*v;
            short h = f2bf_rne(v);
            Ah[row*68 + colhalf + c] = h;
            Al[row*68 + colhalf + c] = f2bf_rne(v - bf2f(h));
        }
        if(wave < 2){
            #pragma unroll
            for(int r=0;r<16;++r){
                int row = wave*32 + (r&3) + 8*(r>>2) + 4*g;
                ysh[row][c] = accY[r];
            }
        }
        __syncthreads();
        // GEMM2: P1 = I @ Wo1a
        f32x16 acc2;
        #pragma unroll
        for(int i=0;i<16;++i) acc2[i]=0.f;
        #pragma unroll
        for(int s=0;s<4;++s){
            int abase = (rowhalf + c)*68 + s*16 + g*4;
            short8v ah, al;
            ((short4v*)&ah)[0] = *(short4v*)&Ah[abase];
            ((short4v*)&ah)[1] = *(short4v*)&Ah[abase + 8];
            ((short4v*)&al)[0] = *(short4v*)&Al[abase];
            ((short4v*)&al)[1] = *(short4v*)&Al[abase + 8];
            acc2 = __builtin_amdgcn_mfma_f32_32x32x16_bf16(ah, w2h[s], acc2, 0,0,0);
            acc2 = __builtin_amdgcn_mfma_f32_32x32x16_bf16(al, w2h[s], acc2, 0,0,0);
            acc2 = __builtin_amdgcn_mfma_f32_32x32x16_bf16(ah, w2l[s], acc2, 0,0,0);
        }
        #pragma unroll
        for(int r=0;r<16;++r){
            int grow = rbase + rowhalf + (r&3) + 8*(r>>2) + 4*g;
            if(grow < N_PREV) P1[grow*64 + colhalf + c] = (unsigned short)f2bf_rne(acc2[r]);
        }
        // scatter Y tile into yb by rank (packed bf16 atomics: 2 channels/op)
        #pragma unroll
        for(int q=0;q<4;++q){
            int e = q*256 + tid;          // 64 rows x 16 pairs
            int row = e >> 4, pr = e & 15;
            int rk = rksh[row];
            if(rk >= 0){
                unsigned h0 = (unsigned)(unsigned short)f2bf_rne(ysh[row][2*pr]);
                unsigned h1 = (unsigned)(unsigned short)f2bf_rne(ysh[row][2*pr+1]);
                unsigned pk = h0 | (h1 << 16);
                unsigned short* addr = yb + (size_t)rk*32 + 2*pr;
                asm volatile("global_atomic_pk_add_bf16 %0, %1, off"
                             :: "v"(addr), "v"(pk) : "memory");
            }
        }
        __syncthreads();
    }
}

// ---- BN1 stats over x1 = lrelu(y/cnt + b1)  (stats only; y is bf16) ----
__global__ void __launch_bounds__(256) k_bn1(const unsigned short* __restrict__ yb,
        const float* __restrict__ cnt, const unsigned* __restrict__ Ucnt,
        const float* __restrict__ b1, float* __restrict__ stats){
    __shared__ float sst[32], qst[32];
    int tid = threadIdx.x;
    if(tid < 32){ sst[tid]=0.f; qst[tid]=0.f; }
    __syncthreads();
    int U = (int)Ucnt[0];
    int total = U*4;                 // uint4 (8 bf16) per element
    int c8 = (tid&3)*8;
    float bb[8];
    #pragma unroll
    for(int j=0;j<8;++j) bb[j] = b1[c8+j];
    float s[8], q[8];
    #pragma unroll
    for(int j=0;j<8;++j){ s[j]=0.f; q[j]=0.f; }
    for(int e = blockIdx.x*256 + tid; e < total; e += gridDim.x*256){
        int row = e >> 2;
        float rv = 1.0f/cnt[row];
        uint4 a = ((const uint4*)yb)[e];
        unsigned wv[4] = {a.x,a.y,a.z,a.w};
        #pragma unroll
        for(int k=0;k<4;++k){
            float lo = __uint_as_float(wv[k]<<16);
            float hi = __uint_as_float(wv[k]&0xffff0000u);
            float v0 = lrelu(lo*rv + bb[2*k]);
            float v1 = lrelu(hi*rv + bb[2*k+1]);
            s[2*k]+=v0; q[2*k]+=v0*v0;
            s[2*k+1]+=v1; q[2*k+1]+=v1*v1;
        }
    }
    #pragma unroll
    for(int j=0;j<8;++j){ atomicAdd(&sst[c8+j], s[j]); atomicAdd(&qst[c8+j], q[j]); }
    __syncthreads();
    if(tid < 32){ atomicAdd(&stats[tid], sst[tid]); atomicAdd(&stats[32+tid], qst[tid]); }
}

__global__ void k_bnfin(const unsigned* __restrict__ Ucnt, const float* __restrict__ g,
                        float* __restrict__ stats, int off){
    int c = threadIdx.x;
    if(c>=32) return;
    float n = (float)max(Ucnt[0], 1u);
    float mu = stats[off+c]/n;
    float var = stats[off+32+c]/n - mu*mu;
    stats[off+64+c] = mu;
    stats[off+96+c] = g[c]*rsqrtf(var + EPSF);
}

// ---- x2 = lrelu(BN1(lrelu(y/cnt+b1)) @ W2 + b2) (bf16 out), BN2 stats.  MFMA 128x32, k=32 ----
__global__ void __launch_bounds__(256) k_ppm2(const unsigned short* __restrict__ yb,
        const float* __restrict__ cnt, const unsigned* __restrict__ Ucnt,
        const float* __restrict__ W2, const float* __restrict__ b1i,
        const float* __restrict__ b2, const float* __restrict__ be1,
        unsigned short* __restrict__ x2b, float* __restrict__ stats){
    __shared__ __align__(16) short Ah[128*36];
    __shared__ __align__(16) short Al[128*36];
    __shared__ float ash[32], bbsh[32], b1sh[32];
    __shared__ float red[4][64];
    int tid = threadIdx.x;
    int wave = tid >> 6, l = tid & 63;
    int g = l >> 5, c = l & 31;

    if(tid < 32){
        float mu=stats[64+tid], sc=stats[96+tid];
        ash[tid]=sc; bbsh[tid]=be1[tid]-mu*sc;
        b1sh[tid]=b1i[tid];
    }
    if(tid >= 64 && tid < 128){
        int t = tid - 64;
        int col = t >> 1, kseg = (t & 1) * 16;
        short hi[16], lo[16];
        #pragma unroll
        for(int j=0;j<16;++j){
            float v = W2[(kseg+j)*32 + col];
            short h = f2bf_rne(v);
            hi[j] = h; lo[j] = f2bf_rne(v - bf2f(h));
        }
        #pragma unroll
        for(int i=0;i<4;++i){
            *(short4v*)&Ah[col*36 + kseg + 4*i] = *(short4v*)&hi[4*i];
            *(short4v*)&Al[col*36 + kseg + 4*i] = *(short4v*)&lo[4*i];
        }
    }
    __syncthreads();
    short8v wh[2], wl[2];
    #pragma unroll
    for(int s=0;s<2;++s){
        int base = c*36 + s*16 + g*4;
        ((short4v*)&wh[s])[0] = *(short4v*)&Ah[base];
        ((short4v*)&wh[s])[1] = *(short4v*)&Ah[base + 8];
        ((short4v*)&wl[s])[0] = *(short4v*)&Al[base];
        ((short4v*)&wl[s])[1] = *(short4v*)&Al[base + 8];
    }
    __syncthreads();

    int U = (int)Ucnt[0];
    float bc = b2[c];
    float s_acc = 0.f, q_acc = 0.f;

    const int NT = (N_PREV + 127) / 128;
    for(int tile = blockIdx.x; tile < NT; tile += gridDim.x){
        int rbase = tile * 128;
        if(rbase >= U) break;
        {
            int row = tid >> 1, kseg = (tid & 1) * 16;
            int grow = rbase + row;
            float fv[16];
            if(grow < U){
                float rv = 1.0f/cnt[grow];
                uint4 a0 = *(const uint4*)&yb[grow*32 + kseg];
                uint4 a1 = *(const uint4*)&yb[grow*32 + kseg + 8];
                unsigned wv[8] = {a0.x,a0.y,a0.z,a0.w,a1.x,a1.y,a1.z,a1.w};
                #pragma unroll
                for(int k=0;k<8;++k){
                    float lo = __uint_as_float(wv[k]<<16);
                    float hi = __uint_as_float(wv[k]&0xffff0000u);
                    float v0 = lrelu(lo*rv + b1sh[kseg+2*k]);
                    float v1 = lrelu(hi*rv + b1sh[kseg+2*k+1]);
                    fv[2*k]   = v0*ash[kseg+2*k]   + bbsh[kseg+2*k];
                    fv[2*k+1] = v1*ash[kseg+2*k+1] + bbsh[kseg+2*k+1];
                }
            } else {
                #pragma unroll
                for(int j=0;j<16;++j) fv[j]=0.f;
            }
            short hi[16], lo[16];
            #pragma unroll
            for(int j=0;j<16;++j){
                short h = f2bf_rne(fv[j]);
                hi[j] = h; lo[j] = f2bf_rne(fv[j] - bf2f(h));
            }
            #pragma unroll
            for(int i=0;i<4;++i){
                *(short4v*)&Ah[row*36 + kseg + 4*i] = *(short4v*)&hi[4*i];
                *(short4v*)&Al[row*36 + kseg + 4*i] = *(short4v*)&lo[4*i];
            }
        }
        __syncthreads();
        f32x16 acc;
        #pragma unroll
        for(int i=0;i<16;++i) acc[i]=0.f;
        #pragma unroll
        for(int s=0;s<2;++s){
            int abase = (wave*32 + c)*36 + s*16 + g*4;
            short8v ah, al;
            ((short4v*)&ah)[0] = *(short4v*)&Ah[abase];
            ((short4v*)&ah)[1] = *(short4v*)&Ah[abase + 8];
            ((short4v*)&al)[0] = *(short4v*)&Al[abase];
            ((short4v*)&al)[1] = *(short4v*)&Al[abase + 8];
            acc = __builtin_amdgcn_mfma_f32_32x32x16_bf16(ah, wh[s], acc, 0,0,0);
            acc = __builtin_amdgcn_mfma_f32_32x32x16_bf16(al, wh[s], acc, 0,0,0);
            acc = __builtin_amdgcn_mfma_f32_32x32x16_bf16(ah, wl[s], acc, 0,0,0);
        }
        #pragma unroll
        for(int r=0;r<16;++r){
            int rl = wave*32 + (r&3) + 8*(r>>2) + 4*g;
            int grow = rbase + rl;
            if(grow < U){
                float v = acc[r] + bc;
                v = v > 0.f ? v : 0.1f*v;
                x2b[grow*32 + c] = (unsigned short)f2bf_rne(v);
                s_acc += v; q_acc += v*v;
            }
        }
        __syncthreads();
    }
    s_acc += __shfl_xor(s_acc, 32);
    q_acc += __shfl_xor(q_acc, 32);
    if(l < 32){ red[wave][c] = s_acc; red[wave][32+c] = q_acc; }
    __syncthreads();
    if(tid < 64){
        float t = red[0][tid]+red[1][tid]+red[2][tid]+red[3][tid];
        atomicAdd(&stats[128+tid], t);
    }
}

// ---- P2 = lrelu(BN2(x2) @ W3 + b3) @ Wo1b  [U,64] bf16.  MFMA 64x64 ----
__global__ void __launch_bounds__(256) k_ppm3(const unsigned short* __restrict__ x2b,
        const unsigned* __restrict__ Ucnt, const float* __restrict__ W3,
        const float* __restrict__ b3, const float* __restrict__ be2,
        const float* __restrict__ Wo1, unsigned short* __restrict__ P2,
        const float* __restrict__ stats){
    __shared__ __align__(16) short Ah[64*36];
    __shared__ __align__(16) short Al[64*36];
    __shared__ __align__(16) short Ih[64*68];
    __shared__ __align__(16) short Il[64*68];
    __shared__ float ash[32], bbsh[32];
    int tid = threadIdx.x;
    int wave = tid >> 6, l = tid & 63;
    int g = l >> 5, c = l & 31;
    int rowhalf = (wave >> 1) * 32, colhalf = (wave & 1) * 32;

    if(tid < 32){
        float mu=stats[192+tid], sc=stats[224+tid];
        ash[tid]=sc; bbsh[tid]=be2[tid]-mu*sc;
    }
    if(tid >= 128){
        int t = tid - 128;
        int col = t >> 1, kseg = (t & 1) * 16;
        short hi[16], lo[16];
        #pragma unroll
        for(int j=0;j<16;++j){
            float v = W3[(kseg+j)*64 + col];
            short h = f2bf_rne(v);
            hi[j] = h; lo[j] = f2bf_rne(v - bf2f(h));
        }
        #pragma unroll
        for(int i=0;i<4;++i){
            *(short4v*)&Ih[col*36 + kseg + 4*i] = *(short4v*)&hi[4*i];
            *(short4v*)&Il[col*36 + kseg + 4*i] = *(short4v*)&lo[4*i];
        }
    }
    __syncthreads();
    short8v w3h[2], w3l[2];
    #pragma unroll
    for(int s=0;s<2;++s){
        int base = (colhalf + c)*36 + s*16 + g*4;
        ((short4v*)&w3h[s])[0] = *(short4v*)&Ih[base];
        ((short4v*)&w3h[s])[1] = *(short4v*)&Ih[base + 8];
        ((short4v*)&w3l[s])[0] = *(short4v*)&Il[base];
        ((short4v*)&w3l[s])[1] = *(short4v*)&Il[base + 8];
    }
    __syncthreads();
    {
        int col = tid >> 2, kseg = (tid & 3) * 16;
        short hi[16], lo[16];
        #pragma unroll
        for(int j=0;j<16;++j){
            float v = Wo1[4096 + (kseg+j)*64 + col];
            short h = f2bf_rne(v);
            hi[j] = h; lo[j] = f2bf_rne(v - bf2f(h));
        }
        #pragma unroll
        for(int i=0;i<4;++i){
            *(short4v*)&Ih[col*68 + kseg + 4*i] = *(short4v*)&hi[4*i];
            *(short4v*)&Il[col*68 + kseg + 4*i] = *(short4v*)&lo[4*i];
        }
    }
    __syncthreads();
    short8v w2h[4], w2l[4];
    #pragma unroll
    for(int s=0;s<4;++s){
        int base = (colhalf + c)*68 + s*16 + g*4;
        ((short4v*)&w2h[s])[0] = *(short4v*)&Ih[base];
        ((short4v*)&w2h[s])[1] = *(short4v*)&Ih[base + 8];
        ((short4v*)&w2l[s])[0] = *(short4v*)&Il[base];
        ((short4v*)&w2l[s])[1] = *(short4v*)&Il[base + 8];
    }
    __syncthreads();

    int U = (int)Ucnt[0];
    float bc3 = b3[colhalf + c];

    const int NT = (N_PREV + 63) / 64;
    for(int tile = blockIdx.x; tile < NT; tile += gridDim.x){
        int rbase = tile * 64;
        if(rbase >= U) break;
        if(tid < 128){
            int row = tid >> 1, kseg = (tid & 1) * 16;
            int grow = rbase + row;
            float fv[16];
            if(grow < U){
                uint4 a0 = *(const uint4*)&x2b[grow*32 + kseg];
                uint4 a1 = *(const uint4*)&x2b[grow*32 + kseg + 8];
                unsigned wv[8] = {a0.x,a0.y,a0.z,a0.w,a1.x,a1.y,a1.z,a1.w};
                #pragma unroll
                for(int k=0;k<8;++k){
                    float lo = __uint_as_float(wv[k]<<16);
                    float hi = __uint_as_float(wv[k]&0xffff0000u);
                    fv[2*k]   = lo*ash[kseg+2*k]   + bbsh[kseg+2*k];
                    fv[2*k+1] = hi*ash[kseg+2*k+1] + bbsh[kseg+2*k+1];
                }
            } else {
                #pragma unroll
                for(int j=0;j<16;++j) fv[j]=0.f;
            }
            short hi[16], lo[16];
            #pragma unroll
            for(int j=0;j<16;++j){
                short h = f2bf_rne(fv[j]);
                hi[j] = h; lo[j] = f2bf_rne(fv[j] - bf2f(h));
            }
            #pragma unroll
            for(int i=0;i<4;++i){
                *(short4v*)&Ah[row*36 + kseg + 4*i] = *(short4v*)&hi[4*i];
                *(short4v*)&Al[row*36 + kseg + 4*i] = *(short4v*)&lo[4*i];
            }
        }
        __syncthreads();
        f32x16 acc;
        #pragma unroll
        for(int i=0;i<16;++i) acc[i]=0.f;
        #pragma unroll
        for(int s=0;s<2;++s){
            int abase = (rowhalf + c)*36 + s*16 + g*4;
            short8v ah, al;
            ((short4v*)&ah)[0] = *(short4v*)&Ah[abase];
            ((short4v*)&ah)[1] = *(short4v*)&Ah[abase + 8];
            ((short4v*)&al)[0] = *(short4v*)&Al[abase];
            ((short4v*)&al)[1] = *(short4v*)&Al[abase + 8];
            acc = __builtin_amdgcn_mfma_f32_32x32x16_bf16(ah, w3h[s], acc, 0,0,0);
            acc = __builtin_amdgcn_mfma_f32_32x32x16_bf16(al, w3h[s], acc, 0,0,0);
            acc = __builtin_amdgcn_mfma_f32_32x32x16_bf16(ah, w3l[s], acc, 0,0,0);
        }
        #pragma unroll
        for(int r=0;r<16;++r){
            int row = rowhalf + (r&3) + 8*(r>>2) + 4*g;
            float v = acc[r] + bc3;
            v = v > 0.f ? v : 0.1f*v;
            short h = f2bf_rne(v);
            Ih[row*68 + colhalf + c] = h;
            Il[row*68 + colhalf + c] = f2bf_rne(v - bf2f(h));
        }
        __syncthreads();
        f32x16 acc2;
        #pragma unroll
        for(int i=0;i<16;++i) acc2[i]=0.f;
        #pragma unroll
        for(int s=0;s<4;++s){
            int abase = (rowhalf + c)*68 + s*16 + g*4;
            short8v ah, al;
            ((short4v*)&ah)[0] = *(short4v*)&Ih[abase];
            ((short4v*)&ah)[1] = *(short4v*)&Ih[abase + 8];
            ((short4v*)&al)[0] = *(short4v*)&Il[abase];
            ((short4v*)&al)[1] = *(short4v*)&Il[abase + 8];
            acc2 = __builtin_amdgcn_mfma_f32_32x32x16_bf16(ah, w2h[s], acc2, 0,0,0);
            acc2 = __builtin_amdgcn_mfma_f32_32x32x16_bf16(al, w2h[s], acc2, 0,0,0);
            acc2 = __builtin_amdgcn_mfma_f32_32x32x16_bf16(ah, w2l[s], acc2, 0,0,0);
        }
        #pragma unroll
        for(int r=0;r<16;++r){
            int grow = rbase + rowhalf + (r&3) + 8*(r>>2) + 4*g;
            if(grow < U) P2[grow*64 + colhalf + c] = (unsigned short)f2bf_rne(acc2[r]);
        }
        __syncthreads();
    }
}

// ---- one wave per voxel (R6-verified math; loads software-pipelined in batches of 8) ----
__global__ void __launch_bounds__(256) k_vox(const unsigned* __restrict__ vstart,
        const int* __restrict__ csr_j, const int* __restrict__ csr_h,
        const unsigned short* __restrict__ P1, const unsigned short* __restrict__ P2,
        const float* __restrict__ bo1, const float* __restrict__ Wo2,
        const float* __restrict__ bo2, float* __restrict__ out){
    __shared__ float tsh[4][64];
    int tid = threadIdx.x;
    int wib = tid>>6, lane = tid&63;
    float wreg[64];
    #pragma unroll
    for(int k=0;k<64;++k) wreg[k] = Wo2[k*64+lane];
    float b1c = bo1[lane], b2c = bo2[lane];
    int wglobal = blockIdx.x*4 + wib;
    for(int vq=0; vq<4; ++vq){
        int vox = wglobal*4 + vq;
        int s = (int)vstart[vox], e = (int)vstart[vox+1];
        float acc = 0.f;
        for(int i=s; i<e; i+=64){
            int n = min(e-i, 64);
            int jv=0, hv=0;
            if(lane<n){ jv = csr_j[i+lane]; hv = csr_h[i+lane]; }
            for(int q0=0; q0<n; q0+=8){
                float pa[8], pb[8];
                #pragma unroll
                for(int t=0;t<8;++t){
                    int qq = q0 + t;
                    qq = (qq < n) ? qq : q0;
                    int j = __shfl(jv, qq);
                    int h = __shfl(hv, qq);
                    pa[t] = bf2f((short)P1[(size_t)j*64 + lane]);
                    pb[t] = bf2f((short)P2[(size_t)h*64 + lane]);
                }
                #pragma unroll
                for(int t=0;t<8;++t){
                    if(q0 + t < n){
                        float g = pa[t] + pb[t] + b1c;
                        acc += (g>0.f) ? g : 0.1f*g;
                    }
                }
            }
        }
        tsh[wib][lane] = acc;
        float dot = 0.f;
        const float4* t4 = (const float4*)tsh[wib];
        #pragma unroll
        for(int k4=0;k4<16;++k4){
            float4 t = t4[k4];
            dot += t.x*wreg[4*k4] + t.y*wreg[4*k4+1] + t.z*wreg[4*k4+2] + t.w*wreg[4*k4+3];
        }
        float cntv = (float)(e - s);
        out[vox*64+lane] = (dot + cntv*b2c) / fmaxf(cntv, 1.f);
    }
}

extern "C" void kernel_launch(void* const* d_in, const int* in_sizes, int n_in,
                              void* d_out, int out_size, void* d_ws, size_t ws_size,
                              hipStream_t stream) {
    if(ws_size < WS_NEEDED) return;

    const float* features = (const float*)d_in[0];
    const int*   coors    = (const int*)d_in[1];
    const int*   cif      = (const int*)d_in[2];
    const int*   scv      = (const int*)d_in[3];
    const float* W_in     = (const float*)d_in[4];
    const float* b_in     = (const float*)d_in[5];
    const float* W1       = (const float*)d_in[6];
    const float* b1       = (const float*)d_in[7];
    const float* g1       = (const float*)d_in[8];
    const float* be1      = (const float*)d_in[9];
    const float* W2       = (const float*)d_in[10];
    const float* b2       = (const float*)d_in[11];
    const float* g2       = (const float*)d_in[12];
    const float* be2      = (const float*)d_in[13];
    const float* W3       = (const float*)d_in[14];
    const float* b3       = (const float*)d_in[15];
    const float* Wo1      = (const float*)d_in[16];
    const float* bo1      = (const float*)d_in[17];
    const float* Wo2      = (const float*)d_in[18];
    const float* bo2      = (const float*)d_in[19];

    char* ws = (char*)d_ws;
    unsigned* bitmap = (unsigned*)(ws + OFF_BITMAP);
    float*    stats  = (float*)(ws + OFF_STATS);
    float*    cnt    = (float*)(ws + OFF_CNT);
    unsigned* vh     = (unsigned*)(ws + OFF_VH);
    unsigned short* yb = (unsigned short*)(ws + OFF_Y);
    unsigned short* P2 = (unsigned short*)(ws + OFF_P2);
    unsigned* pref   = (unsigned*)(ws + OFF_PREF);
    unsigned* bsum   = (unsigned*)(ws + OFF_BSUM);
    unsigned* boff   = (unsigned*)(ws + OFF_BOFF);
    unsigned* Ucnt   = (unsigned*)(ws + OFF_UCNT);
    int*      inv    = (int*)(ws + OFF_INV);
    unsigned short* P1 = (unsigned short*)(ws + OFF_P1);
    unsigned short* x2b = (unsigned short*)(ws + OFF_X2);
    int*      csr_j  = (int*)(ws + OFF_CSRJ);
    int*      csr_h  = (int*)(ws + OFF_CSRH);
    unsigned* vstart = (unsigned*)(ws + OFF_VSTART);
    unsigned* vnext  = (unsigned*)(ws + OFF_VNEXT);
    unsigned* vpart  = (unsigned*)(ws + OFF_VPART);
    unsigned* vbsum  = (unsigned*)(ws + OFF_VBSUM);

    hipMemsetAsync(d_ws, 0, ZERO_BYTES, stream);

    k_mark  <<<(N_PREV+255)/256, 256, 0, stream>>>(coors, bitmap);
    k_scanA <<<1024, 1024, 0, stream>>>(bitmap, pref, bsum);
    k_scanB <<<1, 1024, 0, stream>>>(bsum, boff, Ucnt);
    k_p1f   <<<1024, 256, 0, stream>>>(features, coors, bitmap, pref, boff,
                                       W_in, b_in, Wo1, W1, P1, inv, cnt, yb);
    // CSR build (overwrites bitmap/pref regions — safe after k_p1f)
    k_vhist <<<(N_FULL+255)/256, 256, 0, stream>>>(scv, vh);
    k_vscanA<<<64, 1024, 0, stream>>>(vh, vpart, vbsum);
    k_vscanB<<<1, 64, 0, stream>>>(vbsum);
    k_vfix  <<<64, 1024, 0, stream>>>(vpart, vbsum, vstart, vnext);
    k_fill  <<<(N_FULL+255)/256, 256, 0, stream>>>(cif, scv, inv, vnext, csr_j, csr_h);
    // PPmodel chain
    k_bn1   <<<1024, 256, 0, stream>>>(yb, cnt, Ucnt, b1, stats);
    k_bnfin <<<1, 32, 0, stream>>>(Ucnt, g1, stats, 0);
    k_ppm2  <<<1024, 256, 0, stream>>>(yb, cnt, Ucnt, W2, b1, b2, be1, x2b, stats);
    k_bnfin <<<1, 32, 0, stream>>>(Ucnt, g2, stats, 128);
    k_ppm3  <<<1024, 256, 0, stream>>>(x2b, Ucnt, W3, b3, be2, Wo1, P2, stats);
    k_vox   <<<NVOX/16, 256, 0, stream>>>(vstart, csr_j, csr_h, P1, P2, bo1, Wo2, bo2, (float*)d_out);
}

// Round 11
// 279.700 us; speedup vs baseline: 3.4703x; 1.0618x over previous
//
#include <hip/hip_runtime.h>

#define N_PREV 250000
#define N_FULL 500000
#define NVOX   65536
#define NWORDS (1u<<20)          // bitmap words; keyspace < 2^25 bits
#define EPSF   1e-5f

typedef __attribute__((ext_vector_type(4)))  short short4v;
typedef __attribute__((ext_vector_type(8)))  short short8v;
typedef __attribute__((ext_vector_type(16))) float f32x16;

__device__ __forceinline__ float lrelu(float x){ return x > 0.0f ? x : 0.1f*x; }
__device__ __forceinline__ short f2bf_rne(float v){
    unsigned u = __float_as_uint(v);
    unsigned r = (u + 0x7fffu + ((u>>16)&1u)) >> 16;
    return (short)r;
}
__device__ __forceinline__ float bf2f(short s){
    return __uint_as_float(((unsigned)(unsigned short)s) << 16);
}

// ---------------- ws layout (bytes) ----------------
// zeroed prefix:
#define OFF_BITMAP   0ul            // u32[NWORDS] (aliased as csr_j/csr_h after k_p1f)
#define OFF_STATS    4194304ul      // f32[256]
#define OFF_CNT      4195328ul      // f32[N_PREV]
#define OFF_VH       5195328ul      // u32[NVOX]
#define OFF_Y        5457472ul      // bf16[N_PREV*32]  16 MB
#define ZERO_BYTES   21457472ul
// not zeroed:
#define OFF_P2       37457472ul     // bf16[N_PREV*64] 32 MB
#define OFF_PREF     69457472ul     // u32[NWORDS] (aliased as vstart/vnext/vpart/vbsum after p1f)
#define OFF_BSUM     73651776ul
#define OFF_BOFF     73655872ul
#define OFF_UCNT     73659968ul
#define OFF_INV      73660224ul     // i32[N_PREV]
#define OFF_P1       74660224ul     // bf16[N_PREV*64] 32 MB
#define OFF_X2       106660224ul    // bf16[N_PREV*32]  16 MB
#define WS_NEEDED    138660224ul
#define OFF_CSRJ     0ul
#define OFF_CSRH     2000000ul
#define OFF_VSTART   69457472ul
#define OFF_VNEXT    (OFF_VSTART+262400ul)
#define OFF_VPART    (OFF_VNEXT+262144ul)
#define OFF_VBSUM    (OFF_VPART+262144ul)

__device__ __forceinline__ int voxel_key(int4 c){
    return ((c.x*501 + (c.y>>1))*501 + (c.z>>1))*31 + (c.w>>1);
}

// ---- mark present keys ----
__global__ void k_mark(const int* __restrict__ coors, unsigned* __restrict__ bitmap){
    int i = blockIdx.x*256 + threadIdx.x;
    if(i >= N_PREV) return;
    int4 c = ((const int4*)coors)[i];
    int key = voxel_key(c);
    atomicOr(&bitmap[key>>5], 1u<<(key&31));
}

__global__ void __launch_bounds__(1024) k_scanA(const unsigned* __restrict__ bitmap,
                                                unsigned* __restrict__ pref,
                                                unsigned* __restrict__ bsum){
    __shared__ unsigned sh[1024];
    int tid = threadIdx.x;
    int w = blockIdx.x*1024 + tid;
    unsigned p = __popc(bitmap[w]);
    sh[tid] = p; __syncthreads();
    for(int off=1; off<1024; off<<=1){
        unsigned v = (tid>=off) ? sh[tid-off] : 0u;
        __syncthreads();
        sh[tid] += v;
        __syncthreads();
    }
    pref[w] = sh[tid] - p;
    if(tid==1023) bsum[blockIdx.x] = sh[tid];
}

__global__ void __launch_bounds__(1024) k_scanB(const unsigned* __restrict__ bsum,
                                                unsigned* __restrict__ boff,
                                                unsigned* __restrict__ Ucnt){
    __shared__ unsigned sh[1024];
    int tid = threadIdx.x;
    unsigned p = bsum[tid];
    sh[tid] = p; __syncthreads();
    for(int off=1; off<1024; off<<=1){
        unsigned v = (tid>=off) ? sh[tid-off] : 0u;
        __syncthreads();
        sh[tid] += v;
        __syncthreads();
    }
    boff[tid] = sh[tid] - p;
    if(tid==1023) Ucnt[0] = sh[tid];
}

// ---- CSR build over scale voxels ----
__global__ void k_vhist(const int* __restrict__ scv, unsigned* __restrict__ vh){
    int p = blockIdx.x*256 + threadIdx.x;
    if(p < N_FULL) atomicAdd(&vh[scv[p]], 1u);
}

__global__ void __launch_bounds__(1024) k_vscanA(const unsigned* __restrict__ vh,
                                                 unsigned* __restrict__ vpart,
                                                 unsigned* __restrict__ vbsum){
    __shared__ unsigned sh[1024];
    int tid = threadIdx.x;
    int w = blockIdx.x*1024 + tid;
    unsigned p = vh[w];
    sh[tid] = p; __syncthreads();
    for(int off=1; off<1024; off<<=1){
        unsigned v = (tid>=off) ? sh[tid-off] : 0u;
        __syncthreads();
        sh[tid] += v;
        __syncthreads();
    }
    vpart[w] = sh[tid] - p;
    if(tid==1023) vbsum[blockIdx.x] = sh[tid];
}

__global__ void k_vscanB(unsigned* __restrict__ vbsum){
    int l = threadIdx.x;
    unsigned v = vbsum[l], orig = v;
    for(int off=1; off<64; off<<=1){
        unsigned o = __shfl_up(v, off);
        if(l>=off) v += o;
    }
    vbsum[l] = v - orig;
}

__global__ void __launch_bounds__(1024) k_vfix(const unsigned* __restrict__ vpart,
                                               const unsigned* __restrict__ vbsum,
                                               unsigned* __restrict__ vstart,
                                               unsigned* __restrict__ vnext){
    int w = blockIdx.x*1024 + threadIdx.x;
    unsigned s = vpart[w] + vbsum[w>>10];
    vstart[w] = s; vnext[w] = s;
    if(w == NVOX-1) vstart[NVOX] = N_FULL;
}

__global__ void k_fill(const int* __restrict__ cif, const int* __restrict__ scv,
                       const int* __restrict__ inv, unsigned* __restrict__ vnext,
                       int* __restrict__ csr_j, int* __restrict__ csr_h){
    int p = blockIdx.x*256 + threadIdx.x;
    if(p >= N_FULL) return;
    int jp = cif[p];
    unsigned pos = atomicAdd(&vnext[scv[p]], 1u);
    csr_j[pos] = jp;
    csr_h[pos] = inv[jp];
}

// ---- fused: P1 = lrelu(F@Win+b)@Wo1a (bf16 out, single-pass GEMM2);
//      Y = F@W1 3-pass (BN-amplified path needs f32 grade), pk bf16 atomic scatter;
//      rank/inv/cnt inline. ----
__global__ void __launch_bounds__(256) k_p1f(const float* __restrict__ feat,
        const int* __restrict__ coors, const unsigned* __restrict__ bitmap,
        const unsigned* __restrict__ pref, const unsigned* __restrict__ boff,
        const float* __restrict__ Win, const float* __restrict__ bin,
        const float* __restrict__ Wo1, const float* __restrict__ W1,
        unsigned short* __restrict__ P1, int* __restrict__ inv,
        float* __restrict__ cnt, unsigned short* __restrict__ yb){
    __shared__ __align__(16) short Ah[64*68];
    __shared__ __align__(16) short Al[64*68];
    __shared__ float ysh[64][33];
    __shared__ int rksh[64];
    int tid = threadIdx.x;
    int wave = tid >> 6, l = tid & 63;
    int g = l >> 5, c = l & 31;
    int rowhalf = (wave >> 1) * 32, colhalf = (wave & 1) * 32;

    // stage Win^T (hi/lo), hoist
    {
        int col = tid >> 2, kseg = (tid & 3) * 16;
        short hi[16], lo[16];
        #pragma unroll
        for(int j=0;j<16;++j){
            float v = Win[(kseg+j)*64 + col];
            short h = f2bf_rne(v);
            hi[j] = h; lo[j] = f2bf_rne(v - bf2f(h));
        }
        #pragma unroll
        for(int i=0;i<4;++i){
            *(short4v*)&Ah[col*68 + kseg + 4*i] = *(short4v*)&hi[4*i];
            *(short4v*)&Al[col*68 + kseg + 4*i] = *(short4v*)&lo[4*i];
        }
    }
    __syncthreads();
    short8v w1h[4], w1l[4];
    #pragma unroll
    for(int s=0;s<4;++s){
        int base = (colhalf + c)*68 + s*16 + g*4;
        ((short4v*)&w1h[s])[0] = *(short4v*)&Ah[base];
        ((short4v*)&w1h[s])[1] = *(short4v*)&Ah[base + 8];
        ((short4v*)&w1l[s])[0] = *(short4v*)&Al[base];
        ((short4v*)&w1l[s])[1] = *(short4v*)&Al[base + 8];
    }
    __syncthreads();
    // stage Wo1a^T (hi only), hoist
    {
        int col = tid >> 2, kseg = (tid & 3) * 16;
        short hi[16];
        #pragma unroll
        for(int j=0;j<16;++j) hi[j] = f2bf_rne(Wo1[(kseg+j)*64 + col]);
        #pragma unroll
        for(int i=0;i<4;++i)
            *(short4v*)&Ah[col*68 + kseg + 4*i] = *(short4v*)&hi[4*i];
    }
    __syncthreads();
    short8v w2h[4];
    #pragma unroll
    for(int s=0;s<4;++s){
        int base = (colhalf + c)*68 + s*16 + g*4;
        ((short4v*)&w2h[s])[0] = *(short4v*)&Ah[base];
        ((short4v*)&w2h[s])[1] = *(short4v*)&Ah[base + 8];
    }
    __syncthreads();
    // stage W1^T [32 col][64 k] (hi/lo), hoist
    if(tid < 128){
        int col = tid >> 2, kseg = (tid & 3) * 16;
        short hi[16], lo[16];
        #pragma unroll
        for(int j=0;j<16;++j){
            float v = W1[(kseg+j)*32 + col];
            short h = f2bf_rne(v);
            hi[j] = h; lo[j] = f2bf_rne(v - bf2f(h));
        }
        #pragma unroll
        for(int i=0;i<4;++i){
            *(short4v*)&Ah[col*68 + kseg + 4*i] = *(short4v*)&hi[4*i];
            *(short4v*)&Al[col*68 + kseg + 4*i] = *(short4v*)&lo[4*i];
        }
    }
    __syncthreads();
    short8v w0h[4], w0l[4];
    #pragma unroll
    for(int s=0;s<4;++s){
        int base = c*68 + s*16 + g*4;
        ((short4v*)&w0h[s])[0] = *(short4v*)&Ah[base];
        ((short4v*)&w0h[s])[1] = *(short4v*)&Ah[base + 8];
        ((short4v*)&w0l[s])[0] = *(short4v*)&Al[base];
        ((short4v*)&w0l[s])[1] = *(short4v*)&Al[base + 8];
    }
    __syncthreads();

    float bc1 = bin[colhalf + c];

    const int NT = (N_PREV + 63) / 64;
    for(int tile = blockIdx.x; tile < NT; tile += gridDim.x){
        int rbase = tile * 64;
        // stage F tile hi/lo
        {
            int row = tid >> 2, kseg = (tid & 3) * 16;
            int grow = rbase + row;
            float fv[16];
            if(grow < N_PREV){
                const float4* fp = (const float4*)&feat[grow*64 + kseg];
                *(float4*)&fv[0]  = fp[0];
                *(float4*)&fv[4]  = fp[1];
                *(float4*)&fv[8]  = fp[2];
                *(float4*)&fv[12] = fp[3];
            } else {
                #pragma unroll
                for(int j=0;j<16;++j) fv[j]=0.f;
            }
            short hi[16], lo[16];
            #pragma unroll
            for(int j=0;j<16;++j){
                short h = f2bf_rne(fv[j]);
                hi[j] = h; lo[j] = f2bf_rne(fv[j] - bf2f(h));
            }
            #pragma unroll
            for(int i=0;i<4;++i){
                *(short4v*)&Ah[row*68 + kseg + 4*i] = *(short4v*)&hi[4*i];
                *(short4v*)&Al[row*68 + kseg + 4*i] = *(short4v*)&lo[4*i];
            }
        }
        // ranks for this tile's rows
        if(tid < 64){
            int grow = rbase + tid;
            if(grow < N_PREV){
                int4 c4 = ((const int4*)coors)[grow];
                int key = voxel_key(c4);
                int w = key>>5, b = key&31;
                int rank = (int)(boff[w>>10] + pref[w]) + __popc(bitmap[w] & ((1u<<b)-1u));
                rksh[tid] = rank;
                inv[grow] = rank;
                atomicAdd(&cnt[rank], 1.0f);
            } else rksh[tid] = -1;
        }
        __syncthreads();
        // GEMM1: I = lrelu(F@Win + b)  (3-pass, all waves)
        f32x16 acc;
        #pragma unroll
        for(int i=0;i<16;++i) acc[i]=0.f;
        #pragma unroll
        for(int s=0;s<4;++s){
            int abase = (rowhalf + c)*68 + s*16 + g*4;
            short8v ah, al;
            ((short4v*)&ah)[0] = *(short4v*)&Ah[abase];
            ((short4v*)&ah)[1] = *(short4v*)&Ah[abase + 8];
            ((short4v*)&al)[0] = *(short4v*)&Al[abase];
            ((short4v*)&al)[1] = *(short4v*)&Al[abase + 8];
            acc = __builtin_amdgcn_mfma_f32_32x32x16_bf16(ah, w1h[s], acc, 0,0,0);
            acc = __builtin_amdgcn_mfma_f32_32x32x16_bf16(al, w1h[s], acc, 0,0,0);
            acc = __builtin_amdgcn_mfma_f32_32x32x16_bf16(ah, w1l[s], acc, 0,0,0);
        }
        // GEMM0: Y = F@W1  (3-pass, waves 0/1)
        f32x16 accY;
        #pragma unroll
        for(int i=0;i<16;++i) accY[i]=0.f;
        if(wave < 2){
            #pragma unroll
            for(int s=0;s<4;++s){
                int abase = (wave*32 + c)*68 + s*16 + g*4;
                short8v ah, al;
                ((short4v*)&ah)[0] = *(short4v*)&Ah[abase];
                ((short4v*)&ah)[1] = *(short4v*)&Ah[abase + 8];
                ((short4v*)&al)[0] = *(short4v*)&Al[abase];
                ((short4v*)&al)[1] = *(short4v*)&Al[abase + 8];
                accY = __builtin_amdgcn_mfma_f32_32x32x16_bf16(ah, w0h[s], accY, 0,0,0);
                accY = __builtin_amdgcn_mfma_f32_32x32x16_bf16(al, w0h[s], accY, 0,0,0);
                accY = __builtin_amdgcn_mfma_f32_32x32x16_bf16(ah, w0l[s], accY, 0,0,0);
            }
        }
        __syncthreads();
        // epilogue: I-hi -> Ah; Y -> ysh
        #pragma unroll
        for(int r=0;r<16;++r){
            int row = rowhalf + (r&3) + 8*(r>>2) + 4*g;
            float v = acc[r] + bc1;
            v = v > 0.f ? v : 0.1f*v;
            Ah[row*68 + colhalf + c] = f2bf_rne(v);
        }
        if(wave < 2){
            #pragma unroll
            for(int r=0;r<16;++r){
                int row = wave*32 + (r&3) + 8*(r>>2) + 4*g;
                ysh[row][c] = accY[r];
            }
        }
        __syncthreads();
        // GEMM2: P1 = I @ Wo1a  (single-pass; P1 stored bf16 anyway)
        f32x16 acc2;
        #pragma unroll
        for(int i=0;i<16;++i) acc2[i]=0.f;
        #pragma unroll
        for(int s=0;s<4;++s){
            int abase = (rowhalf + c)*68 + s*16 + g*4;
            short8v ah;
            ((short4v*)&ah)[0] = *(short4v*)&Ah[abase];
            ((short4v*)&ah)[1] = *(short4v*)&Ah[abase + 8];
            acc2 = __builtin_amdgcn_mfma_f32_32x32x16_bf16(ah, w2h[s], acc2, 0,0,0);
        }
        #pragma unroll
        for(int r=0;r<16;++r){
            int grow = rbase + rowhalf + (r&3) + 8*(r>>2) + 4*g;
            if(grow < N_PREV) P1[grow*64 + colhalf + c] = (unsigned short)f2bf_rne(acc2[r]);
        }
        // scatter Y tile into yb by rank (packed bf16 atomics: 2 channels/op)
        #pragma unroll
        for(int q=0;q<4;++q){
            int e = q*256 + tid;          // 64 rows x 16 pairs
            int row = e >> 4, pr = e & 15;
            int rk = rksh[row];
            if(rk >= 0){
                unsigned h0 = (unsigned)(unsigned short)f2bf_rne(ysh[row][2*pr]);
                unsigned h1 = (unsigned)(unsigned short)f2bf_rne(ysh[row][2*pr+1]);
                unsigned pk = h0 | (h1 << 16);
                unsigned short* addr = yb + (size_t)rk*32 + 2*pr;
                asm volatile("global_atomic_pk_add_bf16 %0, %1, off"
                             :: "v"(addr), "v"(pk) : "memory");
            }
        }
        __syncthreads();
    }
}

// ---- BN1 stats over x1 = lrelu(y/cnt + b1)  (stats only; y is bf16) ----
__global__ void __launch_bounds__(256) k_bn1(const unsigned short* __restrict__ yb,
        const float* __restrict__ cnt, const unsigned* __restrict__ Ucnt,
        const float* __restrict__ b1, float* __restrict__ stats){
    __shared__ float sst[32], qst[32];
    int tid = threadIdx.x;
    if(tid < 32){ sst[tid]=0.f; qst[tid]=0.f; }
    __syncthreads();
    int U = (int)Ucnt[0];
    int total = U*4;                 // uint4 (8 bf16) per element
    int c8 = (tid&3)*8;
    float bb[8];
    #pragma unroll
    for(int j=0;j<8;++j) bb[j] = b1[c8+j];
    float s[8], q[8];
    #pragma unroll
    for(int j=0;j<8;++j){ s[j]=0.f; q[j]=0.f; }
    for(int e = blockIdx.x*256 + tid; e < total; e += gridDim.x*256){
        int row = e >> 2;
        float rv = 1.0f/cnt[row];
        uint4 a = ((const uint4*)yb)[e];
        unsigned wv[4] = {a.x,a.y,a.z,a.w};
        #pragma unroll
        for(int k=0;k<4;++k){
            float lo = __uint_as_float(wv[k]<<16);
            float hi = __uint_as_float(wv[k]&0xffff0000u);
            float v0 = lrelu(lo*rv + bb[2*k]);
            float v1 = lrelu(hi*rv + bb[2*k+1]);
            s[2*k]+=v0; q[2*k]+=v0*v0;
            s[2*k+1]+=v1; q[2*k+1]+=v1*v1;
        }
    }
    #pragma unroll
    for(int j=0;j<8;++j){ atomicAdd(&sst[c8+j], s[j]); atomicAdd(&qst[c8+j], q[j]); }
    __syncthreads();
    if(tid < 32){ atomicAdd(&stats[tid], sst[tid]); atomicAdd(&stats[32+tid], qst[tid]); }
}

__global__ void k_bnfin(const unsigned* __restrict__ Ucnt, const float* __restrict__ g,
                        float* __restrict__ stats, int off){
    int c = threadIdx.x;
    if(c>=32) return;
    float n = (float)max(Ucnt[0], 1u);
    float mu = stats[off+c]/n;
    float var = stats[off+32+c]/n - mu*mu;
    stats[off+64+c] = mu;
    stats[off+96+c] = g[c]*rsqrtf(var + EPSF);
}

// ---- x2 = lrelu(BN1(lrelu(y/cnt+b1)) @ W2 + b2) (bf16 out), BN2 stats.  MFMA 128x32, k=32 ----
__global__ void __launch_bounds__(256) k_ppm2(const unsigned short* __restrict__ yb,
        const float* __restrict__ cnt, const unsigned* __restrict__ Ucnt,
        const float* __restrict__ W2, const float* __restrict__ b1i,
        const float* __restrict__ b2, const float* __restrict__ be1,
        unsigned short* __restrict__ x2b, float* __restrict__ stats){
    __shared__ __align__(16) short Ah[128*36];
    __shared__ __align__(16) short Al[128*36];
    __shared__ float ash[32], bbsh[32], b1sh[32];
    __shared__ float red[4][64];
    int tid = threadIdx.x;
    int wave = tid >> 6, l = tid & 63;
    int g = l >> 5, c = l & 31;

    if(tid < 32){
        float mu=stats[64+tid], sc=stats[96+tid];
        ash[tid]=sc; bbsh[tid]=be1[tid]-mu*sc;
        b1sh[tid]=b1i[tid];
    }
    if(tid >= 64 && tid < 128){
        int t = tid - 64;
        int col = t >> 1, kseg = (t & 1) * 16;
        short hi[16], lo[16];
        #pragma unroll
        for(int j=0;j<16;++j){
            float v = W2[(kseg+j)*32 + col];
            short h = f2bf_rne(v);
            hi[j] = h; lo[j] = f2bf_rne(v - bf2f(h));
        }
        #pragma unroll
        for(int i=0;i<4;++i){
            *(short4v*)&Ah[col*36 + kseg + 4*i] = *(short4v*)&hi[4*i];
            *(short4v*)&Al[col*36 + kseg + 4*i] = *(short4v*)&lo[4*i];
        }
    }
    __syncthreads();
    short8v wh[2], wl[2];
    #pragma unroll
    for(int s=0;s<2;++s){
        int base = c*36 + s*16 + g*4;
        ((short4v*)&wh[s])[0] = *(short4v*)&Ah[base];
        ((short4v*)&wh[s])[1] = *(short4v*)&Ah[base + 8];
        ((short4v*)&wl[s])[0] = *(short4v*)&Al[base];
        ((short4v*)&wl[s])[1] = *(short4v*)&Al[base + 8];
    }
    __syncthreads();

    int U = (int)Ucnt[0];
    float bc = b2[c];
    float s_acc = 0.f, q_acc = 0.f;

    const int NT = (N_PREV + 127) / 128;
    for(int tile = blockIdx.x; tile < NT; tile += gridDim.x){
        int rbase = tile * 128;
        if(rbase >= U) break;
        {
            int row = tid >> 1, kseg = (tid & 1) * 16;
            int grow = rbase + row;
            float fv[16];
            if(grow < U){
                float rv = 1.0f/cnt[grow];
                uint4 a0 = *(const uint4*)&yb[grow*32 + kseg];
                uint4 a1 = *(const uint4*)&yb[grow*32 + kseg + 8];
                unsigned wv[8] = {a0.x,a0.y,a0.z,a0.w,a1.x,a1.y,a1.z,a1.w};
                #pragma unroll
                for(int k=0;k<8;++k){
                    float lo = __uint_as_float(wv[k]<<16);
                    float hi = __uint_as_float(wv[k]&0xffff0000u);
                    float v0 = lrelu(lo*rv + b1sh[kseg+2*k]);
                    float v1 = lrelu(hi*rv + b1sh[kseg+2*k+1]);
                    fv[2*k]   = v0*ash[kseg+2*k]   + bbsh[kseg+2*k];
                    fv[2*k+1] = v1*ash[kseg+2*k+1] + bbsh[kseg+2*k+1];
                }
            } else {
                #pragma unroll
                for(int j=0;j<16;++j) fv[j]=0.f;
            }
            short hi[16], lo[16];
            #pragma unroll
            for(int j=0;j<16;++j){
                short h = f2bf_rne(fv[j]);
                hi[j] = h; lo[j] = f2bf_rne(fv[j] - bf2f(h));
            }
            #pragma unroll
            for(int i=0;i<4;++i){
                *(short4v*)&Ah[row*36 + kseg + 4*i] = *(short4v*)&hi[4*i];
                *(short4v*)&Al[row*36 + kseg + 4*i] = *(short4v*)&lo[4*i];
            }
        }
        __syncthreads();
        f32x16 acc;
        #pragma unroll
        for(int i=0;i<16;++i) acc[i]=0.f;
        #pragma unroll
        for(int s=0;s<2;++s){
            int abase = (wave*32 + c)*36 + s*16 + g*4;
            short8v ah, al;
            ((short4v*)&ah)[0] = *(short4v*)&Ah[abase];
            ((short4v*)&ah)[1] = *(short4v*)&Ah[abase + 8];
            ((short4v*)&al)[0] = *(short4v*)&Al[abase];
            ((short4v*)&al)[1] = *(short4v*)&Al[abase + 8];
            acc = __builtin_amdgcn_mfma_f32_32x32x16_bf16(ah, wh[s], acc, 0,0,0);
            acc = __builtin_amdgcn_mfma_f32_32x32x16_bf16(al, wh[s], acc, 0,0,0);
            acc = __builtin_amdgcn_mfma_f32_32x32x16_bf16(ah, wl[s], acc, 0,0,0);
        }
        #pragma unroll
        for(int r=0;r<16;++r){
            int rl = wave*32 + (r&3) + 8*(r>>2) + 4*g;
            int grow = rbase + rl;
            if(grow < U){
                float v = acc[r] + bc;
                v = v > 0.f ? v : 0.1f*v;
                x2b[grow*32 + c] = (unsigned short)f2bf_rne(v);
                s_acc += v; q_acc += v*v;
            }
        }
        __syncthreads();
    }
    s_acc += __shfl_xor(s_acc, 32);
    q_acc += __shfl_xor(q_acc, 32);
    if(l < 32){ red[wave][c] = s_acc; red[wave][32+c] = q_acc; }
    __syncthreads();
    if(tid < 64){
        float t = red[0][tid]+red[1][tid]+red[2][tid]+red[3][tid];
        atomicAdd(&stats[128+tid], t);
    }
}

// ---- P2 = lrelu(BN2(x2) @ W3 + b3) @ Wo1b  [U,64] bf16.  GEMM2 single-pass ----
__global__ void __launch_bounds__(256) k_ppm3(const unsigned short* __restrict__ x2b,
        const unsigned* __restrict__ Ucnt, const float* __restrict__ W3,
        const float* __restrict__ b3, const float* __restrict__ be2,
        const float* __restrict__ Wo1, unsigned short* __restrict__ P2,
        const float* __restrict__ stats){
    __shared__ __align__(16) short Ah[64*36];
    __shared__ __align__(16) short Al[64*36];
    __shared__ __align__(16) short Ih[64*68];
    __shared__ __align__(16) short Il[64*36];
    __shared__ float ash[32], bbsh[32];
    int tid = threadIdx.x;
    int wave = tid >> 6, l = tid & 63;
    int g = l >> 5, c = l & 31;
    int rowhalf = (wave >> 1) * 32, colhalf = (wave & 1) * 32;

    if(tid < 32){
        float mu=stats[192+tid], sc=stats[224+tid];
        ash[tid]=sc; bbsh[tid]=be2[tid]-mu*sc;
    }
    if(tid >= 128){
        int t = tid - 128;
        int col = t >> 1, kseg = (t & 1) * 16;
        short hi[16], lo[16];
        #pragma unroll
        for(int j=0;j<16;++j){
            float v = W3[(kseg+j)*64 + col];
            short h = f2bf_rne(v);
            hi[j] = h; lo[j] = f2bf_rne(v - bf2f(h));
        }
        #pragma unroll
        for(int i=0;i<4;++i){
            *(short4v*)&Ih[col*36 + kseg + 4*i] = *(short4v*)&hi[4*i];
            *(short4v*)&Il[col*36 + kseg + 4*i] = *(short4v*)&lo[4*i];
        }
    }
    __syncthreads();
    short8v w3h[2], w3l[2];
    #pragma unroll
    for(int s=0;s<2;++s){
        int base = (colhalf + c)*36 + s*16 + g*4;
        ((short4v*)&w3h[s])[0] = *(short4v*)&Ih[base];
        ((short4v*)&w3h[s])[1] = *(short4v*)&Ih[base + 8];
        ((short4v*)&w3l[s])[0] = *(short4v*)&Il[base];
        ((short4v*)&w3l[s])[1] = *(short4v*)&Il[base + 8];
    }
    __syncthreads();
    // stage Wo1b^T (hi only), hoist
    {
        int col = tid >> 2, kseg = (tid & 3) * 16;
        short hi[16];
        #pragma unroll
        for(int j=0;j<16;++j) hi[j] = f2bf_rne(Wo1[4096 + (kseg+j)*64 + col]);
        #pragma unroll
        for(int i=0;i<4;++i)
            *(short4v*)&Ih[col*68 + kseg + 4*i] = *(short4v*)&hi[4*i];
    }
    __syncthreads();
    short8v w2h[4];
    #pragma unroll
    for(int s=0;s<4;++s){
        int base = (colhalf + c)*68 + s*16 + g*4;
        ((short4v*)&w2h[s])[0] = *(short4v*)&Ih[base];
        ((short4v*)&w2h[s])[1] = *(short4v*)&Ih[base + 8];
    }
    __syncthreads();

    int U = (int)Ucnt[0];
    float bc3 = b3[colhalf + c];

    const int NT = (N_PREV + 63) / 64;
    for(int tile = blockIdx.x; tile < NT; tile += gridDim.x){
        int rbase = tile * 64;
        if(rbase >= U) break;
        if(tid < 128){
            int row = tid >> 1, kseg = (tid & 1) * 16;
            int grow = rbase + row;
            float fv[16];
            if(grow < U){
                uint4 a0 = *(const uint4*)&x2b[grow*32 + kseg];
                uint4 a1 = *(const uint4*)&x2b[grow*32 + kseg + 8];
                unsigned wv[8] = {a0.x,a0.y,a0.z,a0.w,a1.x,a1.y,a1.z,a1.w};
                #pragma unroll
                for(int k=0;k<8;++k){
                    float lo = __uint_as_float(wv[k]<<16);
                    float hi = __uint_as_float(wv[k]&0xffff0000u);
                    fv[2*k]   = lo*ash[kseg+2*k]   + bbsh[kseg+2*k];
                    fv[2*k+1] = hi*ash[kseg+2*k+1] + bbsh[kseg+2*k+1];
                }
            } else {
                #pragma unroll
                for(int j=0;j<16;++j) fv[j]=0.f;
            }
            short hi[16], lo[16];
            #pragma unroll
            for(int j=0;j<16;++j){
                short h = f2bf_rne(fv[j]);
                hi[j] = h; lo[j] = f2bf_rne(fv[j] - bf2f(h));
            }
            #pragma unroll
            for(int i=0;i<4;++i){
                *(short4v*)&Ah[row*36 + kseg + 4*i] = *(short4v*)&hi[4*i];
                *(short4v*)&Al[row*36 + kseg + 4*i] = *(short4v*)&lo[4*i];
            }
        }
        __syncthreads();
        f32x16 acc;
        #pragma unroll
        for(int i=0;i<16;++i) acc[i]=0.f;
        #pragma unroll
        for(int s=0;s<2;++s){
            int abase = (rowhalf + c)*36 + s*16 + g*4;
            short8v ah, al;
            ((short4v*)&ah)[0] = *(short4v*)&Ah[abase];
            ((short4v*)&ah)[1] = *(short4v*)&Ah[abase + 8];
            ((short4v*)&al)[0] = *(short4v*)&Al[abase];
            ((short4v*)&al)[1] = *(short4v*)&Al[abase + 8];
            acc = __builtin_amdgcn_mfma_f32_32x32x16_bf16(ah, w3h[s], acc, 0,0,0);
            acc = __builtin_amdgcn_mfma_f32_32x32x16_bf16(al, w3h[s], acc, 0,0,0);
            acc = __builtin_amdgcn_mfma_f32_32x32x16_bf16(ah, w3l[s], acc, 0,0,0);
        }
        #pragma unroll
        for(int r=0;r<16;++r){
            int row = rowhalf + (r&3) + 8*(r>>2) + 4*g;
            float v = acc[r] + bc3;
            v = v > 0.f ? v : 0.1f*v;
            Ih[row*68 + colhalf + c] = f2bf_rne(v);
        }
        __syncthreads();
        f32x16 acc2;
        #pragma unroll
        for(int i=0;i<16;++i) acc2[i]=0.f;
        #pragma unroll
        for(int s=0;s<4;++s){
            int abase = (rowhalf + c)*68 + s*16 + g*4;
            short8v ah;
            ((short4v*)&ah)[0] = *(short4v*)&Ih[abase];
            ((short4v*)&ah)[1] = *(short4v*)&Ih[abase + 8];
            acc2 = __builtin_amdgcn_mfma_f32_32x32x16_bf16(ah, w2h[s], acc2, 0,0,0);
        }
        #pragma unroll
        for(int r=0;r<16;++r){
            int grow = rbase + rowhalf + (r&3) + 8*(r>>2) + 4*g;
            if(grow < U) P2[grow*64 + colhalf + c] = (unsigned short)f2bf_rne(acc2[r]);
        }
        __syncthreads();
    }
}

// ---- one wave per voxel (R9-verified: uniform clamped shfl, batch-8 pipelined loads) ----
__global__ void __launch_bounds__(256) k_vox(const unsigned* __restrict__ vstart,
        const int* __restrict__ csr_j, const int* __restrict__ csr_h,
        const unsigned short* __restrict__ P1, const unsigned short* __restrict__ P2,
        const float* __restrict__ bo1, const float* __restrict__ Wo2,
        const float* __restrict__ bo2, float* __restrict__ out){
    __shared__ float tsh[4][64];
    int tid = threadIdx.x;
    int wib = tid>>6, lane = tid&63;
    float wreg[64];
    #pragma unroll
    for(int k=0;k<64;++k) wreg[k] = Wo2[k*64+lane];
    float b1c = bo1[lane], b2c = bo2[lane];
    int wglobal = blockIdx.x*4 + wib;
    for(int vq=0; vq<4; ++vq){
        int vox = wglobal*4 + vq;
        int s = (int)vstart[vox], e = (int)vstart[vox+1];
        float acc = 0.f;
        for(int i=s; i<e; i+=64){
            int n = min(e-i, 64);
            int jv=0, hv=0;
            if(lane<n){ jv = csr_j[i+lane]; hv = csr_h[i+lane]; }
            for(int q0=0; q0<n; q0+=8){
                float pa[8], pb[8];
                #pragma unroll
                for(int t=0;t<8;++t){
                    int qq = q0 + t;
                    qq = (qq < n) ? qq : q0;
                    int j = __shfl(jv, qq);
                    int h = __shfl(hv, qq);
                    pa[t] = bf2f((short)P1[(size_t)j*64 + lane]);
                    pb[t] = bf2f((short)P2[(size_t)h*64 + lane]);
                }
                #pragma unroll
                for(int t=0;t<8;++t){
                    if(q0 + t < n){
                        float g = pa[t] + pb[t] + b1c;
                        acc += (g>0.f) ? g : 0.1f*g;
                    }
                }
            }
        }
        tsh[wib][lane] = acc;
        float dot = 0.f;
        const float4* t4 = (const float4*)tsh[wib];
        #pragma unroll
        for(int k4=0;k4<16;++k4){
            float4 t = t4[k4];
            dot += t.x*wreg[4*k4] + t.y*wreg[4*k4+1] + t.z*wreg[4*k4+2] + t.w*wreg[4*k4+3];
        }
        float cntv = (float)(e - s);
        out[vox*64+lane] = (dot + cntv*b2c) / fmaxf(cntv, 1.f);
    }
}

extern "C" void kernel_launch(void* const* d_in, const int* in_sizes, int n_in,
                              void* d_out, int out_size, void* d_ws, size_t ws_size,
                              hipStream_t stream) {
    if(ws_size < WS_NEEDED) return;

    const float* features = (const float*)d_in[0];
    const int*   coors    = (const int*)d_in[1];
    const int*   cif      = (const int*)d_in[2];
    const int*   scv      = (const int*)d_in[3];
    const float* W_in     = (const float*)d_in[4];
    const float* b_in     = (const float*)d_in[5];
    const float* W1       = (const float*)d_in[6];
    const float* b1       = (const float*)d_in[7];
    const float* g1       = (const float*)d_in[8];
    const float* be1      = (const float*)d_in[9];
    const float* W2       = (const float*)d_in[10];
    const float* b2       = (const float*)d_in[11];
    const float* g2       = (const float*)d_in[12];
    const float* be2      = (const float*)d_in[13];
    const float* W3       = (const float*)d_in[14];
    const float* b3       = (const float*)d_in[15];
    const float* Wo1      = (const float*)d_in[16];
    const float* bo1      = (const float*)d_in[17];
    const float* Wo2      = (const float*)d_in[18];
    const float* bo2      = (const float*)d_in[19];

    char* ws = (char*)d_ws;
    unsigned* bitmap = (unsigned*)(ws + OFF_BITMAP);
    float*    stats  = (float*)(ws + OFF_STATS);
    float*    cnt    = (float*)(ws + OFF_CNT);
    unsigned* vh     = (unsigned*)(ws + OFF_VH);
    unsigned short* yb = (unsigned short*)(ws + OFF_Y);
    unsigned short* P2 = (unsigned short*)(ws + OFF_P2);
    unsigned* pref   = (unsigned*)(ws + OFF_PREF);
    unsigned* bsum   = (unsigned*)(ws + OFF_BSUM);
    unsigned* boff   = (unsigned*)(ws + OFF_BOFF);
    unsigned* Ucnt   = (unsigned*)(ws + OFF_UCNT);
    int*      inv    = (int*)(ws + OFF_INV);
    unsigned short* P1 = (unsigned short*)(ws + OFF_P1);
    unsigned short* x2b = (unsigned short*)(ws + OFF_X2);
    int*      csr_j  = (int*)(ws + OFF_CSRJ);
    int*      csr_h  = (int*)(ws + OFF_CSRH);
    unsigned* vstart = (unsigned*)(ws + OFF_VSTART);
    unsigned* vnext  = (unsigned*)(ws + OFF_VNEXT);
    unsigned* vpart  = (unsigned*)(ws + OFF_VPART);
    unsigned* vbsum  = (unsigned*)(ws + OFF_VBSUM);

    hipMemsetAsync(d_ws, 0, ZERO_BYTES, stream);

    k_mark  <<<(N_PREV+255)/256, 256, 0, stream>>>(coors, bitmap);
    k_scanA <<<1024, 1024, 0, stream>>>(bitmap, pref, bsum);
    k_scanB <<<1, 1024, 0, stream>>>(bsum, boff, Ucnt);
    k_p1f   <<<1024, 256, 0, stream>>>(features, coors, bitmap, pref, boff,
                                       W_in, b_in, Wo1, W1, P1, inv, cnt, yb);
    // CSR build (overwrites bitmap/pref regions — safe after k_p1f)
    k_vhist <<<(N_FULL+255)/256, 256, 0, stream>>>(scv, vh);
    k_vscanA<<<64, 1024, 0, stream>>>(vh, vpart, vbsum);
    k_vscanB<<<1, 64, 0, stream>>>(vbsum);
    k_vfix  <<<64, 1024, 0, stream>>>(vpart, vbsum, vstart, vnext);
    k_fill  <<<(N_FULL+255)/256, 256, 0, stream>>>(cif, scv, inv, vnext, csr_j, csr_h);
    // PPmodel chain
    k_bn1   <<<1024, 256, 0, stream>>>(yb, cnt, Ucnt, b1, stats);
    k_bnfin <<<1, 32, 0, stream>>>(Ucnt, g1, stats, 0);
    k_ppm2  <<<1024, 256, 0, stream>>>(yb, cnt, Ucnt, W2, b1, b2, be1, x2b, stats);
    k_bnfin <<<1, 32, 0, stream>>>(Ucnt, g2, stats, 128);
    k_ppm3  <<<1024, 256, 0, stream>>>(x2b, Ucnt, W3, b3, be2, Wo1, P2, stats);
    k_vox   <<<NVOX/16, 256, 0, stream>>>(vstart, csr_j, csr_h, P1, P2, bo1, Wo2, bo2, (float*)d_out);
}